// Round 10
// baseline (743.315 us; speedup 1.0000x reference)
//
#include <hip/hip_runtime.h>
#include <hip/hip_bf16.h>

#define BH 16
#define NTOK 8192
#define NHEAD 8
#define DH 64
#define MLM 256
#define QSCALE 0.125f
#define LP 72   // ushort stride for flash LDS tiles; MUST be >= 64 (row holds 64 ushorts of K-dim)
#define LOG2E 1.4426950408889634f

typedef unsigned short ushort_t;
using frag_ab = __attribute__((ext_vector_type(8))) short;   // 8 bf16 (4 VGPRs)
using frag_cd = __attribute__((ext_vector_type(4))) float;   // 4 fp32 acc

__device__ __forceinline__ unsigned short f2bs(float f){
  __hip_bfloat16 h = __float2bfloat16(f);
  return *(unsigned short*)&h;
}
__device__ __forceinline__ float bs2f(unsigned short u){
  union { unsigned int i; float f; } cv; cv.i = ((unsigned int)u) << 16; return cv.f;
}

// async global->LDS, 16B per lane.  LDS dest = wave-uniform base + lane*16 (HW).
__device__ __forceinline__ void gl_lds16(const unsigned short* g, unsigned short* l){
  __builtin_amdgcn_global_load_lds((const __attribute__((address_space(1))) unsigned int*)(const void*)g,
                                   (__attribute__((address_space(3))) unsigned int*)(void*)l, 16, 0, 0);
}

// ---------------- weight transpose + hi/lo bf16 split: in[K][N] -> outh/outl [N][K]
// swz!=0: pre-swizzle 16B slot within each 32-col K-group (slot ^= row&3) for gload_lds consumers
__global__ __launch_bounds__(256) void k_splitw(const float* __restrict__ in, int K, int N,
                                                unsigned short* __restrict__ oh,
                                                unsigned short* __restrict__ ol, int swz){
  const int idx = blockIdx.x * 256 + threadIdx.x;   // over N*K
  const int n = idx / K, k = idx - n * K;
  const float v = in[(size_t)k * N + n];
  const unsigned short hi = f2bs(v);
  int kd = k;
  if (swz){
    const int q = (k >> 3) & 3;
    kd = (k & ~31) | (((q ^ (n & 3)) & 3) << 3) | (k & 7);
  }
  oh[(size_t)n * K + kd] = hi;
  ol[(size_t)n * K + kd] = f2bs(v - bs2f(hi));
}

// ---------------- plain hi/lo split of x, PRE-SWIZZLED for gload_lds (slot ^= row&3)
__global__ __launch_bounds__(256) void k_splitx(const float* __restrict__ in,
                                                unsigned short* __restrict__ oh,
                                                unsigned short* __restrict__ ol){
  const size_t i4 = ((size_t)blockIdx.x * 256 + threadIdx.x) * 4;
  const int row = (int)(i4 >> 9);
  const int col = (int)(i4 & 511);
  const int q = (col >> 3) & 3;
  const int cd = (col & ~31) | (((q ^ (row & 3)) & 3) << 3) | (col & 7);
  const size_t o4 = ((size_t)row << 9) + cd;
  float4 v = *(const float4*)(in + i4);
  const unsigned short h0 = f2bs(v.x), h1 = f2bs(v.y), h2 = f2bs(v.z), h3 = f2bs(v.w);
  *(ushort4*)(oh + o4) = make_ushort4(h0, h1, h2, h3);
  *(ushort4*)(ol + o4) = make_ushort4(f2bs(v.x - bs2f(h0)), f2bs(v.y - bs2f(h1)),
                                      f2bs(v.z - bs2f(h2)), f2bs(v.w - bs2f(h3)));
}

// ---------------- MFMA split-bf16 GEMM: qkv.  A = x pre-split+swizzled [16384][512],
// B = wqkvT pre-split+swizzled [1536][512].  128x128 tile, 4 waves, 64x64 each.
// LDS DOUBLE-BUFFER 2-phase: stage(k+1) issued before MFMA(k); ONE barrier per K-step.
__global__ __launch_bounds__(256) void k_mfma_qkv(const unsigned short* __restrict__ xh,
                                                  const unsigned short* __restrict__ xl,
                                                  const unsigned short* __restrict__ bth,
                                                  const unsigned short* __restrict__ btl,
                                                  float* __restrict__ q,
                                                  unsigned short* __restrict__ kSh,
                                                  unsigned short* __restrict__ kSl,
                                                  float* __restrict__ v){
  const int n0 = blockIdx.x * 128;   // over 1536
  const int m0 = blockIdx.y * 128;   // over 16384
  __shared__ unsigned short SB[2][4 * 128 * 32];   // 2 buffers x {Ah,Al,Bh,Bl} planes
  const int tid = threadIdx.x;
  const int wave = tid >> 6, lane = tid & 63;
  const int wm = wave >> 1, wn = wave & 1;
  const int lr = lane & 15, quad = lane >> 4;
  const int cswz = ((quad ^ (lr & 3)) & 3) << 3;   // swizzled 8-ushort slot
  // staging: wave w owns plane w
  const unsigned short* gsrc = (wave == 0) ? xh : (wave == 1) ? xl : (wave == 2) ? bth : btl;
  const int R0 = (wave < 2) ? m0 : n0;
  const int lrow = lane >> 2, lslot = (lane & 3) << 3;
  const int pbase = wave * 4096;
  frag_cd acc[4][4];
#pragma unroll
  for (int mt = 0; mt < 4; mt++)
#pragma unroll
    for (int nt = 0; nt < 4; nt++){
      frag_cd z = {0.f, 0.f, 0.f, 0.f};
      acc[mt][nt] = z;
    }
  // prologue: stage k0=0 into buf 0
#pragma unroll
  for (int u = 0; u < 8; u++)
    gl_lds16(gsrc + (size_t)(R0 + u*16 + lrow) * 512 + lslot, &SB[0][pbase] + u * 512);
  __syncthreads();
  int cur = 0;
  for (int k0 = 0; k0 < 512; k0 += 32){
    // issue next K-step's loads into the other buffer (overlap with MFMA below)
    if (k0 + 32 < 512){
#pragma unroll
      for (int u = 0; u < 8; u++)
        gl_lds16(gsrc + (size_t)(R0 + u*16 + lrow) * 512 + k0 + 32 + lslot,
                 &SB[cur ^ 1][pbase] + u * 512);
    }
    const unsigned short* Ah = &SB[cur][0];
    const unsigned short* Al = &SB[cur][4096];
    const unsigned short* Bh = &SB[cur][8192];
    const unsigned short* Bl = &SB[cur][12288];
    frag_ab a_h[4], a_l[4], b_h[4], b_l[4];
#pragma unroll
    for (int t = 0; t < 4; t++){
      const int ar = (wm*64 + t*16 + lr) << 5;
      const int br = (wn*64 + t*16 + lr) << 5;
      a_h[t] = *(const frag_ab*)&Ah[ar + cswz];
      a_l[t] = *(const frag_ab*)&Al[ar + cswz];
      b_h[t] = *(const frag_ab*)&Bh[br + cswz];
      b_l[t] = *(const frag_ab*)&Bl[br + cswz];
    }
#pragma unroll
    for (int mt = 0; mt < 4; mt++)
#pragma unroll
      for (int nt = 0; nt < 4; nt++){
        acc[mt][nt] = __builtin_amdgcn_mfma_f32_16x16x32_bf16(a_l[mt], b_h[nt], acc[mt][nt], 0, 0, 0);
        acc[mt][nt] = __builtin_amdgcn_mfma_f32_16x16x32_bf16(a_h[mt], b_l[nt], acc[mt][nt], 0, 0, 0);
        acc[mt][nt] = __builtin_amdgcn_mfma_f32_16x16x32_bf16(a_h[mt], b_h[nt], acc[mt][nt], 0, 0, 0);
      }
    __syncthreads();   // drains vmcnt (next buffer landed) + everyone done reading cur
    cur ^= 1;
  }
  // epilogue: D row = quad*4+reg, col = lane&15
#pragma unroll
  for (int mt = 0; mt < 4; mt++)
#pragma unroll
    for (int nt = 0; nt < 4; nt++)
#pragma unroll
      for (int rg = 0; rg < 4; rg++){
        const int row = m0 + wm*64 + mt*16 + quad*4 + rg;
        const int col = n0 + wn*64 + nt*16 + lr;
        const int bb = row >> 13, i = row & 8191;
        const int which = col >> 9;
        const int cc = col & 511;
        const int h = cc >> 6, d = cc & 63;
        const size_t off = (((size_t)(bb * NHEAD + h)) * NTOK + i) * DH + d;
        const float val = acc[mt][nt][rg];
        if (which == 0)      q[off] = val * QSCALE;
        else if (which == 1){
          const unsigned short hi = f2bs(val);
          kSh[off] = hi; kSl[off] = f2bs(val - bs2f(hi));
        }
        else                 v[off] = val;
      }
}

// ---------------- MFMA split-bf16 GEMM: final.  A = oh packed (hi|lo in uint32 slots of qf,
// layout [bh][8192][64]), B = woutT hi/lo [512][512].  out = A@B + bout + x.
// A register-prefetched one K-step ahead (loads overlap MFMA).
__global__ __launch_bounds__(256) void k_mfma_final(const unsigned int* __restrict__ qpk,
                                                    const unsigned short* __restrict__ bth,
                                                    const unsigned short* __restrict__ btl,
                                                    const float* __restrict__ xin,
                                                    const float* __restrict__ bout,
                                                    float* __restrict__ outp){
  const int n0 = blockIdx.x * 128;   // over 512
  const int m0 = blockIdx.y * 128;   // over 16384
  __shared__ unsigned short Ah[128][40], Al[128][40], Bh[128][40], Bl[128][40];
  const int tid = threadIdx.x;
  const int wave = tid >> 6, lane = tid & 63;
  const int wm = wave >> 1, wn = wave & 1;
  const int lr = lane & 15, quad = lane >> 4, koff = quad * 8;
  const int bb = m0 >> 13;
  frag_cd acc[4][4];
#pragma unroll
  for (int mt = 0; mt < 4; mt++)
#pragma unroll
    for (int nt = 0; nt < 4; nt++){
      frag_cd z = {0.f, 0.f, 0.f, 0.f};
      acc[mt][nt] = z;
    }
  const int arow = tid >> 3, ac4 = (tid & 7) << 2;     // A: 4 slots of 32 rows
  const int brow = tid >> 2, bch = (tid & 3) << 3;     // B: 2 slots of 64 rows
  uint4 pw[4];
  // prologue: prefetch A regs for k0=0
#pragma unroll
  for (int u = 0; u < 4; u++){
    const int row = arow + u * 32;
    const int i = (m0 + row) & 8191;
    pw[u] = *(const uint4*)(qpk + (((size_t)(bb * NHEAD + 0)) * NTOK + i) * DH + 0 + ac4);
  }
  for (int k0 = 0; k0 < 512; k0 += 32){
    __syncthreads();
    // write LDS from prefetched A regs
#pragma unroll
    for (int u = 0; u < 4; u++){
      const int row = arow + u * 32;
      *(ushort4*)&Ah[row][ac4] = make_ushort4((unsigned short)pw[u].x, (unsigned short)pw[u].y,
                                              (unsigned short)pw[u].z, (unsigned short)pw[u].w);
      *(ushort4*)&Al[row][ac4] = make_ushort4((unsigned short)(pw[u].x >> 16), (unsigned short)(pw[u].y >> 16),
                                              (unsigned short)(pw[u].z >> 16), (unsigned short)(pw[u].w >> 16));
    }
    // stage B (pre-split copies, L2-hot)
#pragma unroll
    for (int u = 0; u < 2; u++){
      const int row = brow + u * 64;
      *(uint4*)&Bh[row][bch] = *(const uint4*)(bth + (size_t)(n0 + row) * 512 + k0 + bch);
      *(uint4*)&Bl[row][bch] = *(const uint4*)(btl + (size_t)(n0 + row) * 512 + k0 + bch);
    }
    __syncthreads();
    // prefetch A regs for k0+32 (loads in flight during MFMA)
    if (k0 + 32 < 512){
      const int hn = (k0 + 32) >> 6, dbn = (k0 + 32) & 63;
#pragma unroll
      for (int u = 0; u < 4; u++){
        const int row = arow + u * 32;
        const int i = (m0 + row) & 8191;
        pw[u] = *(const uint4*)(qpk + (((size_t)(bb * NHEAD + hn)) * NTOK + i) * DH + dbn + ac4);
      }
    }
    frag_ab a_h[4], a_l[4], b_h[4], b_l[4];
#pragma unroll
    for (int t = 0; t < 4; t++){
      a_h[t] = *(const frag_ab*)&Ah[wm*64 + t*16 + lr][koff];
      a_l[t] = *(const frag_ab*)&Al[wm*64 + t*16 + lr][koff];
      b_h[t] = *(const frag_ab*)&Bh[wn*64 + t*16 + lr][koff];
      b_l[t] = *(const frag_ab*)&Bl[wn*64 + t*16 + lr][koff];
    }
#pragma unroll
    for (int mt = 0; mt < 4; mt++)
#pragma unroll
      for (int nt = 0; nt < 4; nt++){
        acc[mt][nt] = __builtin_amdgcn_mfma_f32_16x16x32_bf16(a_l[mt], b_h[nt], acc[mt][nt], 0, 0, 0);
        acc[mt][nt] = __builtin_amdgcn_mfma_f32_16x16x32_bf16(a_h[mt], b_l[nt], acc[mt][nt], 0, 0, 0);
        acc[mt][nt] = __builtin_amdgcn_mfma_f32_16x16x32_bf16(a_h[mt], b_h[nt], acc[mt][nt], 0, 0, 0);
      }
  }
#pragma unroll
  for (int mt = 0; mt < 4; mt++)
#pragma unroll
    for (int nt = 0; nt < 4; nt++)
#pragma unroll
      for (int rg = 0; rg < 4; rg++){
        const int row = m0 + wm*64 + mt*16 + quad*4 + rg;
        const int col = n0 + wn*64 + nt*16 + lr;
        outp[(size_t)row * 512 + col] = acc[mt][nt][rg] + bout[col] + xin[(size_t)row * 512 + col];
      }
}

// ---------------- landmark means for q and k in one launch (grid.y selects)
// k is read from pre-split planes; also emits hi/lo bf16 split copies
__global__ __launch_bounds__(64) void k_land2(const float* __restrict__ qf,
                                              const unsigned short* __restrict__ kSh,
                                              const unsigned short* __restrict__ kSl,
                                              float* __restrict__ qlf, float* __restrict__ klf,
                                              unsigned short* __restrict__ qlSh, unsigned short* __restrict__ qlSl,
                                              unsigned short* __restrict__ klSh, unsigned short* __restrict__ klSl){
  const int isK = blockIdx.y;
  float* dst = isK ? klf : qlf;
  unsigned short* dh = isK ? klSh : qlSh;
  unsigned short* dl = isK ? klSl : qlSl;
  const int bh = blockIdx.x >> 8;
  const int j  = blockIdx.x & 255;
  const int d  = threadIdx.x;
  const size_t base = ((size_t)bh * NTOK + (size_t)j * 32) * DH + d;
  float s = 0.f;
  if (!isK){
    const float* p = qf + base;
#pragma unroll
    for (int t = 0; t < 32; t++) s += p[t * DH];
  } else {
    const unsigned short* ph = kSh + base;
    const unsigned short* pl = kSl + base;
#pragma unroll
    for (int t = 0; t < 32; t++) s += bs2f(ph[t * DH]) + bs2f(pl[t * DH]);
  }
  const float val = s * (1.f / 32.f);
  const size_t oidx = ((size_t)bh * MLM + j) * DH + d;
  dst[oidx] = val;
  const unsigned short hi = f2bs(val);
  dh[oidx] = hi;
  dl[oidx] = f2bs(val - bs2f(hi));
}

// ---------------- transpose + split v: [bh][8192][64] fp32 -> vTh/vTl [bh][64][8192] bf16
__global__ __launch_bounds__(256) void k_vtrans(const float* __restrict__ vf,
                                                unsigned short* __restrict__ vTh,
                                                unsigned short* __restrict__ vTl){
  __shared__ float T[64][68];
  const int j0 = blockIdx.x * 64, bh = blockIdx.y;
  const int tid = threadIdx.x;
#pragma unroll
  for (int u = 0; u < 4; u++){
    const int f = tid + u * 256, row = f >> 4, c4 = (f & 15) << 2;
    *(float4*)&T[row][c4] = *(const float4*)(vf + ((size_t)bh * NTOK + j0 + row) * DH + c4);
  }
  __syncthreads();
#pragma unroll
  for (int u = 0; u < 4; u++){
    const int f = tid + u * 256, d = f >> 4, j4 = (f & 15) << 2;
    const float v0 = T[j4+0][d], v1 = T[j4+1][d], v2 = T[j4+2][d], v3 = T[j4+3][d];
    const unsigned short h0 = f2bs(v0), h1 = f2bs(v1), h2 = f2bs(v2), h3 = f2bs(v3);
    const size_t off = ((size_t)bh * DH + d) * NTOK + j0 + j4;
    *(ushort4*)(vTh + off) = make_ushort4(h0, h1, h2, h3);
    *(ushort4*)(vTl + off) = make_ushort4(f2bs(v0 - bs2f(h0)), f2bs(v1 - bs2f(h1)),
                                          f2bs(v2 - bs2f(h2)), f2bs(v3 - bs2f(h3)));
  }
}

// ---------------- sim2 = ql @ kl^T (fp32, K=64), batched [bh][256][256]
__global__ __launch_bounds__(256) void k_sim2(const float* __restrict__ qlf,
                                              const float* __restrict__ klf,
                                              float* __restrict__ C){
  const int bh = blockIdx.z;
  const float* Ab = qlf + (size_t)bh * MLM * DH;
  const float* Bb = klf + (size_t)bh * MLM * DH;
  float* Cb = C + (size_t)bh * MLM * MLM;
  const int n0 = blockIdx.x * 64;
  const int m0 = blockIdx.y * 64;
  __shared__ float As[16][64];
  __shared__ float Bs[16][64];
  const int tid = threadIdx.x, ty = tid >> 4, tx = tid & 15;
  const int lm = tid >> 2, lk = (tid & 3) << 2;
  float acc[4][4] = {};
  for (int k0 = 0; k0 < 64; k0 += 16){
    float4 a4 = *(const float4*)(Ab + (size_t)(m0 + lm) * DH + k0 + lk);
    As[lk+0][lm] = a4.x; As[lk+1][lm] = a4.y; As[lk+2][lm] = a4.z; As[lk+3][lm] = a4.w;
    float4 b4 = *(const float4*)(Bb + (size_t)(n0 + lm) * DH + k0 + lk);
    Bs[lk+0][lm] = b4.x; Bs[lk+1][lm] = b4.y; Bs[lk+2][lm] = b4.z; Bs[lk+3][lm] = b4.w;
    __syncthreads();
#pragma unroll
    for (int kk = 0; kk < 16; kk++){
      float a[4], bv[4];
#pragma unroll
      for (int r = 0; r < 4; r++) a[r] = As[kk][ty*4 + r];
#pragma unroll
      for (int c = 0; c < 4; c++) bv[c] = Bs[kk][tx*4 + c];
#pragma unroll
      for (int r = 0; r < 4; r++)
#pragma unroll
        for (int c = 0; c < 4; c++) acc[r][c] += a[r] * bv[c];
    }
    __syncthreads();
  }
#pragma unroll
  for (int r = 0; r < 4; r++)
#pragma unroll
    for (int c = 0; c < 4; c++)
      Cb[(size_t)(m0 + ty*4 + r) * MLM + n0 + tx*4 + c] = acc[r][c];
}

// ---------------- row softmax over 256
__global__ __launch_bounds__(256) void k_softmax256(const float* __restrict__ in, float* __restrict__ outp){
  const int row = blockIdx.x;
  const int t = threadIdx.x;
  float v = in[(size_t)row * 256 + t];
  __shared__ float red[256];
  red[t] = v; __syncthreads();
  for (int o = 128; o > 0; o >>= 1){ if (t < o) red[t] = fmaxf(red[t], red[t+o]); __syncthreads(); }
  float mx = red[0]; __syncthreads();
  float e = exp2f((v - mx) * LOG2E);
  red[t] = e; __syncthreads();
  for (int o = 128; o > 0; o >>= 1){ if (t < o) red[t] += red[t+o]; __syncthreads(); }
  outp[(size_t)row * 256 + t] = e / red[0];
}

// ---------------- per-batch COLUMN abs-sum maxima (row-sums of softmax are exactly 1)
__global__ __launch_bounds__(256) void k_colrow(const float* __restrict__ a2, float* __restrict__ part){
  const int bh = blockIdx.x;
  const int t = threadIdx.x;
  const float* p = a2 + (size_t)bh * 65536;
  float cs = 0.f;
  for (int i = 0; i < 256; i++) cs += fabsf(p[(size_t)i * 256 + t]);
  __shared__ float r2[256];
  r2[t] = cs; __syncthreads();
  for (int o = 128; o > 0; o >>= 1){
    if (t < o) r2[t] = fmaxf(r2[t], r2[t+o]);
    __syncthreads();
  }
  if (t == 0) part[bh] = r2[0];
}

// ---------------- z0 = a2^T * (1/(col*row)); col==1 so sc = 1/max_colsum
// also emits z^T pre-split (= a2 scaled, no transpose needed)
__global__ __launch_bounds__(256) void k_z0(const float* __restrict__ a2, const float* __restrict__ part,
                                            float* __restrict__ z,
                                            unsigned short* __restrict__ zTh,
                                            unsigned short* __restrict__ zTl){
  const int bh = blockIdx.x >> 8;
  const int i  = blockIdx.x & 255;
  const int j  = threadIdx.x;
  float m2 = 0.f;
#pragma unroll
  for (int t = 0; t < 16; t++) m2 = fmaxf(m2, part[t]);
  const float sc = 1.f / m2;
  const size_t ridx = ((size_t)bh * 256 + j) * 256 + i;
  const float val = a2[ridx] * sc;
  z[((size_t)bh * 256 + i) * 256 + j] = val;
  const unsigned short hi = f2bs(val);
  zTh[ridx] = hi;
  zTl[ridx] = f2bs(val - bs2f(hi));
}

// ---------------- batched 256^3 MFMA split-bf16 GEMM (NS chain step):
// C = s0*(c0*D - A@B), B pre-transposed+split.  32x64 tile -> 512 blocks (2/CU),
// register prefetch double-buffer, 3-term split, LDS-transposed coalesced C^T epilogue.
__global__ __launch_bounds__(256) void k_gemm256m(const float* __restrict__ A,
                                                  const unsigned short* __restrict__ BTh,
                                                  const unsigned short* __restrict__ BTl,
                                                  const float* __restrict__ D,
                                                  float* __restrict__ C,
                                                  unsigned short* __restrict__ CTh,
                                                  unsigned short* __restrict__ CTl,
                                                  float c0, float s0, int wC){
  __shared__ unsigned short Ah[32][40], Al[32][40], Bh[64][40], Bl[64][40];
  __shared__ float Ct[64][33];
  const int bh = blockIdx.y, tile = blockIdx.x;
  const int m0 = (tile >> 2) * 32, n0 = (tile & 3) * 64;
  const size_t bo = (size_t)bh * 65536;
  const int tid = threadIdx.x;
  const int wave = tid >> 6, lane = tid & 63;
  const int wm = wave >> 1, wn = wave & 1;
  const int lr = lane & 15, quad = lane >> 4, koff = quad * 8;
  const int ar = tid >> 3, ac = (tid & 7) << 2;     // A tile: 32 rows x 32 cols fp32
  const int br = tid >> 2, bc = (tid & 3) << 3;     // B tile: 64 rows x 32 cols ushort
  frag_cd acc[2];
  { frag_cd z = {0.f,0.f,0.f,0.f}; acc[0] = z; acc[1] = z; }
  float4 ra  = *(const float4*)(A + bo + (size_t)(m0 + ar) * 256 + ac);
  uint4  rbh = *(const uint4*)(BTh + bo + (size_t)(n0 + br) * 256 + bc);
  uint4  rbl = *(const uint4*)(BTl + bo + (size_t)(n0 + br) * 256 + bc);
  for (int k0 = 0; k0 < 256; k0 += 32){
    __syncthreads();
    {
      const unsigned short h0=f2bs(ra.x),h1=f2bs(ra.y),h2=f2bs(ra.z),h3=f2bs(ra.w);
      *(ushort4*)&Ah[ar][ac] = make_ushort4(h0,h1,h2,h3);
      *(ushort4*)&Al[ar][ac] = make_ushort4(f2bs(ra.x-bs2f(h0)), f2bs(ra.y-bs2f(h1)),
                                            f2bs(ra.z-bs2f(h2)), f2bs(ra.w-bs2f(h3)));
      *(uint4*)&Bh[br][bc] = rbh;
      *(uint4*)&Bl[br][bc] = rbl;
    }
    __syncthreads();
    if (k0 < 224){
      ra  = *(const float4*)(A + bo + (size_t)(m0 + ar) * 256 + k0 + 32 + ac);
      rbh = *(const uint4*)(BTh + bo + (size_t)(n0 + br) * 256 + k0 + 32 + bc);
      rbl = *(const uint4*)(BTl + bo + (size_t)(n0 + br) * 256 + k0 + 32 + bc);
    }
    frag_ab a_h = *(const frag_ab*)&Ah[wm*16 + lr][koff];
    frag_ab a_l = *(const frag_ab*)&Al[wm*16 + lr][koff];
#pragma unroll
    for (int b = 0; b < 2; b++){
      frag_ab b_h = *(const frag_ab*)&Bh[wn*32 + b*16 + lr][koff];
      frag_ab b_l = *(const frag_ab*)&Bl[wn*32 + b*16 + lr][koff];
      acc[b] = __builtin_amdgcn_mfma_f32_16x16x32_bf16(a_l, b_h, acc[b], 0, 0, 0);
      acc[b] = __builtin_amdgcn_mfma_f32_16x16x32_bf16(a_h, b_l, acc[b], 0, 0, 0);
      acc[b] = __builtin_amdgcn_mfma_f32_16x16x32_bf16(a_h, b_h, acc[b], 0, 0, 0);
    }
  }
  // epilogue: fp32 C direct; C^T via LDS transpose for coalesced split writes
  const bool useD = (c0 != 0.f);
#pragma unroll
  for (int b = 0; b < 2; b++)
#pragma unroll
    for (int rg = 0; rg < 4; rg++){
      const int row = m0 + wm*16 + quad*4 + rg;
      const int col = n0 + wn*32 + b*16 + lr;
      const size_t idx = bo + (size_t)row * 256 + col;
      const float dv = useD ? D[idx] : 0.f;
      const float val = s0 * (c0 * dv - acc[b][rg]);
      if (wC) C[idx] = val;
      Ct[col - n0][row - m0] = val;
    }
  __syncthreads();
  {
    const int cr = tid >> 2, sg = (tid & 3) << 3;
    unsigned int ph[4], pl[4];
#pragma unroll
    for (int j = 0; j < 4; j++){
      const float v0 = Ct[cr][sg + 2*j], v1 = Ct[cr][sg + 2*j + 1];
      const unsigned short h0 = f2bs(v0), h1 = f2bs(v1);
      ph[j] = (unsigned int)h0 | ((unsigned int)h1 << 16);
      pl[j] = (unsigned int)f2bs(v0 - bs2f(h0)) | ((unsigned int)f2bs(v1 - bs2f(h1)) << 16);
    }
    const size_t tb = bo + (size_t)(n0 + cr) * 256 + m0 + sg;
    *(uint4*)(CTh + tb) = make_uint4(ph[0], ph[1], ph[2], ph[3]);
    *(uint4*)(CTl + tb) = make_uint4(pl[0], pl[1], pl[2], pl[3]);
  }
}

// ---------------- flash (MFMA split-bf16): partial online-softmax (attn3 @ v) per (kc, mtile, bh)
// 4 waves, each owns 16 q-rows x full 64-col chunk.  Q lifted to registers; P aliases K planes.
// LDS = 4 planes (36864 B).  kc split 16-way.  exp2 softmax.
__global__ __launch_bounds__(256) void k_flash(const unsigned short* __restrict__ qlSh,
                                               const unsigned short* __restrict__ qlSl,
                                               const unsigned short* __restrict__ kSh,
                                               const unsigned short* __restrict__ kSl,
                                               const unsigned short* __restrict__ vTh,
                                               const unsigned short* __restrict__ vTl,
                                               float* __restrict__ pbuf){
  extern __shared__ __align__(16) unsigned short sm[];
  unsigned short* Kh  = sm;                 // Q staging, then K, then P (hi)
  unsigned short* Kl  = sm + 1*64*LP;       // Q staging, then K, then P (lo)
  unsigned short* Wth = sm + 2*64*LP;
  unsigned short* Wtl = sm + 3*64*LP;
  const int kc = blockIdx.x, mt = blockIdx.y, bh = blockIdx.z;
  const int m0 = mt * 64, kbeg = kc * 512;
  const int tid = threadIdx.x;
  const int wave = tid >> 6, lane = tid & 63;
  const int lr = lane & 15, quad = lane >> 4;
  const size_t qbase = (size_t)bh * MLM * DH;
  const size_t kb  = (size_t)bh * NTOK * DH;
  const size_t vtb = (size_t)bh * DH * NTOK;
  // prologue: stage Q through K planes, lift own-wave fragments to registers
#pragma unroll
  for (int u = 0; u < 4; u++){
    const int f = tid + u * 256, row = f >> 4, c4 = (f & 15) << 2;
    *(ushort4*)&Kh[row*LP + c4] = *(const ushort4*)(qlSh + qbase + (size_t)(m0 + row) * DH + c4);
    *(ushort4*)&Kl[row*LP + c4] = *(const ushort4*)(qlSl + qbase + (size_t)(m0 + row) * DH + c4);
  }
  __syncthreads();
  frag_ab qa_h[2], qa_l[2];
#pragma unroll
  for (int ks = 0; ks < 2; ks++){
    const int ao = (wave*16 + lr)*LP + ks*32 + quad*8;
    qa_h[ks] = *(const frag_ab*)&Kh[ao];
    qa_l[ks] = *(const frag_ab*)&Kl[ao];
  }
  float m_run[4], l_run[4];
  frag_cd o[4];
#pragma unroll
  for (int r = 0; r < 4; r++){ m_run[r] = -1e30f; l_run[r] = 0.f; }
#pragma unroll
  for (int nt = 0; nt < 4; nt++){ frag_cd z = {0.f,0.f,0.f,0.f}; o[nt] = z; }

  for (int ch = 0; ch < 8; ch++){
    const int kr0 = kbeg + ch * 64;
    __syncthreads();   // prev PV done (and Q frag reads done on first iter)
    // stage K chunk and V^T chunk (all pre-split copies)
#pragma unroll
    for (int u = 0; u < 4; u++){
      const int f = tid + u * 256, row = f >> 4, c4 = (f & 15) << 2;
      *(ushort4*)&Kh[row*LP + c4]  = *(const ushort4*)(kSh + kb + (size_t)(kr0 + row) * DH + c4);
      *(ushort4*)&Kl[row*LP + c4]  = *(const ushort4*)(kSl + kb + (size_t)(kr0 + row) * DH + c4);
      *(ushort4*)&Wth[row*LP + c4] = *(const ushort4*)(vTh + vtb + (size_t)row * NTOK + kr0 + c4);
      *(ushort4*)&Wtl[row*LP + c4] = *(const ushort4*)(vTl + vtb + (size_t)row * NTOK + kr0 + c4);
    }
    __syncthreads();
    // S = Q @ K^T  (3-term split, Q from registers)
    frag_cd s[4];
#pragma unroll
    for (int nt = 0; nt < 4; nt++){ frag_cd z = {0.f,0.f,0.f,0.f}; s[nt] = z; }
#pragma unroll
    for (int ks = 0; ks < 2; ks++){
#pragma unroll
      for (int nt = 0; nt < 4; nt++){
        const int bo = (nt*16 + lr)*LP + ks*32 + quad*8;
        frag_ab b_h = *(const frag_ab*)&Kh[bo];
        frag_ab b_l = *(const frag_ab*)&Kl[bo];
        s[nt] = __builtin_amdgcn_mfma_f32_16x16x32_bf16(qa_l[ks], b_h, s[nt], 0, 0, 0);
        s[nt] = __builtin_amdgcn_mfma_f32_16x16x32_bf16(qa_h[ks], b_l, s[nt], 0, 0, 0);
        s[nt] = __builtin_amdgcn_mfma_f32_16x16x32_bf16(qa_h[ks], b_h, s[nt], 0, 0, 0);
      }
    }
    __syncthreads();   // all cross-wave K reads complete before P overwrites K planes
    // online softmax (exp2); P written into K planes (own-wave rows only)
#pragma unroll
    for (int rg = 0; rg < 4; rg++){
      float mx = fmaxf(fmaxf(s[0][rg], s[1][rg]), fmaxf(s[2][rg], s[3][rg]));
#pragma unroll
      for (int o2 = 8; o2 >= 1; o2 >>= 1) mx = fmaxf(mx, __shfl_xor(mx, o2));
      const float mnew = fmaxf(m_run[rg], mx);
      float e0 = exp2f((s[0][rg] - mnew) * LOG2E), e1 = exp2f((s[1][rg] - mnew) * LOG2E);
      float e2 = exp2f((s[2][rg] - mnew) * LOG2E), e3 = exp2f((s[3][rg] - mnew) * LOG2E);
      float psum = e0 + e1 + e2 + e3;
#pragma unroll
      for (int o2 = 8; o2 >= 1; o2 >>= 1) psum += __shfl_xor(psum, o2);
      const float alpha = exp2f((m_run[rg] - mnew) * LOG2E);
      l_run[rg] = l_run[rg] * alpha + psum;
      m_run[rg] = mnew;
#pragma unroll
      for (int nt = 0; nt < 4; nt++) o[nt][rg] *= alpha;
      const int prow = (wave*16 + quad*4 + rg) * LP;
      float ee[4] = {e0, e1, e2, e3};
#pragma unroll
      for (int nt = 0; nt < 4; nt++){
        const unsigned short hh = f2bs(ee[nt]);
        Kh[prow + nt*16 + lr] = hh;
        Kl[prow + nt*16 + lr] = f2bs(ee[nt] - bs2f(hh));
      }
    }
    // O += P @ V   (P own-wave rows from K planes; V^T cross-wave from W planes)
#pragma unroll
    for (int ks = 0; ks < 2; ks++){
      const int ao = (wave*16 + lr)*LP + ks*32 + quad*8;
      frag_ab p_h = *(const frag_ab*)&Kh[ao];
      frag_ab p_l = *(const frag_ab*)&Kl[ao];
#pragma unroll
      for (int nt = 0; nt < 4; nt++){
        const int bo = (nt*16 + lr)*LP + ks*32 + quad*8;
        frag_ab b_h = *(const frag_ab*)&Wth[bo];
        frag_ab b_l = *(const frag_ab*)&Wtl[bo];
        o[nt] = __builtin_amdgcn_mfma_f32_16x16x32_bf16(p_l, b_h, o[nt], 0, 0, 0);
        o[nt] = __builtin_amdgcn_mfma_f32_16x16x32_bf16(p_h, b_l, o[nt], 0, 0, 0);
        o[nt] = __builtin_amdgcn_mfma_f32_16x16x32_bf16(p_h, b_h, o[nt], 0, 0, 0);
      }
    }
  }
  // epilogue: unnormalized o + (m,l) partials, layout compatible with k_comb
  float* pb = pbuf + (((size_t)bh * 16 + kc) * 256 + m0) * 68;
#pragma unroll
  for (int rg = 0; rg < 4; rg++){
    const int row = wave*16 + quad*4 + rg;
#pragma unroll
    for (int nt = 0; nt < 4; nt++)
      pb[(size_t)row * 68 + nt*16 + lr] = o[nt][rg];
    if (lr == 0){
      pb[(size_t)row * 68 + 64] = m_run[rg];
      pb[(size_t)row * 68 + 65] = l_run[rg];
    }
  }
}

// ---------------- combine flash partials (16) -> av fp32 [bh][256][64]
__global__ __launch_bounds__(256) void k_comb(const float* __restrict__ pbuf, float* __restrict__ av){
  const int wv = threadIdx.x >> 6, lane = threadIdx.x & 63;
  const int id = blockIdx.x * 4 + wv;
  const int bh = id >> 8, row = id & 255;
  const float* base = pbuf + ((size_t)bh * 16 * 256 + row) * 68;
  float M = -1e30f;
#pragma unroll
  for (int k = 0; k < 16; k++) M = fmaxf(M, base[(size_t)k * 256 * 68 + 64]);
  float L = 0.f, o = 0.f;
#pragma unroll
  for (int k = 0; k < 16; k++){
    const float* p = base + (size_t)k * 256 * 68;
    float w = exp2f((p[64] - M) * LOG2E);
    L += p[65] * w;
    o += p[lane] * w;
  }
  av[((size_t)bh * MLM + row) * DH + lane] = o / L;
}

// ---------------- w2 = z_final @ av (fp32, M=256,N=64,K=256), batched
// also emits transposed hi/lo split w2T [bh][64][256] for the MFMA attn1 PV operand
__global__ __launch_bounds__(256) void k_w2(const float* __restrict__ Z, const float* __restrict__ AV,
                                            float* __restrict__ W2,
                                            unsigned short* __restrict__ w2Th,
                                            unsigned short* __restrict__ w2Tl){
  const int bh = blockIdx.y, mt = blockIdx.x;
  const float* Zb = Z + (size_t)bh * 65536;
  const float* Vb = AV + (size_t)bh * MLM * DH;
  float* Wb = W2 + (size_t)bh * MLM * DH;
  const int m0 = mt * 64;
  __shared__ float As[16][64];
  __shared__ float Bs[16][64];
  const int tid = threadIdx.x, ty = tid >> 4, tx = tid & 15;
  const int lm = tid >> 2, lk = (tid & 3) << 2;
  const int lk2 = tid >> 4, ln = (tid & 15) << 2;
  float acc[4][4] = {};
  for (int k0 = 0; k0 < 256; k0 += 16){
    float4 a4 = *(const float4*)(Zb + (size_t)(m0 + lm) * 256 + k0 + lk);
    As[lk+0][lm] = a4.x; As[lk+1][lm] = a4.y; As[lk+2][lm] = a4.z; As[lk+3][lm] = a4.w;
    float4 b4 = *(const float4*)(Vb + (size_t)(k0 + lk2) * DH + ln);
    *(float4*)&Bs[lk2][ln] = b4;
    __syncthreads();
#pragma unroll
    for (int kk = 0; kk < 16; kk++){
      float a[4], bv[4];
#pragma unroll
      for (int r = 0; r < 4; r++) a[r] = As[kk][ty*4 + r];
#pragma unroll
      for (int c = 0; c < 4; c++) bv[c] = Bs[kk][tx*4 + c];
#pragma unroll
      for (int r = 0; r < 4; r++)
#pragma unroll
        for (int c = 0; c < 4; c++) acc[r][c] += a[r] * bv[c];
    }
    __syncthreads();
  }
#pragma unroll
  for (int r = 0; r < 4; r++)
#pragma unroll
    for (int c = 0; c < 4; c++){
      const float val = acc[r][c];
      Wb[(size_t)(m0 + ty*4 + r) * DH + tx*4 + c] = val;
      const unsigned short hi = f2bs(val);
      const size_t tidx = ((size_t)bh * DH + tx*4 + c) * MLM + m0 + ty*4 + r;
      w2Th[tidx] = hi;
      w2Tl[tidx] = f2bs(val - bs2f(hi));
    }
}

// ---------------- fused attn1 (MFMA split-bf16): 512 threads / 8 waves, 128-row q tiles.
// K_l and W2^T fragments loaded DIRECTLY from global (L2-resident, 64 KB/bh) — no staging,
// no barriers in the jc loop.  LDS = P planes only (2 x [128][LP], wave-private rows).
// exp2 softmax.  Output packed (hi|lo) bf16 IN PLACE over q.
__global__ __launch_bounds__(512) void k_attn1(float* __restrict__ qoh,
                                               const unsigned short* __restrict__ klSh,
                                               const unsigned short* __restrict__ klSl,
                                               const float* __restrict__ vf,
                                               const unsigned short* __restrict__ w2Th,
                                               const unsigned short* __restrict__ w2Tl,
                                               const float* __restrict__ wconv){
  extern __shared__ __align__(16) unsigned short sm[];
  unsigned short* Ph  = sm;                 // [128][LP]
  unsigned short* Pl  = sm + 128*LP;        // [128][LP]
  float (*Vs)[68] = (float (*)[68])sm;      // conv phase: [160][68] = 43520 B (planes dead)
  float (*St)[68] = (float (*)[68])sm;      // pack phase: [128][68] = 34816 B
  __shared__ float wcs[33];
  const int it = blockIdx.x, bh = blockIdx.y, h = bh & 7;
  const int i0 = it * 128;
  float* qb = qoh + (size_t)bh * NTOK * DH;
  const int tid = threadIdx.x;
  const int wave = tid >> 6, lane = tid & 63;
  const int lr = lane & 15, quad = lane >> 4;
  if (tid < 33) wcs[tid] = wconv[h*33 + tid];
  // prologue: Q fragments direct from global (fp32 -> split in registers)
  frag_ab qa_h[2], qa_l[2];
#pragma unroll
  for (int ks = 0; ks < 2; ks++){
    const float* qsrc = qb + (size_t)(i0 + wave*16 + lr) * DH + ks*32 + quad*8;
    float4 a0 = *(const float4*)qsrc;
    float4 a1 = *(const float4*)(qsrc + 4);
    float vv[8] = {a0.x, a0.y, a0.z, a0.w, a1.x, a1.y, a1.z, a1.w};
    frag_ab fh, fl;
#pragma unroll
    for (int j = 0; j < 8; j++){
      const unsigned short hb = f2bs(vv[j]);
      fh[j] = (short)hb;
      fl[j] = (short)f2bs(vv[j] - bs2f(hb));
    }
    qa_h[ks] = fh; qa_l[ks] = fl;
  }
  float m_run[4], l_run[4];
  frag_cd o[4];
#pragma unroll
  for (int r = 0; r < 4; r++){ m_run[r] = -1e30f; l_run[r] = 0.f; }
#pragma unroll
  for (int nt = 0; nt < 4; nt++){ frag_cd z = {0.f,0.f,0.f,0.f}; o[nt] = z; }
  const size_t klbase = (size_t)bh * MLM * DH;
  const size_t wtbase = (size_t)bh * DH * MLM;

  for (int jc = 0; jc < 4; jc++){
    const int j0 = jc * 64;
    // S = Q @ K_l^T  (Q from regs, K frags direct from global — L2-hot)
    frag_cd s[4];
#pragma unroll
    for (int nt = 0; nt < 4; nt++){ frag_cd z = {0.f,0.f,0.f,0.f}; s[nt] = z; }
#pragma unroll
    for (int ks = 0; ks < 2; ks++){
      frag_ab kb_h[4], kb_l[4];
#pragma unroll
      for (int nt = 0; nt < 4; nt++){
        const size_t ko = klbase + (size_t)(j0 + nt*16 + lr) * DH + ks*32 + quad*8;
        kb_h[nt] = *(const frag_ab*)(klSh + ko);
        kb_l[nt] = *(const frag_ab*)(klSl + ko);
      }
#pragma unroll
      for (int nt = 0; nt < 4; nt++){
        s[nt] = __builtin_amdgcn_mfma_f32_16x16x32_bf16(qa_l[ks], kb_h[nt], s[nt], 0, 0, 0);
        s[nt] = __builtin_amdgcn_mfma_f32_16x16x32_bf16(qa_h[ks], kb_l[nt], s[nt], 0, 0, 0);
        s[nt] = __builtin_amdgcn_mfma_f32_16x16x32_bf16(qa_h[ks], kb_h[nt], s[nt], 0, 0, 0);
      }
    }
    // online softmax (exp2); P into LDS planes (wave-private rows, no barrier)
#pragma unroll
    for (int rg = 0; rg < 4; rg++){
      float mx = fmaxf(fmaxf(s[0][rg], s[1][rg]), fmaxf(s[2][rg], s[3][rg]));
#pragma unroll
      for (int o2 = 8; o2 >= 1; o2 >>= 1) mx = fmaxf(mx, __shfl_xor(mx, o2));
      const float mnew = fmaxf(m_run[rg], mx);
      float e0 = exp2f((s[0][rg] - mnew) * LOG2E), e1 = exp2f((s[1][rg] - mnew) * LOG2E);
      float e2 = exp2f((s[2][rg] - mnew) * LOG2E), e3 = exp2f((s[3][rg] - mnew) * LOG2E);
      float psum = e0 + e1 + e2 + e3;
#pragma unroll
      for (int o2 = 8; o2 >= 1; o2 >>= 1) psum += __shfl_xor(psum, o2);
      const float alpha = exp2f((m_run[rg] - mnew) * LOG2E);
      l_run[rg] = l_run[rg] * alpha + psum;
      m_run[rg] = mnew;
#pragma unroll
      for (int nt = 0; nt < 4; nt++) o[nt][rg] *= alpha;
      const int prow = (wave*16 + quad*4 + rg) * LP;
      float ee[4] = {e0, e1, e2, e3};
#pragma unroll
      for (int nt = 0; nt < 4; nt++){
        const unsigned short hh = f2bs(ee[nt]);
        Ph[prow + nt*16 + lr] = hh;
        Pl[prow + nt*16 + lr] = f2bs(ee[nt] - bs2f(hh));
      }
    }
    // O += P @ W2chunk  (P from LDS wave-private rows; W frags direct from global — L2-hot)
#pragma unroll
    for (int ks = 0; ks < 2; ks++){
      const int ao = (wave*16 + lr)*LP + ks*32 + quad*8;
      frag_ab p_h = *(const frag_ab*)&Ph[ao];
      frag_ab p_l = *(const frag_ab*)&Pl[ao];
      frag_ab wb_h[4], wb_l[4];
#pragma unroll
      for (int nt = 0; nt < 4; nt++){
        const size_t wo = wtbase + (size_t)(nt*16 + lr) * MLM + j0 + ks*32 + quad*8;
        wb_h[nt] = *(const frag_ab*)(w2Th + wo);
        wb_l[nt] = *(const frag_ab*)(w2Tl + wo);
      }
#pragma unroll
      for (int nt = 0; nt < 4; nt++){
        o[nt] = __builtin_amdgcn_mfma_f32_16x16x32_bf16(p_l, wb_h[nt], o[nt], 0, 0, 0);
        o[nt] = __builtin_amdgcn_mfma_f32_16x16x32_bf16(p_h, wb_l[nt], o[nt], 0, 0, 0);
        o[nt] = __builtin_amdgcn_mfma_f32_16x16x32_bf16(p_h, wb_h[nt], o[nt], 0, 0, 0);
      }
    }
  }
  // normalize
#pragma unroll
  for (int rg = 0; rg < 4; rg++){
    const float inv = 1.f / l_run[rg];
#pragma unroll
    for (int nt = 0; nt < 4; nt++) o[nt][rg] *= inv;
  }
  // conv: stage v rows [i0-16, i0+143] (160 rows) into Vs (P planes dead)
  __syncthreads();
#pragma unroll
  for (int u = 0; u < 5; u++){
    const int f = tid + u * 512, row = f >> 4, c4 = (f & 15) << 2;
    const int g = i0 - 16 + row;
    float4 vv = make_float4(0.f, 0.f, 0.f, 0.f);
    if (g >= 0 && g < NTOK) vv = *(const float4*)(vf + ((size_t)bh * NTOK + g) * DH + c4);
    *(float4*)&Vs[row][c4] = vv;
  }
  __syncthreads();
  // sliding-window conv: 36 reads per (nt), reuse across rg.
  const int rbase = wave*16 + quad*4;
#pragma unroll
  for (int nt = 0; nt < 4; nt++){
    const int col = nt*16 + lr;
#pragma unroll
    for (int s5 = 0; s5 < 36; s5++){
      const float v = Vs[rbase + s5][col];
#pragma unroll
      for (int rg = 0; rg < 4; rg++){
        const int t = s5 - rg;
        if (t >= 0 && t <= 32) o[nt][rg] += wcs[t] * v;
      }
    }
  }
  // pack (hi|lo) bf16, stage in St, coalesced write over q tile
  __syncthreads();
#pragma unroll
  for (int nt = 0; nt < 4; nt++)
#pragma unroll
    for (int rg = 0; rg < 4; rg++){
      const float val = o[nt][rg];
      const unsigned short hi = f2bs(val);
      const unsigned short lo = f2bs(val - bs2f(hi));
      St[rbase + rg][nt*16 + lr] = __uint_as_float((unsigned int)hi | ((unsigned int)lo << 16));
    }
  __syncthreads();
#pragma unroll
  for (int u = 0; u < 4; u++){
    const int f = tid + u * 512, row = f >> 4, c4 = (f & 15) << 2;
    *(float4*)(qb + (size_t)(i0 + row) * DH + c4) = *(const float4*)&St[row][c4];
  }
}

extern "C" void kernel_launch(void* const* d_in, const int* in_sizes, int n_in,
                              void* d_out, int out_size, void* d_ws, size_t ws_size,
                              hipStream_t stream){
  (void)in_sizes; (void)n_in; (void)out_size; (void)ws_size;
  const float* x     = (const float*)d_in[0];
  const float* wqkv  = (const float*)d_in[1];
  const float* wout  = (const float*)d_in[2];
  const float* bout  = (const float*)d_in[3];
  const float* wconv = (const float*)d_in[4];
  float* outp = (float*)d_out;

  char* base = (char*)d_ws;
  auto alloc = [&](size_t bytes)->char*{
    char* p = base; base += (bytes + 255) & ~(size_t)255; return p;
  };
  const size_t QS = (size_t)BH * NTOK * DH;   // 8388608
  const size_t LS = (size_t)BH * MLM * DH;    // 262144
  const size_t MM = (size_t)BH * MLM * MLM;   // 1048576

  float* qf   = (float*)alloc(QS * 4);   // q; packed oh overwrites in place
  float* vf   = (float*)alloc(QS * 4);
  unsigned short* kSh = (unsigned short*)alloc(QS * 2);
  unsigned short* kSl = (unsigned short*)alloc(QS * 2);
  float* qlf  = (float*)alloc(LS * 4);
  float* klf  = (float*)alloc(LS * 4);
  float* a2   = (float*)alloc(MM * 4);
  float* zb   = (float*)alloc(MM * 4);
  float* z2   = (float*)alloc(MM * 4);
  float* xz   = (float*)alloc(MM * 4);
  float* t2   = (float*)alloc(MM * 4);
  float* t4   = (float*)alloc(MM * 4);
  float* part = (float*)alloc(64 * 4);
  // union region: pinv transpose-split planes (10 x MM ushorts = 21.0 MB) alias pbuf
  // (flash partials, 16 x 16 x 256 x 68 x 4 B = 17.8 MB).  Planes dead before k_flash.
  char* un = alloc(10 * MM * 2);
  unsigned short* pl0 = (unsigned short*)un;
  unsigned short* zbTh = pl0 + 0*MM; unsigned short* zbTl = pl0 + 1*MM;
  unsigned short* z2Th = pl0 + 2*MM; unsigned short* z2Tl = pl0 + 3*MM;
  unsigned short* xzTh = pl0 + 4*MM; unsigned short* xzTl = pl0 + 5*MM;
  unsigned short* t2Th = pl0 + 6*MM; unsigned short* t2Tl = pl0 + 7*MM;
  unsigned short* t4Th = pl0 + 8*MM; unsigned short* t4Tl = pl0 + 9*MM;
  float* pbuf = (float*)un;
  float* av   = (float*)alloc(LS * 4);
  float* w2   = (float*)alloc(LS * 4);
  unsigned short* wqTh = (unsigned short*)alloc((size_t)1536 * 512 * 2);
  unsigned short* wqTl = (unsigned short*)alloc((size_t)1536 * 512 * 2);
  unsigned short* woTh = (unsigned short*)alloc((size_t)512 * 512 * 2);
  unsigned short* woTl = (unsigned short*)alloc((size_t)512 * 512 * 2);
  unsigned short* qlSh = (unsigned short*)alloc(LS * 2);
  unsigned short* qlSl = (unsigned short*)alloc(LS * 2);
  unsigned short* klSh = (unsigned short*)alloc(LS * 2);
  unsigned short* klSl = (unsigned short*)alloc(LS * 2);
  unsigned short* w2Th = (unsigned short*)alloc(LS * 2);
  unsigned short* w2Tl = (unsigned short*)alloc(LS * 2);
  unsigned short* vTh  = (unsigned short*)alloc(QS * 2);
  unsigned short* vTl  = (unsigned short*)alloc(QS * 2);
  // xh/xl alias vTh/vTl: consumed by k_mfma_qkv before k_vtrans overwrites.
  unsigned short* xh = vTh;
  unsigned short* xl = vTl;

  // 0. weight transpose + split (wqkv pre-swizzled for gload_lds; wout NOT); x split+swizzled
  k_splitw<<<1536 * 512 / 256, 256, 0, stream>>>(wqkv, 512, 1536, wqTh, wqTl, 1);
  k_splitw<<<512 * 512 / 256, 256, 0, stream>>>(wout, 512, 512, woTh, woTl, 0);
  k_splitx<<<8192, 256, 0, stream>>>(x, xh, xl);
  // 1. QKV projection (MFMA split-bf16, double-buffered gload_lds); k written pre-split
  k_mfma_qkv<<<dim3(12, 128), 256, 0, stream>>>(xh, xl, wqTh, wqTl, qf, kSh, kSl, vf);
  // 1b. v transpose+split for MFMA PV operand (overwrites xh/xl)
  k_vtrans<<<dim3(NTOK / 64, BH), 256, 0, stream>>>(vf, vTh, vTl);
  // 2. landmarks (+ split copies)
  k_land2<<<dim3(BH * MLM, 2), 64, 0, stream>>>(qf, kSh, kSl, qlf, klf, qlSh, qlSl, klSh, klSl);
  // 3. sim2 + softmax -> attn2
  k_sim2<<<dim3(4, 4, BH), 256, 0, stream>>>(qlf, klf, xz);
  k_softmax256<<<BH * MLM, 256, 0, stream>>>(xz, a2);
  // 4. pinv init (z0 also emits z^T split)
  k_colrow<<<BH, 256, 0, stream>>>(a2, part);
  k_z0<<<BH * MLM, 256, 0, stream>>>(a2, part, zb, zbTh, zbTl);
  // 5. 6 Newton-Schulz iterations (24 dispatches, 512-block prefetch GEMM, 3-term)
  {
    float* zc = zb;  unsigned short* zcTh = zbTh; unsigned short* zcTl = zbTl;
    float* zn = z2;  unsigned short* znTh = z2Th; unsigned short* znTl = z2Tl;
    for (int it = 0; it < 6; ++it){
      k_gemm256m<<<dim3(32, BH), 256, 0, stream>>>(a2, zcTh, zcTl, a2, xz, xzTh, xzTl, 0.f, -1.f, 1);
      k_gemm256m<<<dim3(32, BH), 256, 0, stream>>>(xz, xzTh, xzTl, xz, t2, t2Th, t2Tl, 7.f, 1.f, 0);
      k_gemm256m<<<dim3(32, BH), 256, 0, stream>>>(xz, t2Th, t2Tl, xz, t4, t4Th, t4Tl, 15.f, 1.f, 0);
      k_gemm256m<<<dim3(32, BH), 256, 0, stream>>>(zc, t4Th, t4Tl, zc, zn, znTh, znTl, 13.f, 0.25f, 1);
      float* tf = zc; zc = zn; zn = tf;
      unsigned short* th = zcTh; zcTh = znTh; znTh = th;
      unsigned short* tl = zcTl; zcTl = znTl; znTl = tl;
    }
  }
  const size_t FLASH_LDS = (size_t)4 * 64 * LP * 2;   // 36864 B
  const size_t ATTN1_LDS = (size_t)160 * 68 * 4;      // 43520 B (Vs conv buffer > P planes 36864)
  // 6. flash attn3@v (MFMA, all pre-split; kc split 16-way) + combine
  k_flash<<<dim3(16, 4, BH), 256, FLASH_LDS, stream>>>(qlSh, qlSl, kSh, kSl, vTh, vTl, pbuf);
  k_comb<<<BH * MLM / 4, 256, 0, stream>>>(pbuf, av);
  // 7. w2 = z_final @ av (final z lands in zb after 6 iters; + transposed split for attn1)
  k_w2<<<dim3(4, BH), 256, 0, stream>>>(zb, av, w2, w2Th, w2Tl);
  // 8. fused flash attn1 + conv (MFMA, 512 thr, K/W2 direct-from-L2, barrier-free jc loop)
  k_attn1<<<dim3(64, BH), 512, ATTN1_LDS, stream>>>(qf, klSh, klSl, vf, w2Th, w2Tl, wconv);
  // 9. output projection + residual (MFMA split-bf16)
  k_mfma_final<<<dim3(4, 128), 256, 0, stream>>>((const unsigned int*)qf, woTh, woTl, x, bout, outp);
}

// Round 11
// 677.634 us; speedup vs baseline: 1.0969x; 1.0969x over previous
//
#include <hip/hip_runtime.h>
#include <hip/hip_bf16.h>

#define BH 16
#define NTOK 8192
#define NHEAD 8
#define DH 64
#define MLM 256
#define QSCALE 0.125f
#define LP 72   // ushort stride for flash LDS tiles; MUST be >= 64 (row holds 64 ushorts of K-dim)
#define LOG2E 1.4426950408889634f

typedef unsigned short ushort_t;
using frag_ab = __attribute__((ext_vector_type(8))) short;   // 8 bf16 (4 VGPRs)
using frag_cd = __attribute__((ext_vector_type(4))) float;   // 4 fp32 acc

__device__ __forceinline__ unsigned short f2bs(float f){
  __hip_bfloat16 h = __float2bfloat16(f);
  return *(unsigned short*)&h;
}
__device__ __forceinline__ float bs2f(unsigned short u){
  union { unsigned int i; float f; } cv; cv.i = ((unsigned int)u) << 16; return cv.f;
}

// async global->LDS, 16B per lane.  LDS dest = wave-uniform base + lane*16 (HW).
__device__ __forceinline__ void gl_lds16(const unsigned short* g, unsigned short* l){
  __builtin_amdgcn_global_load_lds((const __attribute__((address_space(1))) unsigned int*)(const void*)g,
                                   (__attribute__((address_space(3))) unsigned int*)(void*)l, 16, 0, 0);
}

// ---------------- weight transpose + hi/lo bf16 split: in[K][N] -> outh/outl [N][K]
// swz!=0: pre-swizzle 16B slot within each 32-col K-group (slot ^= row&3) for gload_lds consumers
__global__ __launch_bounds__(256) void k_splitw(const float* __restrict__ in, int K, int N,
                                                unsigned short* __restrict__ oh,
                                                unsigned short* __restrict__ ol, int swz){
  const int idx = blockIdx.x * 256 + threadIdx.x;   // over N*K
  const int n = idx / K, k = idx - n * K;
  const float v = in[(size_t)k * N + n];
  const unsigned short hi = f2bs(v);
  int kd = k;
  if (swz){
    const int q = (k >> 3) & 3;
    kd = (k & ~31) | (((q ^ (n & 3)) & 3) << 3) | (k & 7);
  }
  oh[(size_t)n * K + kd] = hi;
  ol[(size_t)n * K + kd] = f2bs(v - bs2f(hi));
}

// ---------------- plain hi/lo split of x, PRE-SWIZZLED for gload_lds (slot ^= row&3)
__global__ __launch_bounds__(256) void k_splitx(const float* __restrict__ in,
                                                unsigned short* __restrict__ oh,
                                                unsigned short* __restrict__ ol){
  const size_t i4 = ((size_t)blockIdx.x * 256 + threadIdx.x) * 4;
  const int row = (int)(i4 >> 9);
  const int col = (int)(i4 & 511);
  const int q = (col >> 3) & 3;
  const int cd = (col & ~31) | (((q ^ (row & 3)) & 3) << 3) | (col & 7);
  const size_t o4 = ((size_t)row << 9) + cd;
  float4 v = *(const float4*)(in + i4);
  const unsigned short h0 = f2bs(v.x), h1 = f2bs(v.y), h2 = f2bs(v.z), h3 = f2bs(v.w);
  *(ushort4*)(oh + o4) = make_ushort4(h0, h1, h2, h3);
  *(ushort4*)(ol + o4) = make_ushort4(f2bs(v.x - bs2f(h0)), f2bs(v.y - bs2f(h1)),
                                      f2bs(v.z - bs2f(h2)), f2bs(v.w - bs2f(h3)));
}

// ---------------- MFMA split-bf16 GEMM: qkv.  A = x pre-split+swizzled [16384][512],
// B = wqkvT pre-split+swizzled [1536][512].  128x128 tile, 4 waves, 64x64 each.
// LDS DOUBLE-BUFFER 2-phase: stage(k+1) issued before MFMA(k); ONE barrier per K-step.
__global__ __launch_bounds__(256) void k_mfma_qkv(const unsigned short* __restrict__ xh,
                                                  const unsigned short* __restrict__ xl,
                                                  const unsigned short* __restrict__ bth,
                                                  const unsigned short* __restrict__ btl,
                                                  float* __restrict__ q,
                                                  unsigned short* __restrict__ kSh,
                                                  unsigned short* __restrict__ kSl,
                                                  float* __restrict__ v){
  const int n0 = blockIdx.x * 128;   // over 1536
  const int m0 = blockIdx.y * 128;   // over 16384
  __shared__ unsigned short SB[2][4 * 128 * 32];   // 2 buffers x {Ah,Al,Bh,Bl} planes
  const int tid = threadIdx.x;
  const int wave = tid >> 6, lane = tid & 63;
  const int wm = wave >> 1, wn = wave & 1;
  const int lr = lane & 15, quad = lane >> 4;
  const int cswz = ((quad ^ (lr & 3)) & 3) << 3;   // swizzled 8-ushort slot
  // staging: wave w owns plane w
  const unsigned short* gsrc = (wave == 0) ? xh : (wave == 1) ? xl : (wave == 2) ? bth : btl;
  const int R0 = (wave < 2) ? m0 : n0;
  const int lrow = lane >> 2, lslot = (lane & 3) << 3;
  const int pbase = wave * 4096;
  frag_cd acc[4][4];
#pragma unroll
  for (int mt = 0; mt < 4; mt++)
#pragma unroll
    for (int nt = 0; nt < 4; nt++){
      frag_cd z = {0.f, 0.f, 0.f, 0.f};
      acc[mt][nt] = z;
    }
  // prologue: stage k0=0 into buf 0
#pragma unroll
  for (int u = 0; u < 8; u++)
    gl_lds16(gsrc + (size_t)(R0 + u*16 + lrow) * 512 + lslot, &SB[0][pbase] + u * 512);
  __syncthreads();
  int cur = 0;
  for (int k0 = 0; k0 < 512; k0 += 32){
    // issue next K-step's loads into the other buffer (overlap with MFMA below)
    if (k0 + 32 < 512){
#pragma unroll
      for (int u = 0; u < 8; u++)
        gl_lds16(gsrc + (size_t)(R0 + u*16 + lrow) * 512 + k0 + 32 + lslot,
                 &SB[cur ^ 1][pbase] + u * 512);
    }
    const unsigned short* Ah = &SB[cur][0];
    const unsigned short* Al = &SB[cur][4096];
    const unsigned short* Bh = &SB[cur][8192];
    const unsigned short* Bl = &SB[cur][12288];
    frag_ab a_h[4], a_l[4], b_h[4], b_l[4];
#pragma unroll
    for (int t = 0; t < 4; t++){
      const int ar = (wm*64 + t*16 + lr) << 5;
      const int br = (wn*64 + t*16 + lr) << 5;
      a_h[t] = *(const frag_ab*)&Ah[ar + cswz];
      a_l[t] = *(const frag_ab*)&Al[ar + cswz];
      b_h[t] = *(const frag_ab*)&Bh[br + cswz];
      b_l[t] = *(const frag_ab*)&Bl[br + cswz];
    }
#pragma unroll
    for (int mt = 0; mt < 4; mt++)
#pragma unroll
      for (int nt = 0; nt < 4; nt++){
        acc[mt][nt] = __builtin_amdgcn_mfma_f32_16x16x32_bf16(a_l[mt], b_h[nt], acc[mt][nt], 0, 0, 0);
        acc[mt][nt] = __builtin_amdgcn_mfma_f32_16x16x32_bf16(a_h[mt], b_l[nt], acc[mt][nt], 0, 0, 0);
        acc[mt][nt] = __builtin_amdgcn_mfma_f32_16x16x32_bf16(a_h[mt], b_h[nt], acc[mt][nt], 0, 0, 0);
      }
    __syncthreads();   // drains vmcnt (next buffer landed) + everyone done reading cur
    cur ^= 1;
  }
  // epilogue: D row = quad*4+reg, col = lane&15
#pragma unroll
  for (int mt = 0; mt < 4; mt++)
#pragma unroll
    for (int nt = 0; nt < 4; nt++)
#pragma unroll
      for (int rg = 0; rg < 4; rg++){
        const int row = m0 + wm*64 + mt*16 + quad*4 + rg;
        const int col = n0 + wn*64 + nt*16 + lr;
        const int bb = row >> 13, i = row & 8191;
        const int which = col >> 9;
        const int cc = col & 511;
        const int h = cc >> 6, d = cc & 63;
        const size_t off = (((size_t)(bb * NHEAD + h)) * NTOK + i) * DH + d;
        const float val = acc[mt][nt][rg];
        if (which == 0)      q[off] = val * QSCALE;
        else if (which == 1){
          const unsigned short hi = f2bs(val);
          kSh[off] = hi; kSl[off] = f2bs(val - bs2f(hi));
        }
        else                 v[off] = val;
      }
}

// ---------------- MFMA split-bf16 GEMM: final.  A = oh packed (hi|lo in uint32 slots of qf,
// layout [bh][8192][64]), B = woutT hi/lo [512][512].  out = A@B + bout + x.
// A register-prefetched one K-step ahead (loads overlap MFMA).
__global__ __launch_bounds__(256) void k_mfma_final(const unsigned int* __restrict__ qpk,
                                                    const unsigned short* __restrict__ bth,
                                                    const unsigned short* __restrict__ btl,
                                                    const float* __restrict__ xin,
                                                    const float* __restrict__ bout,
                                                    float* __restrict__ outp){
  const int n0 = blockIdx.x * 128;   // over 512
  const int m0 = blockIdx.y * 128;   // over 16384
  __shared__ unsigned short Ah[128][40], Al[128][40], Bh[128][40], Bl[128][40];
  const int tid = threadIdx.x;
  const int wave = tid >> 6, lane = tid & 63;
  const int wm = wave >> 1, wn = wave & 1;
  const int lr = lane & 15, quad = lane >> 4, koff = quad * 8;
  const int bb = m0 >> 13;
  frag_cd acc[4][4];
#pragma unroll
  for (int mt = 0; mt < 4; mt++)
#pragma unroll
    for (int nt = 0; nt < 4; nt++){
      frag_cd z = {0.f, 0.f, 0.f, 0.f};
      acc[mt][nt] = z;
    }
  const int arow = tid >> 3, ac4 = (tid & 7) << 2;     // A: 4 slots of 32 rows
  const int brow = tid >> 2, bch = (tid & 3) << 3;     // B: 2 slots of 64 rows
  uint4 pw[4];
  // prologue: prefetch A regs for k0=0
#pragma unroll
  for (int u = 0; u < 4; u++){
    const int row = arow + u * 32;
    const int i = (m0 + row) & 8191;
    pw[u] = *(const uint4*)(qpk + (((size_t)(bb * NHEAD + 0)) * NTOK + i) * DH + 0 + ac4);
  }
  for (int k0 = 0; k0 < 512; k0 += 32){
    __syncthreads();
    // write LDS from prefetched A regs
#pragma unroll
    for (int u = 0; u < 4; u++){
      const int row = arow + u * 32;
      *(ushort4*)&Ah[row][ac4] = make_ushort4((unsigned short)pw[u].x, (unsigned short)pw[u].y,
                                              (unsigned short)pw[u].z, (unsigned short)pw[u].w);
      *(ushort4*)&Al[row][ac4] = make_ushort4((unsigned short)(pw[u].x >> 16), (unsigned short)(pw[u].y >> 16),
                                              (unsigned short)(pw[u].z >> 16), (unsigned short)(pw[u].w >> 16));
    }
    // stage B (pre-split copies, L2-hot)
#pragma unroll
    for (int u = 0; u < 2; u++){
      const int row = brow + u * 64;
      *(uint4*)&Bh[row][bch] = *(const uint4*)(bth + (size_t)(n0 + row) * 512 + k0 + bch);
      *(uint4*)&Bl[row][bch] = *(const uint4*)(btl + (size_t)(n0 + row) * 512 + k0 + bch);
    }
    __syncthreads();
    // prefetch A regs for k0+32 (loads in flight during MFMA)
    if (k0 + 32 < 512){
      const int hn = (k0 + 32) >> 6, dbn = (k0 + 32) & 63;
#pragma unroll
      for (int u = 0; u < 4; u++){
        const int row = arow + u * 32;
        const int i = (m0 + row) & 8191;
        pw[u] = *(const uint4*)(qpk + (((size_t)(bb * NHEAD + hn)) * NTOK + i) * DH + dbn + ac4);
      }
    }
    frag_ab a_h[4], a_l[4], b_h[4], b_l[4];
#pragma unroll
    for (int t = 0; t < 4; t++){
      a_h[t] = *(const frag_ab*)&Ah[wm*64 + t*16 + lr][koff];
      a_l[t] = *(const frag_ab*)&Al[wm*64 + t*16 + lr][koff];
      b_h[t] = *(const frag_ab*)&Bh[wn*64 + t*16 + lr][koff];
      b_l[t] = *(const frag_ab*)&Bl[wn*64 + t*16 + lr][koff];
    }
#pragma unroll
    for (int mt = 0; mt < 4; mt++)
#pragma unroll
      for (int nt = 0; nt < 4; nt++){
        acc[mt][nt] = __builtin_amdgcn_mfma_f32_16x16x32_bf16(a_l[mt], b_h[nt], acc[mt][nt], 0, 0, 0);
        acc[mt][nt] = __builtin_amdgcn_mfma_f32_16x16x32_bf16(a_h[mt], b_l[nt], acc[mt][nt], 0, 0, 0);
        acc[mt][nt] = __builtin_amdgcn_mfma_f32_16x16x32_bf16(a_h[mt], b_h[nt], acc[mt][nt], 0, 0, 0);
      }
  }
#pragma unroll
  for (int mt = 0; mt < 4; mt++)
#pragma unroll
    for (int nt = 0; nt < 4; nt++)
#pragma unroll
      for (int rg = 0; rg < 4; rg++){
        const int row = m0 + wm*64 + mt*16 + quad*4 + rg;
        const int col = n0 + wn*64 + nt*16 + lr;
        outp[(size_t)row * 512 + col] = acc[mt][nt][rg] + bout[col] + xin[(size_t)row * 512 + col];
      }
}

// ---------------- landmark means for q and k in one launch (grid.y selects)
// k is read from pre-split planes; also emits hi/lo bf16 split copies
__global__ __launch_bounds__(64) void k_land2(const float* __restrict__ qf,
                                              const unsigned short* __restrict__ kSh,
                                              const unsigned short* __restrict__ kSl,
                                              float* __restrict__ qlf, float* __restrict__ klf,
                                              unsigned short* __restrict__ qlSh, unsigned short* __restrict__ qlSl,
                                              unsigned short* __restrict__ klSh, unsigned short* __restrict__ klSl){
  const int isK = blockIdx.y;
  float* dst = isK ? klf : qlf;
  unsigned short* dh = isK ? klSh : qlSh;
  unsigned short* dl = isK ? klSl : qlSl;
  const int bh = blockIdx.x >> 8;
  const int j  = blockIdx.x & 255;
  const int d  = threadIdx.x;
  const size_t base = ((size_t)bh * NTOK + (size_t)j * 32) * DH + d;
  float s = 0.f;
  if (!isK){
    const float* p = qf + base;
#pragma unroll
    for (int t = 0; t < 32; t++) s += p[t * DH];
  } else {
    const unsigned short* ph = kSh + base;
    const unsigned short* pl = kSl + base;
#pragma unroll
    for (int t = 0; t < 32; t++) s += bs2f(ph[t * DH]) + bs2f(pl[t * DH]);
  }
  const float val = s * (1.f / 32.f);
  const size_t oidx = ((size_t)bh * MLM + j) * DH + d;
  dst[oidx] = val;
  const unsigned short hi = f2bs(val);
  dh[oidx] = hi;
  dl[oidx] = f2bs(val - bs2f(hi));
}

// ---------------- transpose + split v: [bh][8192][64] fp32 -> vTh/vTl [bh][64][8192] bf16
__global__ __launch_bounds__(256) void k_vtrans(const float* __restrict__ vf,
                                                unsigned short* __restrict__ vTh,
                                                unsigned short* __restrict__ vTl){
  __shared__ float T[64][68];
  const int j0 = blockIdx.x * 64, bh = blockIdx.y;
  const int tid = threadIdx.x;
#pragma unroll
  for (int u = 0; u < 4; u++){
    const int f = tid + u * 256, row = f >> 4, c4 = (f & 15) << 2;
    *(float4*)&T[row][c4] = *(const float4*)(vf + ((size_t)bh * NTOK + j0 + row) * DH + c4);
  }
  __syncthreads();
#pragma unroll
  for (int u = 0; u < 4; u++){
    const int f = tid + u * 256, d = f >> 4, j4 = (f & 15) << 2;
    const float v0 = T[j4+0][d], v1 = T[j4+1][d], v2 = T[j4+2][d], v3 = T[j4+3][d];
    const unsigned short h0 = f2bs(v0), h1 = f2bs(v1), h2 = f2bs(v2), h3 = f2bs(v3);
    const size_t off = ((size_t)bh * DH + d) * NTOK + j0 + j4;
    *(ushort4*)(vTh + off) = make_ushort4(h0, h1, h2, h3);
    *(ushort4*)(vTl + off) = make_ushort4(f2bs(v0 - bs2f(h0)), f2bs(v1 - bs2f(h1)),
                                          f2bs(v2 - bs2f(h2)), f2bs(v3 - bs2f(h3)));
  }
}

// ---------------- sim2 = ql @ kl^T (fp32, K=64), batched [bh][256][256]
__global__ __launch_bounds__(256) void k_sim2(const float* __restrict__ qlf,
                                              const float* __restrict__ klf,
                                              float* __restrict__ C){
  const int bh = blockIdx.z;
  const float* Ab = qlf + (size_t)bh * MLM * DH;
  const float* Bb = klf + (size_t)bh * MLM * DH;
  float* Cb = C + (size_t)bh * MLM * MLM;
  const int n0 = blockIdx.x * 64;
  const int m0 = blockIdx.y * 64;
  __shared__ float As[16][64];
  __shared__ float Bs[16][64];
  const int tid = threadIdx.x, ty = tid >> 4, tx = tid & 15;
  const int lm = tid >> 2, lk = (tid & 3) << 2;
  float acc[4][4] = {};
  for (int k0 = 0; k0 < 64; k0 += 16){
    float4 a4 = *(const float4*)(Ab + (size_t)(m0 + lm) * DH + k0 + lk);
    As[lk+0][lm] = a4.x; As[lk+1][lm] = a4.y; As[lk+2][lm] = a4.z; As[lk+3][lm] = a4.w;
    float4 b4 = *(const float4*)(Bb + (size_t)(n0 + lm) * DH + k0 + lk);
    Bs[lk+0][lm] = b4.x; Bs[lk+1][lm] = b4.y; Bs[lk+2][lm] = b4.z; Bs[lk+3][lm] = b4.w;
    __syncthreads();
#pragma unroll
    for (int kk = 0; kk < 16; kk++){
      float a[4], bv[4];
#pragma unroll
      for (int r = 0; r < 4; r++) a[r] = As[kk][ty*4 + r];
#pragma unroll
      for (int c = 0; c < 4; c++) bv[c] = Bs[kk][tx*4 + c];
#pragma unroll
      for (int r = 0; r < 4; r++)
#pragma unroll
        for (int c = 0; c < 4; c++) acc[r][c] += a[r] * bv[c];
    }
    __syncthreads();
  }
#pragma unroll
  for (int r = 0; r < 4; r++)
#pragma unroll
    for (int c = 0; c < 4; c++)
      Cb[(size_t)(m0 + ty*4 + r) * MLM + n0 + tx*4 + c] = acc[r][c];
}

// ---------------- row softmax over 256
__global__ __launch_bounds__(256) void k_softmax256(const float* __restrict__ in, float* __restrict__ outp){
  const int row = blockIdx.x;
  const int t = threadIdx.x;
  float v = in[(size_t)row * 256 + t];
  __shared__ float red[256];
  red[t] = v; __syncthreads();
  for (int o = 128; o > 0; o >>= 1){ if (t < o) red[t] = fmaxf(red[t], red[t+o]); __syncthreads(); }
  float mx = red[0]; __syncthreads();
  float e = exp2f((v - mx) * LOG2E);
  red[t] = e; __syncthreads();
  for (int o = 128; o > 0; o >>= 1){ if (t < o) red[t] += red[t+o]; __syncthreads(); }
  outp[(size_t)row * 256 + t] = e / red[0];
}

// ---------------- per-batch COLUMN abs-sum maxima (row-sums of softmax are exactly 1)
__global__ __launch_bounds__(256) void k_colrow(const float* __restrict__ a2, float* __restrict__ part){
  const int bh = blockIdx.x;
  const int t = threadIdx.x;
  const float* p = a2 + (size_t)bh * 65536;
  float cs = 0.f;
  for (int i = 0; i < 256; i++) cs += fabsf(p[(size_t)i * 256 + t]);
  __shared__ float r2[256];
  r2[t] = cs; __syncthreads();
  for (int o = 128; o > 0; o >>= 1){
    if (t < o) r2[t] = fmaxf(r2[t], r2[t+o]);
    __syncthreads();
  }
  if (t == 0) part[bh] = r2[0];
}

// ---------------- z0 = a2^T * (1/(col*row)); col==1 so sc = 1/max_colsum
// also emits z^T pre-split (= a2 scaled, no transpose needed)
__global__ __launch_bounds__(256) void k_z0(const float* __restrict__ a2, const float* __restrict__ part,
                                            float* __restrict__ z,
                                            unsigned short* __restrict__ zTh,
                                            unsigned short* __restrict__ zTl){
  const int bh = blockIdx.x >> 8;
  const int i  = blockIdx.x & 255;
  const int j  = threadIdx.x;
  float m2 = 0.f;
#pragma unroll
  for (int t = 0; t < 16; t++) m2 = fmaxf(m2, part[t]);
  const float sc = 1.f / m2;
  const size_t ridx = ((size_t)bh * 256 + j) * 256 + i;
  const float val = a2[ridx] * sc;
  z[((size_t)bh * 256 + i) * 256 + j] = val;
  const unsigned short hi = f2bs(val);
  zTh[ridx] = hi;
  zTl[ridx] = f2bs(val - bs2f(hi));
}

// ---------------- batched 256^3 MFMA split-bf16 GEMM (NS chain step):
// C = s0*(c0*D - A@B), B pre-transposed+split.  32x64 tile -> 512 blocks (2/CU),
// register prefetch double-buffer, 3-term split, LDS-transposed coalesced C^T epilogue.
__global__ __launch_bounds__(256) void k_gemm256m(const float* __restrict__ A,
                                                  const unsigned short* __restrict__ BTh,
                                                  const unsigned short* __restrict__ BTl,
                                                  const float* __restrict__ D,
                                                  float* __restrict__ C,
                                                  unsigned short* __restrict__ CTh,
                                                  unsigned short* __restrict__ CTl,
                                                  float c0, float s0, int wC){
  __shared__ unsigned short Ah[32][40], Al[32][40], Bh[64][40], Bl[64][40];
  __shared__ float Ct[64][33];
  const int bh = blockIdx.y, tile = blockIdx.x;
  const int m0 = (tile >> 2) * 32, n0 = (tile & 3) * 64;
  const size_t bo = (size_t)bh * 65536;
  const int tid = threadIdx.x;
  const int wave = tid >> 6, lane = tid & 63;
  const int wm = wave >> 1, wn = wave & 1;
  const int lr = lane & 15, quad = lane >> 4, koff = quad * 8;
  const int ar = tid >> 3, ac = (tid & 7) << 2;     // A tile: 32 rows x 32 cols fp32
  const int br = tid >> 2, bc = (tid & 3) << 3;     // B tile: 64 rows x 32 cols ushort
  frag_cd acc[2];
  { frag_cd z = {0.f,0.f,0.f,0.f}; acc[0] = z; acc[1] = z; }
  float4 ra  = *(const float4*)(A + bo + (size_t)(m0 + ar) * 256 + ac);
  uint4  rbh = *(const uint4*)(BTh + bo + (size_t)(n0 + br) * 256 + bc);
  uint4  rbl = *(const uint4*)(BTl + bo + (size_t)(n0 + br) * 256 + bc);
  for (int k0 = 0; k0 < 256; k0 += 32){
    __syncthreads();
    {
      const unsigned short h0=f2bs(ra.x),h1=f2bs(ra.y),h2=f2bs(ra.z),h3=f2bs(ra.w);
      *(ushort4*)&Ah[ar][ac] = make_ushort4(h0,h1,h2,h3);
      *(ushort4*)&Al[ar][ac] = make_ushort4(f2bs(ra.x-bs2f(h0)), f2bs(ra.y-bs2f(h1)),
                                            f2bs(ra.z-bs2f(h2)), f2bs(ra.w-bs2f(h3)));
      *(uint4*)&Bh[br][bc] = rbh;
      *(uint4*)&Bl[br][bc] = rbl;
    }
    __syncthreads();
    if (k0 < 224){
      ra  = *(const float4*)(A + bo + (size_t)(m0 + ar) * 256 + k0 + 32 + ac);
      rbh = *(const uint4*)(BTh + bo + (size_t)(n0 + br) * 256 + k0 + 32 + bc);
      rbl = *(const uint4*)(BTl + bo + (size_t)(n0 + br) * 256 + k0 + 32 + bc);
    }
    frag_ab a_h = *(const frag_ab*)&Ah[wm*16 + lr][koff];
    frag_ab a_l = *(const frag_ab*)&Al[wm*16 + lr][koff];
#pragma unroll
    for (int b = 0; b < 2; b++){
      frag_ab b_h = *(const frag_ab*)&Bh[wn*32 + b*16 + lr][koff];
      frag_ab b_l = *(const frag_ab*)&Bl[wn*32 + b*16 + lr][koff];
      acc[b] = __builtin_amdgcn_mfma_f32_16x16x32_bf16(a_l, b_h, acc[b], 0, 0, 0);
      acc[b] = __builtin_amdgcn_mfma_f32_16x16x32_bf16(a_h, b_l, acc[b], 0, 0, 0);
      acc[b] = __builtin_amdgcn_mfma_f32_16x16x32_bf16(a_h, b_h, acc[b], 0, 0, 0);
    }
  }
  // epilogue: fp32 C direct; C^T via LDS transpose for coalesced split writes
  const bool useD = (c0 != 0.f);
#pragma unroll
  for (int b = 0; b < 2; b++)
#pragma unroll
    for (int rg = 0; rg < 4; rg++){
      const int row = m0 + wm*16 + quad*4 + rg;
      const int col = n0 + wn*32 + b*16 + lr;
      const size_t idx = bo + (size_t)row * 256 + col;
      const float dv = useD ? D[idx] : 0.f;
      const float val = s0 * (c0 * dv - acc[b][rg]);
      if (wC) C[idx] = val;
      Ct[col - n0][row - m0] = val;
    }
  __syncthreads();
  {
    const int cr = tid >> 2, sg = (tid & 3) << 3;
    unsigned int ph[4], pl[4];
#pragma unroll
    for (int j = 0; j < 4; j++){
      const float v0 = Ct[cr][sg + 2*j], v1 = Ct[cr][sg + 2*j + 1];
      const unsigned short h0 = f2bs(v0), h1 = f2bs(v1);
      ph[j] = (unsigned int)h0 | ((unsigned int)h1 << 16);
      pl[j] = (unsigned int)f2bs(v0 - bs2f(h0)) | ((unsigned int)f2bs(v1 - bs2f(h1)) << 16);
    }
    const size_t tb = bo + (size_t)(n0 + cr) * 256 + m0 + sg;
    *(uint4*)(CTh + tb) = make_uint4(ph[0], ph[1], ph[2], ph[3]);
    *(uint4*)(CTl + tb) = make_uint4(pl[0], pl[1], pl[2], pl[3]);
  }
}

// ---------------- flash (MFMA split-bf16): partial online-softmax (attn3 @ v) per (kc, mtile, bh)
// 4 waves, each owns 16 q-rows x full 64-col chunk.  Q lifted to registers; P aliases K planes.
// LDS = 4 planes (36864 B).  kc split 16-way.  exp2 softmax.
__global__ __launch_bounds__(256) void k_flash(const unsigned short* __restrict__ qlSh,
                                               const unsigned short* __restrict__ qlSl,
                                               const unsigned short* __restrict__ kSh,
                                               const unsigned short* __restrict__ kSl,
                                               const unsigned short* __restrict__ vTh,
                                               const unsigned short* __restrict__ vTl,
                                               float* __restrict__ pbuf){
  extern __shared__ __align__(16) unsigned short sm[];
  unsigned short* Kh  = sm;                 // Q staging, then K, then P (hi)
  unsigned short* Kl  = sm + 1*64*LP;       // Q staging, then K, then P (lo)
  unsigned short* Wth = sm + 2*64*LP;
  unsigned short* Wtl = sm + 3*64*LP;
  const int kc = blockIdx.x, mt = blockIdx.y, bh = blockIdx.z;
  const int m0 = mt * 64, kbeg = kc * 512;
  const int tid = threadIdx.x;
  const int wave = tid >> 6, lane = tid & 63;
  const int lr = lane & 15, quad = lane >> 4;
  const size_t qbase = (size_t)bh * MLM * DH;
  const size_t kb  = (size_t)bh * NTOK * DH;
  const size_t vtb = (size_t)bh * DH * NTOK;
  // prologue: stage Q through K planes, lift own-wave fragments to registers
#pragma unroll
  for (int u = 0; u < 4; u++){
    const int f = tid + u * 256, row = f >> 4, c4 = (f & 15) << 2;
    *(ushort4*)&Kh[row*LP + c4] = *(const ushort4*)(qlSh + qbase + (size_t)(m0 + row) * DH + c4);
    *(ushort4*)&Kl[row*LP + c4] = *(const ushort4*)(qlSl + qbase + (size_t)(m0 + row) * DH + c4);
  }
  __syncthreads();
  frag_ab qa_h[2], qa_l[2];
#pragma unroll
  for (int ks = 0; ks < 2; ks++){
    const int ao = (wave*16 + lr)*LP + ks*32 + quad*8;
    qa_h[ks] = *(const frag_ab*)&Kh[ao];
    qa_l[ks] = *(const frag_ab*)&Kl[ao];
  }
  float m_run[4], l_run[4];
  frag_cd o[4];
#pragma unroll
  for (int r = 0; r < 4; r++){ m_run[r] = -1e30f; l_run[r] = 0.f; }
#pragma unroll
  for (int nt = 0; nt < 4; nt++){ frag_cd z = {0.f,0.f,0.f,0.f}; o[nt] = z; }

  for (int ch = 0; ch < 8; ch++){
    const int kr0 = kbeg + ch * 64;
    __syncthreads();   // prev PV done (and Q frag reads done on first iter)
    // stage K chunk and V^T chunk (all pre-split copies)
#pragma unroll
    for (int u = 0; u < 4; u++){
      const int f = tid + u * 256, row = f >> 4, c4 = (f & 15) << 2;
      *(ushort4*)&Kh[row*LP + c4]  = *(const ushort4*)(kSh + kb + (size_t)(kr0 + row) * DH + c4);
      *(ushort4*)&Kl[row*LP + c4]  = *(const ushort4*)(kSl + kb + (size_t)(kr0 + row) * DH + c4);
      *(ushort4*)&Wth[row*LP + c4] = *(const ushort4*)(vTh + vtb + (size_t)row * NTOK + kr0 + c4);
      *(ushort4*)&Wtl[row*LP + c4] = *(const ushort4*)(vTl + vtb + (size_t)row * NTOK + kr0 + c4);
    }
    __syncthreads();
    // S = Q @ K^T  (3-term split, Q from registers)
    frag_cd s[4];
#pragma unroll
    for (int nt = 0; nt < 4; nt++){ frag_cd z = {0.f,0.f,0.f,0.f}; s[nt] = z; }
#pragma unroll
    for (int ks = 0; ks < 2; ks++){
#pragma unroll
      for (int nt = 0; nt < 4; nt++){
        const int bo = (nt*16 + lr)*LP + ks*32 + quad*8;
        frag_ab b_h = *(const frag_ab*)&Kh[bo];
        frag_ab b_l = *(const frag_ab*)&Kl[bo];
        s[nt] = __builtin_amdgcn_mfma_f32_16x16x32_bf16(qa_l[ks], b_h, s[nt], 0, 0, 0);
        s[nt] = __builtin_amdgcn_mfma_f32_16x16x32_bf16(qa_h[ks], b_l, s[nt], 0, 0, 0);
        s[nt] = __builtin_amdgcn_mfma_f32_16x16x32_bf16(qa_h[ks], b_h, s[nt], 0, 0, 0);
      }
    }
    __syncthreads();   // all cross-wave K reads complete before P overwrites K planes
    // online softmax (exp2); P written into K planes (own-wave rows only)
#pragma unroll
    for (int rg = 0; rg < 4; rg++){
      float mx = fmaxf(fmaxf(s[0][rg], s[1][rg]), fmaxf(s[2][rg], s[3][rg]));
#pragma unroll
      for (int o2 = 8; o2 >= 1; o2 >>= 1) mx = fmaxf(mx, __shfl_xor(mx, o2));
      const float mnew = fmaxf(m_run[rg], mx);
      float e0 = exp2f((s[0][rg] - mnew) * LOG2E), e1 = exp2f((s[1][rg] - mnew) * LOG2E);
      float e2 = exp2f((s[2][rg] - mnew) * LOG2E), e3 = exp2f((s[3][rg] - mnew) * LOG2E);
      float psum = e0 + e1 + e2 + e3;
#pragma unroll
      for (int o2 = 8; o2 >= 1; o2 >>= 1) psum += __shfl_xor(psum, o2);
      const float alpha = exp2f((m_run[rg] - mnew) * LOG2E);
      l_run[rg] = l_run[rg] * alpha + psum;
      m_run[rg] = mnew;
#pragma unroll
      for (int nt = 0; nt < 4; nt++) o[nt][rg] *= alpha;
      const int prow = (wave*16 + quad*4 + rg) * LP;
      float ee[4] = {e0, e1, e2, e3};
#pragma unroll
      for (int nt = 0; nt < 4; nt++){
        const unsigned short hh = f2bs(ee[nt]);
        Kh[prow + nt*16 + lr] = hh;
        Kl[prow + nt*16 + lr] = f2bs(ee[nt] - bs2f(hh));
      }
    }
    // O += P @ V   (P own-wave rows from K planes; V^T cross-wave from W planes)
#pragma unroll
    for (int ks = 0; ks < 2; ks++){
      const int ao = (wave*16 + lr)*LP + ks*32 + quad*8;
      frag_ab p_h = *(const frag_ab*)&Kh[ao];
      frag_ab p_l = *(const frag_ab*)&Kl[ao];
#pragma unroll
      for (int nt = 0; nt < 4; nt++){
        const int bo = (nt*16 + lr)*LP + ks*32 + quad*8;
        frag_ab b_h = *(const frag_ab*)&Wth[bo];
        frag_ab b_l = *(const frag_ab*)&Wtl[bo];
        o[nt] = __builtin_amdgcn_mfma_f32_16x16x32_bf16(p_l, b_h, o[nt], 0, 0, 0);
        o[nt] = __builtin_amdgcn_mfma_f32_16x16x32_bf16(p_h, b_l, o[nt], 0, 0, 0);
        o[nt] = __builtin_amdgcn_mfma_f32_16x16x32_bf16(p_h, b_h, o[nt], 0, 0, 0);
      }
    }
  }
  // epilogue: unnormalized o + (m,l) partials, layout compatible with k_comb
  float* pb = pbuf + (((size_t)bh * 16 + kc) * 256 + m0) * 68;
#pragma unroll
  for (int rg = 0; rg < 4; rg++){
    const int row = wave*16 + quad*4 + rg;
#pragma unroll
    for (int nt = 0; nt < 4; nt++)
      pb[(size_t)row * 68 + nt*16 + lr] = o[nt][rg];
    if (lr == 0){
      pb[(size_t)row * 68 + 64] = m_run[rg];
      pb[(size_t)row * 68 + 65] = l_run[rg];
    }
  }
}

// ---------------- combine flash partials (16) -> av fp32 [bh][256][64]
__global__ __launch_bounds__(256) void k_comb(const float* __restrict__ pbuf, float* __restrict__ av){
  const int wv = threadIdx.x >> 6, lane = threadIdx.x & 63;
  const int id = blockIdx.x * 4 + wv;
  const int bh = id >> 8, row = id & 255;
  const float* base = pbuf + ((size_t)bh * 16 * 256 + row) * 68;
  float M = -1e30f;
#pragma unroll
  for (int k = 0; k < 16; k++) M = fmaxf(M, base[(size_t)k * 256 * 68 + 64]);
  float L = 0.f, o = 0.f;
#pragma unroll
  for (int k = 0; k < 16; k++){
    const float* p = base + (size_t)k * 256 * 68;
    float w = exp2f((p[64] - M) * LOG2E);
    L += p[65] * w;
    o += p[lane] * w;
  }
  av[((size_t)bh * MLM + row) * DH + lane] = o / L;
}

// ---------------- w2 = z_final @ av (fp32, M=256,N=64,K=256), batched
// also emits transposed hi/lo split w2T [bh][64][256] for the MFMA attn1 PV operand
__global__ __launch_bounds__(256) void k_w2(const float* __restrict__ Z, const float* __restrict__ AV,
                                            float* __restrict__ W2,
                                            unsigned short* __restrict__ w2Th,
                                            unsigned short* __restrict__ w2Tl){
  const int bh = blockIdx.y, mt = blockIdx.x;
  const float* Zb = Z + (size_t)bh * 65536;
  const float* Vb = AV + (size_t)bh * MLM * DH;
  float* Wb = W2 + (size_t)bh * MLM * DH;
  const int m0 = mt * 64;
  __shared__ float As[16][64];
  __shared__ float Bs[16][64];
  const int tid = threadIdx.x, ty = tid >> 4, tx = tid & 15;
  const int lm = tid >> 2, lk = (tid & 3) << 2;
  const int lk2 = tid >> 4, ln = (tid & 15) << 2;
  float acc[4][4] = {};
  for (int k0 = 0; k0 < 256; k0 += 16){
    float4 a4 = *(const float4*)(Zb + (size_t)(m0 + lm) * 256 + k0 + lk);
    As[lk+0][lm] = a4.x; As[lk+1][lm] = a4.y; As[lk+2][lm] = a4.z; As[lk+3][lm] = a4.w;
    float4 b4 = *(const float4*)(Vb + (size_t)(k0 + lk2) * DH + ln);
    *(float4*)&Bs[lk2][ln] = b4;
    __syncthreads();
#pragma unroll
    for (int kk = 0; kk < 16; kk++){
      float a[4], bv[4];
#pragma unroll
      for (int r = 0; r < 4; r++) a[r] = As[kk][ty*4 + r];
#pragma unroll
      for (int c = 0; c < 4; c++) bv[c] = Bs[kk][tx*4 + c];
#pragma unroll
      for (int r = 0; r < 4; r++)
#pragma unroll
        for (int c = 0; c < 4; c++) acc[r][c] += a[r] * bv[c];
    }
    __syncthreads();
  }
#pragma unroll
  for (int r = 0; r < 4; r++)
#pragma unroll
    for (int c = 0; c < 4; c++){
      const float val = acc[r][c];
      Wb[(size_t)(m0 + ty*4 + r) * DH + tx*4 + c] = val;
      const unsigned short hi = f2bs(val);
      const size_t tidx = ((size_t)bh * DH + tx*4 + c) * MLM + m0 + ty*4 + r;
      w2Th[tidx] = hi;
      w2Tl[tidx] = f2bs(val - bs2f(hi));
    }
}

// ---------------- fused attn1 (MFMA split-bf16): 512 threads / 8 waves, 128-row q tiles.
// Q fragments direct from global; K/W2 4 planes [64][LP]; P dedicated 2 planes [128][LP].
// exp2 softmax.  Output packed (hi|lo) bf16 IN PLACE over q.
__global__ __launch_bounds__(512) void k_attn1(float* __restrict__ qoh,
                                               const unsigned short* __restrict__ klSh,
                                               const unsigned short* __restrict__ klSl,
                                               const float* __restrict__ vf,
                                               const unsigned short* __restrict__ w2Th,
                                               const unsigned short* __restrict__ w2Tl,
                                               const float* __restrict__ wconv){
  extern __shared__ __align__(16) unsigned short sm[];
  unsigned short* Kh  = sm;                 // [64][LP]
  unsigned short* Kl  = sm + 1*64*LP;
  unsigned short* Wth = sm + 2*64*LP;
  unsigned short* Wtl = sm + 3*64*LP;
  unsigned short* Ph  = sm + 4*64*LP;       // [128][LP]
  unsigned short* Pl  = sm + 6*64*LP;       // [128][LP]
  float (*Vs)[68] = (float (*)[68])sm;      // conv phase: [160][68] = 43520 B
  float (*St)[68] = (float (*)[68])sm;      // pack phase: [128][68] = 34816 B
  __shared__ float wcs[33];
  const int it = blockIdx.x, bh = blockIdx.y, h = bh & 7;
  const int i0 = it * 128;
  float* qb = qoh + (size_t)bh * NTOK * DH;
  const int tid = threadIdx.x;
  const int wave = tid >> 6, lane = tid & 63;
  const int lr = lane & 15, quad = lane >> 4;
  if (tid < 33) wcs[tid] = wconv[h*33 + tid];
  // prologue: Q fragments direct from global (fp32 -> split in registers)
  frag_ab qa_h[2], qa_l[2];
#pragma unroll
  for (int ks = 0; ks < 2; ks++){
    const float* qsrc = qb + (size_t)(i0 + wave*16 + lr) * DH + ks*32 + quad*8;
    float4 a0 = *(const float4*)qsrc;
    float4 a1 = *(const float4*)(qsrc + 4);
    float vv[8] = {a0.x, a0.y, a0.z, a0.w, a1.x, a1.y, a1.z, a1.w};
    frag_ab fh, fl;
#pragma unroll
    for (int j = 0; j < 8; j++){
      const unsigned short hb = f2bs(vv[j]);
      fh[j] = (short)hb;
      fl[j] = (short)f2bs(vv[j] - bs2f(hb));
    }
    qa_h[ks] = fh; qa_l[ks] = fl;
  }
  float m_run[4], l_run[4];
  frag_cd o[4];
#pragma unroll
  for (int r = 0; r < 4; r++){ m_run[r] = -1e30f; l_run[r] = 0.f; }
#pragma unroll
  for (int nt = 0; nt < 4; nt++){ frag_cd z = {0.f,0.f,0.f,0.f}; o[nt] = z; }
  const size_t klbase = (size_t)bh * MLM * DH;
  const size_t wtbase = (size_t)bh * DH * MLM;

  for (int jc = 0; jc < 4; jc++){
    const int j0 = jc * 64;
    __syncthreads();   // prev iter's K/W reads done before restage
    // stage K_l chunk and W2^T chunk (512 threads, 2 slots each)
#pragma unroll
    for (int u = 0; u < 2; u++){
      const int f = tid + u * 512, row = f >> 4, c4 = (f & 15) << 2;
      *(ushort4*)&Kh[row*LP + c4]  = *(const ushort4*)(klSh + klbase + (size_t)(j0 + row) * DH + c4);
      *(ushort4*)&Kl[row*LP + c4]  = *(const ushort4*)(klSl + klbase + (size_t)(j0 + row) * DH + c4);
      *(ushort4*)&Wth[row*LP + c4] = *(const ushort4*)(w2Th + wtbase + (size_t)row * MLM + j0 + c4);
      *(ushort4*)&Wtl[row*LP + c4] = *(const ushort4*)(w2Tl + wtbase + (size_t)row * MLM + j0 + c4);
    }
    __syncthreads();
    // S = Q @ K_l^T  (Q from registers)
    frag_cd s[4];
#pragma unroll
    for (int nt = 0; nt < 4; nt++){ frag_cd z = {0.f,0.f,0.f,0.f}; s[nt] = z; }
#pragma unroll
    for (int ks = 0; ks < 2; ks++){
#pragma unroll
      for (int nt = 0; nt < 4; nt++){
        const int bo = (nt*16 + lr)*LP + ks*32 + quad*8;
        frag_ab b_h = *(const frag_ab*)&Kh[bo];
        frag_ab b_l = *(const frag_ab*)&Kl[bo];
        s[nt] = __builtin_amdgcn_mfma_f32_16x16x32_bf16(qa_l[ks], b_h, s[nt], 0, 0, 0);
        s[nt] = __builtin_amdgcn_mfma_f32_16x16x32_bf16(qa_h[ks], b_l, s[nt], 0, 0, 0);
        s[nt] = __builtin_amdgcn_mfma_f32_16x16x32_bf16(qa_h[ks], b_h, s[nt], 0, 0, 0);
      }
    }
    // online softmax (exp2); P into dedicated planes (wave-private rows, no barrier needed)
#pragma unroll
    for (int rg = 0; rg < 4; rg++){
      float mx = fmaxf(fmaxf(s[0][rg], s[1][rg]), fmaxf(s[2][rg], s[3][rg]));
#pragma unroll
      for (int o2 = 8; o2 >= 1; o2 >>= 1) mx = fmaxf(mx, __shfl_xor(mx, o2));
      const float mnew = fmaxf(m_run[rg], mx);
      float e0 = exp2f((s[0][rg] - mnew) * LOG2E), e1 = exp2f((s[1][rg] - mnew) * LOG2E);
      float e2 = exp2f((s[2][rg] - mnew) * LOG2E), e3 = exp2f((s[3][rg] - mnew) * LOG2E);
      float psum = e0 + e1 + e2 + e3;
#pragma unroll
      for (int o2 = 8; o2 >= 1; o2 >>= 1) psum += __shfl_xor(psum, o2);
      const float alpha = exp2f((m_run[rg] - mnew) * LOG2E);
      l_run[rg] = l_run[rg] * alpha + psum;
      m_run[rg] = mnew;
#pragma unroll
      for (int nt = 0; nt < 4; nt++) o[nt][rg] *= alpha;
      const int prow = (wave*16 + quad*4 + rg) * LP;
      float ee[4] = {e0, e1, e2, e3};
#pragma unroll
      for (int nt = 0; nt < 4; nt++){
        const unsigned short hh = f2bs(ee[nt]);
        Ph[prow + nt*16 + lr] = hh;
        Pl[prow + nt*16 + lr] = f2bs(ee[nt] - bs2f(hh));
      }
    }
    // O += P @ W2chunk   (P wave-private rows; W planes synced at stage barrier)
#pragma unroll
    for (int ks = 0; ks < 2; ks++){
      const int ao = (wave*16 + lr)*LP + ks*32 + quad*8;
      frag_ab p_h = *(const frag_ab*)&Ph[ao];
      frag_ab p_l = *(const frag_ab*)&Pl[ao];
#pragma unroll
      for (int nt = 0; nt < 4; nt++){
        const int bo = (nt*16 + lr)*LP + ks*32 + quad*8;
        frag_ab b_h = *(const frag_ab*)&Wth[bo];
        frag_ab b_l = *(const frag_ab*)&Wtl[bo];
        o[nt] = __builtin_amdgcn_mfma_f32_16x16x32_bf16(p_l, b_h, o[nt], 0, 0, 0);
        o[nt] = __builtin_amdgcn_mfma_f32_16x16x32_bf16(p_h, b_l, o[nt], 0, 0, 0);
        o[nt] = __builtin_amdgcn_mfma_f32_16x16x32_bf16(p_h, b_h, o[nt], 0, 0, 0);
      }
    }
  }
  // normalize
#pragma unroll
  for (int rg = 0; rg < 4; rg++){
    const float inv = 1.f / l_run[rg];
#pragma unroll
    for (int nt = 0; nt < 4; nt++) o[nt][rg] *= inv;
  }
  // conv: stage v rows [i0-16, i0+143] (160 rows) into Vs (all LDS planes dead)
  __syncthreads();
#pragma unroll
  for (int u = 0; u < 5; u++){
    const int f = tid + u * 512, row = f >> 4, c4 = (f & 15) << 2;
    const int g = i0 - 16 + row;
    float4 vv = make_float4(0.f, 0.f, 0.f, 0.f);
    if (g >= 0 && g < NTOK) vv = *(const float4*)(vf + ((size_t)bh * NTOK + g) * DH + c4);
    *(float4*)&Vs[row][c4] = vv;
  }
  __syncthreads();
  // sliding-window conv: 36 reads per (nt), reuse across rg.
  // block-local out row R (0..127) uses Vs rows R..R+32
  const int rbase = wave*16 + quad*4;
#pragma unroll
  for (int nt = 0; nt < 4; nt++){
    const int col = nt*16 + lr;
#pragma unroll
    for (int s5 = 0; s5 < 36; s5++){
      const float v = Vs[rbase + s5][col];
#pragma unroll
      for (int rg = 0; rg < 4; rg++){
        const int t = s5 - rg;
        if (t >= 0 && t <= 32) o[nt][rg] += wcs[t] * v;
      }
    }
  }
  // pack (hi|lo) bf16, stage in St, coalesced write over q tile
  __syncthreads();
#pragma unroll
  for (int nt = 0; nt < 4; nt++)
#pragma unroll
    for (int rg = 0; rg < 4; rg++){
      const float val = o[nt][rg];
      const unsigned short hi = f2bs(val);
      const unsigned short lo = f2bs(val - bs2f(hi));
      St[rbase + rg][nt*16 + lr] = __uint_as_float((unsigned int)hi | ((unsigned int)lo << 16));
    }
  __syncthreads();
#pragma unroll
  for (int u = 0; u < 4; u++){
    const int f = tid + u * 512, row = f >> 4, c4 = (f & 15) << 2;
    *(float4*)(qb + (size_t)(i0 + row) * DH + c4) = *(const float4*)&St[row][c4];
  }
}

extern "C" void kernel_launch(void* const* d_in, const int* in_sizes, int n_in,
                              void* d_out, int out_size, void* d_ws, size_t ws_size,
                              hipStream_t stream){
  (void)in_sizes; (void)n_in; (void)out_size; (void)ws_size;
  const float* x     = (const float*)d_in[0];
  const float* wqkv  = (const float*)d_in[1];
  const float* wout  = (const float*)d_in[2];
  const float* bout  = (const float*)d_in[3];
  const float* wconv = (const float*)d_in[4];
  float* outp = (float*)d_out;

  char* base = (char*)d_ws;
  auto alloc = [&](size_t bytes)->char*{
    char* p = base; base += (bytes + 255) & ~(size_t)255; return p;
  };
  const size_t QS = (size_t)BH * NTOK * DH;   // 8388608
  const size_t LS = (size_t)BH * MLM * DH;    // 262144
  const size_t MM = (size_t)BH * MLM * MLM;   // 1048576

  float* qf   = (float*)alloc(QS * 4);   // q; packed oh overwrites in place
  float* vf   = (float*)alloc(QS * 4);
  unsigned short* kSh = (unsigned short*)alloc(QS * 2);
  unsigned short* kSl = (unsigned short*)alloc(QS * 2);
  float* qlf  = (float*)alloc(LS * 4);
  float* klf  = (float*)alloc(LS * 4);
  float* a2   = (float*)alloc(MM * 4);
  float* zb   = (float*)alloc(MM * 4);
  float* z2   = (float*)alloc(MM * 4);
  float* xz   = (float*)alloc(MM * 4);
  float* t2   = (float*)alloc(MM * 4);
  float* t4   = (float*)alloc(MM * 4);
  float* part = (float*)alloc(64 * 4);
  // union region: pinv transpose-split planes (10 x MM ushorts = 21.0 MB) alias pbuf
  // (flash partials, 16 x 16 x 256 x 68 x 4 B = 17.8 MB).  Planes dead before k_flash.
  char* un = alloc(10 * MM * 2);
  unsigned short* pl0 = (unsigned short*)un;
  unsigned short* zbTh = pl0 + 0*MM; unsigned short* zbTl = pl0 + 1*MM;
  unsigned short* z2Th = pl0 + 2*MM; unsigned short* z2Tl = pl0 + 3*MM;
  unsigned short* xzTh = pl0 + 4*MM; unsigned short* xzTl = pl0 + 5*MM;
  unsigned short* t2Th = pl0 + 6*MM; unsigned short* t2Tl = pl0 + 7*MM;
  unsigned short* t4Th = pl0 + 8*MM; unsigned short* t4Tl = pl0 + 9*MM;
  float* pbuf = (float*)un;
  float* av   = (float*)alloc(LS * 4);
  float* w2   = (float*)alloc(LS * 4);
  unsigned short* wqTh = (unsigned short*)alloc((size_t)1536 * 512 * 2);
  unsigned short* wqTl = (unsigned short*)alloc((size_t)1536 * 512 * 2);
  unsigned short* woTh = (unsigned short*)alloc((size_t)512 * 512 * 2);
  unsigned short* woTl = (unsigned short*)alloc((size_t)512 * 512 * 2);
  unsigned short* qlSh = (unsigned short*)alloc(LS * 2);
  unsigned short* qlSl = (unsigned short*)alloc(LS * 2);
  unsigned short* klSh = (unsigned short*)alloc(LS * 2);
  unsigned short* klSl = (unsigned short*)alloc(LS * 2);
  unsigned short* w2Th = (unsigned short*)alloc(LS * 2);
  unsigned short* w2Tl = (unsigned short*)alloc(LS * 2);
  unsigned short* vTh  = (unsigned short*)alloc(QS * 2);
  unsigned short* vTl  = (unsigned short*)alloc(QS * 2);
  // xh/xl alias vTh/vTl: consumed by k_mfma_qkv before k_vtrans overwrites.
  unsigned short* xh = vTh;
  unsigned short* xl = vTl;

  // 0. weight transpose + split (wqkv pre-swizzled for gload_lds; wout NOT); x split+swizzled
  k_splitw<<<1536 * 512 / 256, 256, 0, stream>>>(wqkv, 512, 1536, wqTh, wqTl, 1);
  k_splitw<<<512 * 512 / 256, 256, 0, stream>>>(wout, 512, 512, woTh, woTl, 0);
  k_splitx<<<8192, 256, 0, stream>>>(x, xh, xl);
  // 1. QKV projection (MFMA split-bf16, double-buffered gload_lds); k written pre-split
  k_mfma_qkv<<<dim3(12, 128), 256, 0, stream>>>(xh, xl, wqTh, wqTl, qf, kSh, kSl, vf);
  // 1b. v transpose+split for MFMA PV operand (overwrites xh/xl)
  k_vtrans<<<dim3(NTOK / 64, BH), 256, 0, stream>>>(vf, vTh, vTl);
  // 2. landmarks (+ split copies)
  k_land2<<<dim3(BH * MLM, 2), 64, 0, stream>>>(qf, kSh, kSl, qlf, klf, qlSh, qlSl, klSh, klSl);
  // 3. sim2 + softmax -> attn2
  k_sim2<<<dim3(4, 4, BH), 256, 0, stream>>>(qlf, klf, xz);
  k_softmax256<<<BH * MLM, 256, 0, stream>>>(xz, a2);
  // 4. pinv init (z0 also emits z^T split)
  k_colrow<<<BH, 256, 0, stream>>>(a2, part);
  k_z0<<<BH * MLM, 256, 0, stream>>>(a2, part, zb, zbTh, zbTl);
  // 5. 6 Newton-Schulz iterations (24 dispatches, 512-block prefetch GEMM, 3-term)
  {
    float* zc = zb;  unsigned short* zcTh = zbTh; unsigned short* zcTl = zbTl;
    float* zn = z2;  unsigned short* znTh = z2Th; unsigned short* znTl = z2Tl;
    for (int it = 0; it < 6; ++it){
      k_gemm256m<<<dim3(32, BH), 256, 0, stream>>>(a2, zcTh, zcTl, a2, xz, xzTh, xzTl, 0.f, -1.f, 1);
      k_gemm256m<<<dim3(32, BH), 256, 0, stream>>>(xz, xzTh, xzTl, xz, t2, t2Th, t2Tl, 7.f, 1.f, 0);
      k_gemm256m<<<dim3(32, BH), 256, 0, stream>>>(xz, t2Th, t2Tl, xz, t4, t4Th, t4Tl, 15.f, 1.f, 0);
      k_gemm256m<<<dim3(32, BH), 256, 0, stream>>>(zc, t4Th, t4Tl, zc, zn, znTh, znTl, 13.f, 0.25f, 1);
      float* tf = zc; zc = zn; zn = tf;
      unsigned short* th = zcTh; zcTh = znTh; znTh = th;
      unsigned short* tl = zcTl; zcTl = znTl; znTl = tl;
    }
  }
  const size_t FLASH_LDS = (size_t)4 * 64 * LP * 2;   // 36864 B
  const size_t ATTN1_LDS = (size_t)8 * 64 * LP * 2;   // 73728 B (K/W 4 planes + P 2x128-row)
  // 6. flash attn3@v (MFMA, all pre-split; kc split 16-way) + combine
  k_flash<<<dim3(16, 4, BH), 256, FLASH_LDS, stream>>>(qlSh, qlSl, kSh, kSl, vTh, vTl, pbuf);
  k_comb<<<BH * MLM / 4, 256, 0, stream>>>(pbuf, av);
  // 7. w2 = z_final @ av (final z lands in zb after 6 iters; + transposed split for attn1)
  k_w2<<<dim3(4, BH), 256, 0, stream>>>(zb, av, w2, w2Th, w2Tl);
  // 8. fused flash attn1 + conv (MFMA, 512 threads / 128-row tiles); packed oh overwrites q
  k_attn1<<<dim3(64, BH), 512, ATTN1_LDS, stream>>>(qf, klSh, klSl, vf, w2Th, w2Tl, wconv);
  // 9. output projection + residual (MFMA split-bf16)
  k_mfma_final<<<dim3(4, 128), 256, 0, stream>>>((const unsigned int*)qf, woTh, woTl, x, bout, outp);
}

// Round 12
// 676.520 us; speedup vs baseline: 1.0987x; 1.0016x over previous
//
#include <hip/hip_runtime.h>
#include <hip/hip_bf16.h>

#define BH 16
#define NTOK 8192
#define NHEAD 8
#define DH 64
#define MLM 256
#define QSCALE 0.125f
#define LP 72   // ushort stride for flash LDS tiles; MUST be >= 64 (row holds 64 ushorts of K-dim)
#define LOG2E 1.4426950408889634f

typedef unsigned short ushort_t;
using frag_ab = __attribute__((ext_vector_type(8))) short;   // 8 bf16 (4 VGPRs)
using frag_cd = __attribute__((ext_vector_type(4))) float;   // 4 fp32 acc

__device__ __forceinline__ unsigned short f2bs(float f){
  __hip_bfloat16 h = __float2bfloat16(f);
  return *(unsigned short*)&h;
}
__device__ __forceinline__ float bs2f(unsigned short u){
  union { unsigned int i; float f; } cv; cv.i = ((unsigned int)u) << 16; return cv.f;
}

// async global->LDS, 16B per lane.  LDS dest = wave-uniform base + lane*16 (HW).
__device__ __forceinline__ void gl_lds16(const unsigned short* g, unsigned short* l){
  __builtin_amdgcn_global_load_lds((const __attribute__((address_space(1))) unsigned int*)(const void*)g,
                                   (__attribute__((address_space(3))) unsigned int*)(void*)l, 16, 0, 0);
}

// ---------------- weight transpose + hi/lo bf16 split: in[K][N] -> outh/outl [N][K]
// swz!=0: pre-swizzle 16B slot within each 32-col K-group (slot ^= row&3) for gload_lds consumers
__global__ __launch_bounds__(256) void k_splitw(const float* __restrict__ in, int K, int N,
                                                unsigned short* __restrict__ oh,
                                                unsigned short* __restrict__ ol, int swz){
  const int idx = blockIdx.x * 256 + threadIdx.x;   // over N*K
  const int n = idx / K, k = idx - n * K;
  const float v = in[(size_t)k * N + n];
  const unsigned short hi = f2bs(v);
  int kd = k;
  if (swz){
    const int q = (k >> 3) & 3;
    kd = (k & ~31) | (((q ^ (n & 3)) & 3) << 3) | (k & 7);
  }
  oh[(size_t)n * K + kd] = hi;
  ol[(size_t)n * K + kd] = f2bs(v - bs2f(hi));
}

// ---------------- plain hi/lo split of x, PRE-SWIZZLED for gload_lds (slot ^= row&3)
__global__ __launch_bounds__(256) void k_splitx(const float* __restrict__ in,
                                                unsigned short* __restrict__ oh,
                                                unsigned short* __restrict__ ol){
  const size_t i4 = ((size_t)blockIdx.x * 256 + threadIdx.x) * 4;
  const int row = (int)(i4 >> 9);
  const int col = (int)(i4 & 511);
  const int q = (col >> 3) & 3;
  const int cd = (col & ~31) | (((q ^ (row & 3)) & 3) << 3) | (col & 7);
  const size_t o4 = ((size_t)row << 9) + cd;
  float4 v = *(const float4*)(in + i4);
  const unsigned short h0 = f2bs(v.x), h1 = f2bs(v.y), h2 = f2bs(v.z), h3 = f2bs(v.w);
  *(ushort4*)(oh + o4) = make_ushort4(h0, h1, h2, h3);
  *(ushort4*)(ol + o4) = make_ushort4(f2bs(v.x - bs2f(h0)), f2bs(v.y - bs2f(h1)),
                                      f2bs(v.z - bs2f(h2)), f2bs(v.w - bs2f(h3)));
}

// ---------------- MFMA split-bf16 GEMM: qkv.  A = x pre-split+swizzled [16384][512],
// B = wqkvT pre-split+swizzled [1536][512].  128x128 tile, 4 waves, 64x64 each.
// LDS DOUBLE-BUFFER 2-phase; XCD-aware bijective block swizzle (m-major chunks per XCD).
__global__ __launch_bounds__(256) void k_mfma_qkv(const unsigned short* __restrict__ xh,
                                                  const unsigned short* __restrict__ xl,
                                                  const unsigned short* __restrict__ bth,
                                                  const unsigned short* __restrict__ btl,
                                                  float* __restrict__ q,
                                                  unsigned short* __restrict__ kSh,
                                                  unsigned short* __restrict__ kSl,
                                                  float* __restrict__ v){
  // XCD swizzle: 1536 blocks, 8 XCDs, 192/chunk.  Blocks with the same orig%8 run on the
  // same XCD; give each XCD contiguous m-major work so A-panels stay in its private L2.
  const int orig = blockIdx.x;
  const int sw = (orig & 7) * 192 + (orig >> 3);
  const int n0 = (sw % 12) * 128;   // over 1536
  const int m0 = (sw / 12) * 128;   // over 16384
  __shared__ unsigned short SB[2][4 * 128 * 32];   // 2 buffers x {Ah,Al,Bh,Bl} planes
  const int tid = threadIdx.x;
  const int wave = tid >> 6, lane = tid & 63;
  const int wm = wave >> 1, wn = wave & 1;
  const int lr = lane & 15, quad = lane >> 4;
  const int cswz = ((quad ^ (lr & 3)) & 3) << 3;   // swizzled 8-ushort slot
  // staging: wave w owns plane w
  const unsigned short* gsrc = (wave == 0) ? xh : (wave == 1) ? xl : (wave == 2) ? bth : btl;
  const int R0 = (wave < 2) ? m0 : n0;
  const int lrow = lane >> 2, lslot = (lane & 3) << 3;
  const int pbase = wave * 4096;
  frag_cd acc[4][4];
#pragma unroll
  for (int mt = 0; mt < 4; mt++)
#pragma unroll
    for (int nt = 0; nt < 4; nt++){
      frag_cd z = {0.f, 0.f, 0.f, 0.f};
      acc[mt][nt] = z;
    }
  // prologue: stage k0=0 into buf 0
#pragma unroll
  for (int u = 0; u < 8; u++)
    gl_lds16(gsrc + (size_t)(R0 + u*16 + lrow) * 512 + lslot, &SB[0][pbase] + u * 512);
  __syncthreads();
  int cur = 0;
  for (int k0 = 0; k0 < 512; k0 += 32){
    // issue next K-step's loads into the other buffer (overlap with MFMA below)
    if (k0 + 32 < 512){
#pragma unroll
      for (int u = 0; u < 8; u++)
        gl_lds16(gsrc + (size_t)(R0 + u*16 + lrow) * 512 + k0 + 32 + lslot,
                 &SB[cur ^ 1][pbase] + u * 512);
    }
    const unsigned short* Ah = &SB[cur][0];
    const unsigned short* Al = &SB[cur][4096];
    const unsigned short* Bh = &SB[cur][8192];
    const unsigned short* Bl = &SB[cur][12288];
    frag_ab a_h[4], a_l[4], b_h[4], b_l[4];
#pragma unroll
    for (int t = 0; t < 4; t++){
      const int ar = (wm*64 + t*16 + lr) << 5;
      const int br = (wn*64 + t*16 + lr) << 5;
      a_h[t] = *(const frag_ab*)&Ah[ar + cswz];
      a_l[t] = *(const frag_ab*)&Al[ar + cswz];
      b_h[t] = *(const frag_ab*)&Bh[br + cswz];
      b_l[t] = *(const frag_ab*)&Bl[br + cswz];
    }
#pragma unroll
    for (int mt = 0; mt < 4; mt++)
#pragma unroll
      for (int nt = 0; nt < 4; nt++){
        acc[mt][nt] = __builtin_amdgcn_mfma_f32_16x16x32_bf16(a_l[mt], b_h[nt], acc[mt][nt], 0, 0, 0);
        acc[mt][nt] = __builtin_amdgcn_mfma_f32_16x16x32_bf16(a_h[mt], b_l[nt], acc[mt][nt], 0, 0, 0);
        acc[mt][nt] = __builtin_amdgcn_mfma_f32_16x16x32_bf16(a_h[mt], b_h[nt], acc[mt][nt], 0, 0, 0);
      }
    __syncthreads();   // drains vmcnt (next buffer landed) + everyone done reading cur
    cur ^= 1;
  }
  // epilogue: D row = quad*4+reg, col = lane&15
#pragma unroll
  for (int mt = 0; mt < 4; mt++)
#pragma unroll
    for (int nt = 0; nt < 4; nt++)
#pragma unroll
      for (int rg = 0; rg < 4; rg++){
        const int row = m0 + wm*64 + mt*16 + quad*4 + rg;
        const int col = n0 + wn*64 + nt*16 + lr;
        const int bb = row >> 13, i = row & 8191;
        const int which = col >> 9;
        const int cc = col & 511;
        const int h = cc >> 6, d = cc & 63;
        const size_t off = (((size_t)(bb * NHEAD + h)) * NTOK + i) * DH + d;
        const float val = acc[mt][nt][rg];
        if (which == 0)      q[off] = val * QSCALE;
        else if (which == 1){
          const unsigned short hi = f2bs(val);
          kSh[off] = hi; kSl[off] = f2bs(val - bs2f(hi));
        }
        else                 v[off] = val;
      }
}

// ---------------- MFMA split-bf16 GEMM: final.  A = oh packed (hi|lo in uint32 slots of qf,
// layout [bh][8192][64]), B = woutT hi/lo [512][512].  out = A@B + bout + x.
// A register-prefetched one K-step ahead; XCD-aware bijective block swizzle.
__global__ __launch_bounds__(256) void k_mfma_final(const unsigned int* __restrict__ qpk,
                                                    const unsigned short* __restrict__ bth,
                                                    const unsigned short* __restrict__ btl,
                                                    const float* __restrict__ xin,
                                                    const float* __restrict__ bout,
                                                    float* __restrict__ outp){
  // XCD swizzle: 512 blocks, 8 XCDs, 64/chunk, m-major within chunk.
  const int orig = blockIdx.x;
  const int sw = (orig & 7) * 64 + (orig >> 3);
  const int n0 = (sw & 3) * 128;    // over 512
  const int m0 = (sw >> 2) * 128;   // over 16384
  __shared__ unsigned short Ah[128][40], Al[128][40], Bh[128][40], Bl[128][40];
  const int tid = threadIdx.x;
  const int wave = tid >> 6, lane = tid & 63;
  const int wm = wave >> 1, wn = wave & 1;
  const int lr = lane & 15, quad = lane >> 4, koff = quad * 8;
  const int bb = m0 >> 13;
  frag_cd acc[4][4];
#pragma unroll
  for (int mt = 0; mt < 4; mt++)
#pragma unroll
    for (int nt = 0; nt < 4; nt++){
      frag_cd z = {0.f, 0.f, 0.f, 0.f};
      acc[mt][nt] = z;
    }
  const int arow = tid >> 3, ac4 = (tid & 7) << 2;     // A: 4 slots of 32 rows
  const int brow = tid >> 2, bch = (tid & 3) << 3;     // B: 2 slots of 64 rows
  uint4 pw[4];
  // prologue: prefetch A regs for k0=0
#pragma unroll
  for (int u = 0; u < 4; u++){
    const int row = arow + u * 32;
    const int i = (m0 + row) & 8191;
    pw[u] = *(const uint4*)(qpk + (((size_t)(bb * NHEAD + 0)) * NTOK + i) * DH + 0 + ac4);
  }
  for (int k0 = 0; k0 < 512; k0 += 32){
    __syncthreads();
    // write LDS from prefetched A regs
#pragma unroll
    for (int u = 0; u < 4; u++){
      const int row = arow + u * 32;
      *(ushort4*)&Ah[row][ac4] = make_ushort4((unsigned short)pw[u].x, (unsigned short)pw[u].y,
                                              (unsigned short)pw[u].z, (unsigned short)pw[u].w);
      *(ushort4*)&Al[row][ac4] = make_ushort4((unsigned short)(pw[u].x >> 16), (unsigned short)(pw[u].y >> 16),
                                              (unsigned short)(pw[u].z >> 16), (unsigned short)(pw[u].w >> 16));
    }
    // stage B (pre-split copies, L2-hot)
#pragma unroll
    for (int u = 0; u < 2; u++){
      const int row = brow + u * 64;
      *(uint4*)&Bh[row][bch] = *(const uint4*)(bth + (size_t)(n0 + row) * 512 + k0 + bch);
      *(uint4*)&Bl[row][bch] = *(const uint4*)(btl + (size_t)(n0 + row) * 512 + k0 + bch);
    }
    __syncthreads();
    // prefetch A regs for k0+32 (loads in flight during MFMA)
    if (k0 + 32 < 512){
      const int hn = (k0 + 32) >> 6, dbn = (k0 + 32) & 63;
#pragma unroll
      for (int u = 0; u < 4; u++){
        const int row = arow + u * 32;
        const int i = (m0 + row) & 8191;
        pw[u] = *(const uint4*)(qpk + (((size_t)(bb * NHEAD + hn)) * NTOK + i) * DH + dbn + ac4);
      }
    }
    frag_ab a_h[4], a_l[4], b_h[4], b_l[4];
#pragma unroll
    for (int t = 0; t < 4; t++){
      a_h[t] = *(const frag_ab*)&Ah[wm*64 + t*16 + lr][koff];
      a_l[t] = *(const frag_ab*)&Al[wm*64 + t*16 + lr][koff];
      b_h[t] = *(const frag_ab*)&Bh[wn*64 + t*16 + lr][koff];
      b_l[t] = *(const frag_ab*)&Bl[wn*64 + t*16 + lr][koff];
    }
#pragma unroll
    for (int mt = 0; mt < 4; mt++)
#pragma unroll
      for (int nt = 0; nt < 4; nt++){
        acc[mt][nt] = __builtin_amdgcn_mfma_f32_16x16x32_bf16(a_l[mt], b_h[nt], acc[mt][nt], 0, 0, 0);
        acc[mt][nt] = __builtin_amdgcn_mfma_f32_16x16x32_bf16(a_h[mt], b_l[nt], acc[mt][nt], 0, 0, 0);
        acc[mt][nt] = __builtin_amdgcn_mfma_f32_16x16x32_bf16(a_h[mt], b_h[nt], acc[mt][nt], 0, 0, 0);
      }
  }
#pragma unroll
  for (int mt = 0; mt < 4; mt++)
#pragma unroll
    for (int nt = 0; nt < 4; nt++)
#pragma unroll
      for (int rg = 0; rg < 4; rg++){
        const int row = m0 + wm*64 + mt*16 + quad*4 + rg;
        const int col = n0 + wn*64 + nt*16 + lr;
        outp[(size_t)row * 512 + col] = acc[mt][nt][rg] + bout[col] + xin[(size_t)row * 512 + col];
      }
}

// ---------------- landmark means for q and k in one launch (grid.y selects)
// k is read from pre-split planes; also emits hi/lo bf16 split copies
__global__ __launch_bounds__(64) void k_land2(const float* __restrict__ qf,
                                              const unsigned short* __restrict__ kSh,
                                              const unsigned short* __restrict__ kSl,
                                              float* __restrict__ qlf, float* __restrict__ klf,
                                              unsigned short* __restrict__ qlSh, unsigned short* __restrict__ qlSl,
                                              unsigned short* __restrict__ klSh, unsigned short* __restrict__ klSl){
  const int isK = blockIdx.y;
  float* dst = isK ? klf : qlf;
  unsigned short* dh = isK ? klSh : qlSh;
  unsigned short* dl = isK ? klSl : qlSl;
  const int bh = blockIdx.x >> 8;
  const int j  = blockIdx.x & 255;
  const int d  = threadIdx.x;
  const size_t base = ((size_t)bh * NTOK + (size_t)j * 32) * DH + d;
  float s = 0.f;
  if (!isK){
    const float* p = qf + base;
#pragma unroll
    for (int t = 0; t < 32; t++) s += p[t * DH];
  } else {
    const unsigned short* ph = kSh + base;
    const unsigned short* pl = kSl + base;
#pragma unroll
    for (int t = 0; t < 32; t++) s += bs2f(ph[t * DH]) + bs2f(pl[t * DH]);
  }
  const float val = s * (1.f / 32.f);
  const size_t oidx = ((size_t)bh * MLM + j) * DH + d;
  dst[oidx] = val;
  const unsigned short hi = f2bs(val);
  dh[oidx] = hi;
  dl[oidx] = f2bs(val - bs2f(hi));
}

// ---------------- transpose + split v: [bh][8192][64] fp32 -> vTh/vTl [bh][64][8192] bf16
__global__ __launch_bounds__(256) void k_vtrans(const float* __restrict__ vf,
                                                unsigned short* __restrict__ vTh,
                                                unsigned short* __restrict__ vTl){
  __shared__ float T[64][68];
  const int j0 = blockIdx.x * 64, bh = blockIdx.y;
  const int tid = threadIdx.x;
#pragma unroll
  for (int u = 0; u < 4; u++){
    const int f = tid + u * 256, row = f >> 4, c4 = (f & 15) << 2;
    *(float4*)&T[row][c4] = *(const float4*)(vf + ((size_t)bh * NTOK + j0 + row) * DH + c4);
  }
  __syncthreads();
#pragma unroll
  for (int u = 0; u < 4; u++){
    const int f = tid + u * 256, d = f >> 4, j4 = (f & 15) << 2;
    const float v0 = T[j4+0][d], v1 = T[j4+1][d], v2 = T[j4+2][d], v3 = T[j4+3][d];
    const unsigned short h0 = f2bs(v0), h1 = f2bs(v1), h2 = f2bs(v2), h3 = f2bs(v3);
    const size_t off = ((size_t)bh * DH + d) * NTOK + j0 + j4;
    *(ushort4*)(vTh + off) = make_ushort4(h0, h1, h2, h3);
    *(ushort4*)(vTl + off) = make_ushort4(f2bs(v0 - bs2f(h0)), f2bs(v1 - bs2f(h1)),
                                          f2bs(v2 - bs2f(h2)), f2bs(v3 - bs2f(h3)));
  }
}

// ---------------- sim2 = ql @ kl^T (fp32, K=64), batched [bh][256][256]
__global__ __launch_bounds__(256) void k_sim2(const float* __restrict__ qlf,
                                              const float* __restrict__ klf,
                                              float* __restrict__ C){
  const int bh = blockIdx.z;
  const float* Ab = qlf + (size_t)bh * MLM * DH;
  const float* Bb = klf + (size_t)bh * MLM * DH;
  float* Cb = C + (size_t)bh * MLM * MLM;
  const int n0 = blockIdx.x * 64;
  const int m0 = blockIdx.y * 64;
  __shared__ float As[16][64];
  __shared__ float Bs[16][64];
  const int tid = threadIdx.x, ty = tid >> 4, tx = tid & 15;
  const int lm = tid >> 2, lk = (tid & 3) << 2;
  float acc[4][4] = {};
  for (int k0 = 0; k0 < 64; k0 += 16){
    float4 a4 = *(const float4*)(Ab + (size_t)(m0 + lm) * DH + k0 + lk);
    As[lk+0][lm] = a4.x; As[lk+1][lm] = a4.y; As[lk+2][lm] = a4.z; As[lk+3][lm] = a4.w;
    float4 b4 = *(const float4*)(Bb + (size_t)(n0 + lm) * DH + k0 + lk);
    Bs[lk+0][lm] = b4.x; Bs[lk+1][lm] = b4.y; Bs[lk+2][lm] = b4.z; Bs[lk+3][lm] = b4.w;
    __syncthreads();
#pragma unroll
    for (int kk = 0; kk < 16; kk++){
      float a[4], bv[4];
#pragma unroll
      for (int r = 0; r < 4; r++) a[r] = As[kk][ty*4 + r];
#pragma unroll
      for (int c = 0; c < 4; c++) bv[c] = Bs[kk][tx*4 + c];
#pragma unroll
      for (int r = 0; r < 4; r++)
#pragma unroll
        for (int c = 0; c < 4; c++) acc[r][c] += a[r] * bv[c];
    }
    __syncthreads();
  }
#pragma unroll
  for (int r = 0; r < 4; r++)
#pragma unroll
    for (int c = 0; c < 4; c++)
      Cb[(size_t)(m0 + ty*4 + r) * MLM + n0 + tx*4 + c] = acc[r][c];
}

// ---------------- row softmax over 256
__global__ __launch_bounds__(256) void k_softmax256(const float* __restrict__ in, float* __restrict__ outp){
  const int row = blockIdx.x;
  const int t = threadIdx.x;
  float v = in[(size_t)row * 256 + t];
  __shared__ float red[256];
  red[t] = v; __syncthreads();
  for (int o = 128; o > 0; o >>= 1){ if (t < o) red[t] = fmaxf(red[t], red[t+o]); __syncthreads(); }
  float mx = red[0]; __syncthreads();
  float e = exp2f((v - mx) * LOG2E);
  red[t] = e; __syncthreads();
  for (int o = 128; o > 0; o >>= 1){ if (t < o) red[t] += red[t+o]; __syncthreads(); }
  outp[(size_t)row * 256 + t] = e / red[0];
}

// ---------------- per-batch COLUMN abs-sum maxima (row-sums of softmax are exactly 1)
__global__ __launch_bounds__(256) void k_colrow(const float* __restrict__ a2, float* __restrict__ part){
  const int bh = blockIdx.x;
  const int t = threadIdx.x;
  const float* p = a2 + (size_t)bh * 65536;
  float cs = 0.f;
  for (int i = 0; i < 256; i++) cs += fabsf(p[(size_t)i * 256 + t]);
  __shared__ float r2[256];
  r2[t] = cs; __syncthreads();
  for (int o = 128; o > 0; o >>= 1){
    if (t < o) r2[t] = fmaxf(r2[t], r2[t+o]);
    __syncthreads();
  }
  if (t == 0) part[bh] = r2[0];
}

// ---------------- z0 = a2^T * (1/(col*row)); col==1 so sc = 1/max_colsum
// also emits z^T pre-split (= a2 scaled, no transpose needed)
__global__ __launch_bounds__(256) void k_z0(const float* __restrict__ a2, const float* __restrict__ part,
                                            float* __restrict__ z,
                                            unsigned short* __restrict__ zTh,
                                            unsigned short* __restrict__ zTl){
  const int bh = blockIdx.x >> 8;
  const int i  = blockIdx.x & 255;
  const int j  = threadIdx.x;
  float m2 = 0.f;
#pragma unroll
  for (int t = 0; t < 16; t++) m2 = fmaxf(m2, part[t]);
  const float sc = 1.f / m2;
  const size_t ridx = ((size_t)bh * 256 + j) * 256 + i;
  const float val = a2[ridx] * sc;
  z[((size_t)bh * 256 + i) * 256 + j] = val;
  const unsigned short hi = f2bs(val);
  zTh[ridx] = hi;
  zTl[ridx] = f2bs(val - bs2f(hi));
}

// ---------------- batched 256^3 MFMA split-bf16 GEMM (NS chain step):
// C = s0*(c0*D - A@B), B pre-transposed+split.  32x64 tile -> 512 blocks (2/CU),
// register prefetch double-buffer, 3-term split, LDS-transposed coalesced C^T epilogue.
__global__ __launch_bounds__(256) void k_gemm256m(const float* __restrict__ A,
                                                  const unsigned short* __restrict__ BTh,
                                                  const unsigned short* __restrict__ BTl,
                                                  const float* __restrict__ D,
                                                  float* __restrict__ C,
                                                  unsigned short* __restrict__ CTh,
                                                  unsigned short* __restrict__ CTl,
                                                  float c0, float s0, int wC){
  __shared__ unsigned short Ah[32][40], Al[32][40], Bh[64][40], Bl[64][40];
  __shared__ float Ct[64][33];
  const int bh = blockIdx.y, tile = blockIdx.x;
  const int m0 = (tile >> 2) * 32, n0 = (tile & 3) * 64;
  const size_t bo = (size_t)bh * 65536;
  const int tid = threadIdx.x;
  const int wave = tid >> 6, lane = tid & 63;
  const int wm = wave >> 1, wn = wave & 1;
  const int lr = lane & 15, quad = lane >> 4, koff = quad * 8;
  const int ar = tid >> 3, ac = (tid & 7) << 2;     // A tile: 32 rows x 32 cols fp32
  const int br = tid >> 2, bc = (tid & 3) << 3;     // B tile: 64 rows x 32 cols ushort
  frag_cd acc[2];
  { frag_cd z = {0.f,0.f,0.f,0.f}; acc[0] = z; acc[1] = z; }
  float4 ra  = *(const float4*)(A + bo + (size_t)(m0 + ar) * 256 + ac);
  uint4  rbh = *(const uint4*)(BTh + bo + (size_t)(n0 + br) * 256 + bc);
  uint4  rbl = *(const uint4*)(BTl + bo + (size_t)(n0 + br) * 256 + bc);
  for (int k0 = 0; k0 < 256; k0 += 32){
    __syncthreads();
    {
      const unsigned short h0=f2bs(ra.x),h1=f2bs(ra.y),h2=f2bs(ra.z),h3=f2bs(ra.w);
      *(ushort4*)&Ah[ar][ac] = make_ushort4(h0,h1,h2,h3);
      *(ushort4*)&Al[ar][ac] = make_ushort4(f2bs(ra.x-bs2f(h0)), f2bs(ra.y-bs2f(h1)),
                                            f2bs(ra.z-bs2f(h2)), f2bs(ra.w-bs2f(h3)));
      *(uint4*)&Bh[br][bc] = rbh;
      *(uint4*)&Bl[br][bc] = rbl;
    }
    __syncthreads();
    if (k0 < 224){
      ra  = *(const float4*)(A + bo + (size_t)(m0 + ar) * 256 + k0 + 32 + ac);
      rbh = *(const uint4*)(BTh + bo + (size_t)(n0 + br) * 256 + k0 + 32 + bc);
      rbl = *(const uint4*)(BTl + bo + (size_t)(n0 + br) * 256 + k0 + 32 + bc);
    }
    frag_ab a_h = *(const frag_ab*)&Ah[wm*16 + lr][koff];
    frag_ab a_l = *(const frag_ab*)&Al[wm*16 + lr][koff];
#pragma unroll
    for (int b = 0; b < 2; b++){
      frag_ab b_h = *(const frag_ab*)&Bh[wn*32 + b*16 + lr][koff];
      frag_ab b_l = *(const frag_ab*)&Bl[wn*32 + b*16 + lr][koff];
      acc[b] = __builtin_amdgcn_mfma_f32_16x16x32_bf16(a_l, b_h, acc[b], 0, 0, 0);
      acc[b] = __builtin_amdgcn_mfma_f32_16x16x32_bf16(a_h, b_l, acc[b], 0, 0, 0);
      acc[b] = __builtin_amdgcn_mfma_f32_16x16x32_bf16(a_h, b_h, acc[b], 0, 0, 0);
    }
  }
  // epilogue: fp32 C direct; C^T via LDS transpose for coalesced split writes
  const bool useD = (c0 != 0.f);
#pragma unroll
  for (int b = 0; b < 2; b++)
#pragma unroll
    for (int rg = 0; rg < 4; rg++){
      const int row = m0 + wm*16 + quad*4 + rg;
      const int col = n0 + wn*32 + b*16 + lr;
      const size_t idx = bo + (size_t)row * 256 + col;
      const float dv = useD ? D[idx] : 0.f;
      const float val = s0 * (c0 * dv - acc[b][rg]);
      if (wC) C[idx] = val;
      Ct[col - n0][row - m0] = val;
    }
  __syncthreads();
  {
    const int cr = tid >> 2, sg = (tid & 3) << 3;
    unsigned int ph[4], pl[4];
#pragma unroll
    for (int j = 0; j < 4; j++){
      const float v0 = Ct[cr][sg + 2*j], v1 = Ct[cr][sg + 2*j + 1];
      const unsigned short h0 = f2bs(v0), h1 = f2bs(v1);
      ph[j] = (unsigned int)h0 | ((unsigned int)h1 << 16);
      pl[j] = (unsigned int)f2bs(v0 - bs2f(h0)) | ((unsigned int)f2bs(v1 - bs2f(h1)) << 16);
    }
    const size_t tb = bo + (size_t)(n0 + cr) * 256 + m0 + sg;
    *(uint4*)(CTh + tb) = make_uint4(ph[0], ph[1], ph[2], ph[3]);
    *(uint4*)(CTl + tb) = make_uint4(pl[0], pl[1], pl[2], pl[3]);
  }
}

// ---------------- flash (MFMA split-bf16): partial online-softmax (attn3 @ v) per (kc, mtile, bh)
// 4 waves, each owns 16 q-rows x full 64-col chunk.  Q lifted to registers; P aliases K planes.
// LDS = 4 planes (36864 B).  kc split 16-way.  exp2 softmax.
__global__ __launch_bounds__(256) void k_flash(const unsigned short* __restrict__ qlSh,
                                               const unsigned short* __restrict__ qlSl,
                                               const unsigned short* __restrict__ kSh,
                                               const unsigned short* __restrict__ kSl,
                                               const unsigned short* __restrict__ vTh,
                                               const unsigned short* __restrict__ vTl,
                                               float* __restrict__ pbuf){
  extern __shared__ __align__(16) unsigned short sm[];
  unsigned short* Kh  = sm;                 // Q staging, then K, then P (hi)
  unsigned short* Kl  = sm + 1*64*LP;       // Q staging, then K, then P (lo)
  unsigned short* Wth = sm + 2*64*LP;
  unsigned short* Wtl = sm + 3*64*LP;
  const int kc = blockIdx.x, mt = blockIdx.y, bh = blockIdx.z;
  const int m0 = mt * 64, kbeg = kc * 512;
  const int tid = threadIdx.x;
  const int wave = tid >> 6, lane = tid & 63;
  const int lr = lane & 15, quad = lane >> 4;
  const size_t qbase = (size_t)bh * MLM * DH;
  const size_t kb  = (size_t)bh * NTOK * DH;
  const size_t vtb = (size_t)bh * DH * NTOK;
  // prologue: stage Q through K planes, lift own-wave fragments to registers
#pragma unroll
  for (int u = 0; u < 4; u++){
    const int f = tid + u * 256, row = f >> 4, c4 = (f & 15) << 2;
    *(ushort4*)&Kh[row*LP + c4] = *(const ushort4*)(qlSh + qbase + (size_t)(m0 + row) * DH + c4);
    *(ushort4*)&Kl[row*LP + c4] = *(const ushort4*)(qlSl + qbase + (size_t)(m0 + row) * DH + c4);
  }
  __syncthreads();
  frag_ab qa_h[2], qa_l[2];
#pragma unroll
  for (int ks = 0; ks < 2; ks++){
    const int ao = (wave*16 + lr)*LP + ks*32 + quad*8;
    qa_h[ks] = *(const frag_ab*)&Kh[ao];
    qa_l[ks] = *(const frag_ab*)&Kl[ao];
  }
  float m_run[4], l_run[4];
  frag_cd o[4];
#pragma unroll
  for (int r = 0; r < 4; r++){ m_run[r] = -1e30f; l_run[r] = 0.f; }
#pragma unroll
  for (int nt = 0; nt < 4; nt++){ frag_cd z = {0.f,0.f,0.f,0.f}; o[nt] = z; }

  for (int ch = 0; ch < 8; ch++){
    const int kr0 = kbeg + ch * 64;
    __syncthreads();   // prev PV done (and Q frag reads done on first iter)
    // stage K chunk and V^T chunk (all pre-split copies)
#pragma unroll
    for (int u = 0; u < 4; u++){
      const int f = tid + u * 256, row = f >> 4, c4 = (f & 15) << 2;
      *(ushort4*)&Kh[row*LP + c4]  = *(const ushort4*)(kSh + kb + (size_t)(kr0 + row) * DH + c4);
      *(ushort4*)&Kl[row*LP + c4]  = *(const ushort4*)(kSl + kb + (size_t)(kr0 + row) * DH + c4);
      *(ushort4*)&Wth[row*LP + c4] = *(const ushort4*)(vTh + vtb + (size_t)row * NTOK + kr0 + c4);
      *(ushort4*)&Wtl[row*LP + c4] = *(const ushort4*)(vTl + vtb + (size_t)row * NTOK + kr0 + c4);
    }
    __syncthreads();
    // S = Q @ K^T  (3-term split, Q from registers)
    frag_cd s[4];
#pragma unroll
    for (int nt = 0; nt < 4; nt++){ frag_cd z = {0.f,0.f,0.f,0.f}; s[nt] = z; }
#pragma unroll
    for (int ks = 0; ks < 2; ks++){
#pragma unroll
      for (int nt = 0; nt < 4; nt++){
        const int bo = (nt*16 + lr)*LP + ks*32 + quad*8;
        frag_ab b_h = *(const frag_ab*)&Kh[bo];
        frag_ab b_l = *(const frag_ab*)&Kl[bo];
        s[nt] = __builtin_amdgcn_mfma_f32_16x16x32_bf16(qa_l[ks], b_h, s[nt], 0, 0, 0);
        s[nt] = __builtin_amdgcn_mfma_f32_16x16x32_bf16(qa_h[ks], b_l, s[nt], 0, 0, 0);
        s[nt] = __builtin_amdgcn_mfma_f32_16x16x32_bf16(qa_h[ks], b_h, s[nt], 0, 0, 0);
      }
    }
    __syncthreads();   // all cross-wave K reads complete before P overwrites K planes
    // online softmax (exp2); P written into K planes (own-wave rows only)
#pragma unroll
    for (int rg = 0; rg < 4; rg++){
      float mx = fmaxf(fmaxf(s[0][rg], s[1][rg]), fmaxf(s[2][rg], s[3][rg]));
#pragma unroll
      for (int o2 = 8; o2 >= 1; o2 >>= 1) mx = fmaxf(mx, __shfl_xor(mx, o2));
      const float mnew = fmaxf(m_run[rg], mx);
      float e0 = exp2f((s[0][rg] - mnew) * LOG2E), e1 = exp2f((s[1][rg] - mnew) * LOG2E);
      float e2 = exp2f((s[2][rg] - mnew) * LOG2E), e3 = exp2f((s[3][rg] - mnew) * LOG2E);
      float psum = e0 + e1 + e2 + e3;
#pragma unroll
      for (int o2 = 8; o2 >= 1; o2 >>= 1) psum += __shfl_xor(psum, o2);
      const float alpha = exp2f((m_run[rg] - mnew) * LOG2E);
      l_run[rg] = l_run[rg] * alpha + psum;
      m_run[rg] = mnew;
#pragma unroll
      for (int nt = 0; nt < 4; nt++) o[nt][rg] *= alpha;
      const int prow = (wave*16 + quad*4 + rg) * LP;
      float ee[4] = {e0, e1, e2, e3};
#pragma unroll
      for (int nt = 0; nt < 4; nt++){
        const unsigned short hh = f2bs(ee[nt]);
        Kh[prow + nt*16 + lr] = hh;
        Kl[prow + nt*16 + lr] = f2bs(ee[nt] - bs2f(hh));
      }
    }
    // O += P @ V   (P own-wave rows from K planes; V^T cross-wave from W planes)
#pragma unroll
    for (int ks = 0; ks < 2; ks++){
      const int ao = (wave*16 + lr)*LP + ks*32 + quad*8;
      frag_ab p_h = *(const frag_ab*)&Kh[ao];
      frag_ab p_l = *(const frag_ab*)&Kl[ao];
#pragma unroll
      for (int nt = 0; nt < 4; nt++){
        const int bo = (nt*16 + lr)*LP + ks*32 + quad*8;
        frag_ab b_h = *(const frag_ab*)&Wth[bo];
        frag_ab b_l = *(const frag_ab*)&Wtl[bo];
        o[nt] = __builtin_amdgcn_mfma_f32_16x16x32_bf16(p_l, b_h, o[nt], 0, 0, 0);
        o[nt] = __builtin_amdgcn_mfma_f32_16x16x32_bf16(p_h, b_l, o[nt], 0, 0, 0);
        o[nt] = __builtin_amdgcn_mfma_f32_16x16x32_bf16(p_h, b_h, o[nt], 0, 0, 0);
      }
    }
  }
  // epilogue: unnormalized o + (m,l) partials, layout compatible with k_comb
  float* pb = pbuf + (((size_t)bh * 16 + kc) * 256 + m0) * 68;
#pragma unroll
  for (int rg = 0; rg < 4; rg++){
    const int row = wave*16 + quad*4 + rg;
#pragma unroll
    for (int nt = 0; nt < 4; nt++)
      pb[(size_t)row * 68 + nt*16 + lr] = o[nt][rg];
    if (lr == 0){
      pb[(size_t)row * 68 + 64] = m_run[rg];
      pb[(size_t)row * 68 + 65] = l_run[rg];
    }
  }
}

// ---------------- combine flash partials (16) -> av fp32 [bh][256][64]
__global__ __launch_bounds__(256) void k_comb(const float* __restrict__ pbuf, float* __restrict__ av){
  const int wv = threadIdx.x >> 6, lane = threadIdx.x & 63;
  const int id = blockIdx.x * 4 + wv;
  const int bh = id >> 8, row = id & 255;
  const float* base = pbuf + ((size_t)bh * 16 * 256 + row) * 68;
  float M = -1e30f;
#pragma unroll
  for (int k = 0; k < 16; k++) M = fmaxf(M, base[(size_t)k * 256 * 68 + 64]);
  float L = 0.f, o = 0.f;
#pragma unroll
  for (int k = 0; k < 16; k++){
    const float* p = base + (size_t)k * 256 * 68;
    float w = exp2f((p[64] - M) * LOG2E);
    L += p[65] * w;
    o += p[lane] * w;
  }
  av[((size_t)bh * MLM + row) * DH + lane] = o / L;
}

// ---------------- w2 = z_final @ av (fp32, M=256,N=64,K=256), batched
// also emits transposed hi/lo split w2T [bh][64][256] for the MFMA attn1 PV operand
__global__ __launch_bounds__(256) void k_w2(const float* __restrict__ Z, const float* __restrict__ AV,
                                            float* __restrict__ W2,
                                            unsigned short* __restrict__ w2Th,
                                            unsigned short* __restrict__ w2Tl){
  const int bh = blockIdx.y, mt = blockIdx.x;
  const float* Zb = Z + (size_t)bh * 65536;
  const float* Vb = AV + (size_t)bh * MLM * DH;
  float* Wb = W2 + (size_t)bh * MLM * DH;
  const int m0 = mt * 64;
  __shared__ float As[16][64];
  __shared__ float Bs[16][64];
  const int tid = threadIdx.x, ty = tid >> 4, tx = tid & 15;
  const int lm = tid >> 2, lk = (tid & 3) << 2;
  const int lk2 = tid >> 4, ln = (tid & 15) << 2;
  float acc[4][4] = {};
  for (int k0 = 0; k0 < 256; k0 += 16){
    float4 a4 = *(const float4*)(Zb + (size_t)(m0 + lm) * 256 + k0 + lk);
    As[lk+0][lm] = a4.x; As[lk+1][lm] = a4.y; As[lk+2][lm] = a4.z; As[lk+3][lm] = a4.w;
    float4 b4 = *(const float4*)(Vb + (size_t)(k0 + lk2) * DH + ln);
    *(float4*)&Bs[lk2][ln] = b4;
    __syncthreads();
#pragma unroll
    for (int kk = 0; kk < 16; kk++){
      float a[4], bv[4];
#pragma unroll
      for (int r = 0; r < 4; r++) a[r] = As[kk][ty*4 + r];
#pragma unroll
      for (int c = 0; c < 4; c++) bv[c] = Bs[kk][tx*4 + c];
#pragma unroll
      for (int r = 0; r < 4; r++)
#pragma unroll
        for (int c = 0; c < 4; c++) acc[r][c] += a[r] * bv[c];
    }
    __syncthreads();
  }
#pragma unroll
  for (int r = 0; r < 4; r++)
#pragma unroll
    for (int c = 0; c < 4; c++){
      const float val = acc[r][c];
      Wb[(size_t)(m0 + ty*4 + r) * DH + tx*4 + c] = val;
      const unsigned short hi = f2bs(val);
      const size_t tidx = ((size_t)bh * DH + tx*4 + c) * MLM + m0 + ty*4 + r;
      w2Th[tidx] = hi;
      w2Tl[tidx] = f2bs(val - bs2f(hi));
    }
}

// ---------------- fused attn1 (MFMA split-bf16): 512 threads / 8 waves, 128-row q tiles.
// Q fragments direct from global; K/W2 4 planes [64][LP]; P dedicated 2 planes [128][LP].
// exp2 softmax.  Output packed (hi|lo) bf16 IN PLACE over q.
__global__ __launch_bounds__(512) void k_attn1(float* __restrict__ qoh,
                                               const unsigned short* __restrict__ klSh,
                                               const unsigned short* __restrict__ klSl,
                                               const float* __restrict__ vf,
                                               const unsigned short* __restrict__ w2Th,
                                               const unsigned short* __restrict__ w2Tl,
                                               const float* __restrict__ wconv){
  extern __shared__ __align__(16) unsigned short sm[];
  unsigned short* Kh  = sm;                 // [64][LP]
  unsigned short* Kl  = sm + 1*64*LP;
  unsigned short* Wth = sm + 2*64*LP;
  unsigned short* Wtl = sm + 3*64*LP;
  unsigned short* Ph  = sm + 4*64*LP;       // [128][LP]
  unsigned short* Pl  = sm + 6*64*LP;       // [128][LP]
  float (*Vs)[68] = (float (*)[68])sm;      // conv phase: [160][68] = 43520 B
  float (*St)[68] = (float (*)[68])sm;      // pack phase: [128][68] = 34816 B
  __shared__ float wcs[33];
  const int it = blockIdx.x, bh = blockIdx.y, h = bh & 7;
  const int i0 = it * 128;
  float* qb = qoh + (size_t)bh * NTOK * DH;
  const int tid = threadIdx.x;
  const int wave = tid >> 6, lane = tid & 63;
  const int lr = lane & 15, quad = lane >> 4;
  if (tid < 33) wcs[tid] = wconv[h*33 + tid];
  // prologue: Q fragments direct from global (fp32 -> split in registers)
  frag_ab qa_h[2], qa_l[2];
#pragma unroll
  for (int ks = 0; ks < 2; ks++){
    const float* qsrc = qb + (size_t)(i0 + wave*16 + lr) * DH + ks*32 + quad*8;
    float4 a0 = *(const float4*)qsrc;
    float4 a1 = *(const float4*)(qsrc + 4);
    float vv[8] = {a0.x, a0.y, a0.z, a0.w, a1.x, a1.y, a1.z, a1.w};
    frag_ab fh, fl;
#pragma unroll
    for (int j = 0; j < 8; j++){
      const unsigned short hb = f2bs(vv[j]);
      fh[j] = (short)hb;
      fl[j] = (short)f2bs(vv[j] - bs2f(hb));
    }
    qa_h[ks] = fh; qa_l[ks] = fl;
  }
  float m_run[4], l_run[4];
  frag_cd o[4];
#pragma unroll
  for (int r = 0; r < 4; r++){ m_run[r] = -1e30f; l_run[r] = 0.f; }
#pragma unroll
  for (int nt = 0; nt < 4; nt++){ frag_cd z = {0.f,0.f,0.f,0.f}; o[nt] = z; }
  const size_t klbase = (size_t)bh * MLM * DH;
  const size_t wtbase = (size_t)bh * DH * MLM;

  for (int jc = 0; jc < 4; jc++){
    const int j0 = jc * 64;
    __syncthreads();   // prev iter's K/W reads done before restage
    // stage K_l chunk and W2^T chunk (512 threads, 2 slots each)
#pragma unroll
    for (int u = 0; u < 2; u++){
      const int f = tid + u * 512, row = f >> 4, c4 = (f & 15) << 2;
      *(ushort4*)&Kh[row*LP + c4]  = *(const ushort4*)(klSh + klbase + (size_t)(j0 + row) * DH + c4);
      *(ushort4*)&Kl[row*LP + c4]  = *(const ushort4*)(klSl + klbase + (size_t)(j0 + row) * DH + c4);
      *(ushort4*)&Wth[row*LP + c4] = *(const ushort4*)(w2Th + wtbase + (size_t)row * MLM + j0 + c4);
      *(ushort4*)&Wtl[row*LP + c4] = *(const ushort4*)(w2Tl + wtbase + (size_t)row * MLM + j0 + c4);
    }
    __syncthreads();
    // S = Q @ K_l^T  (Q from registers)
    frag_cd s[4];
#pragma unroll
    for (int nt = 0; nt < 4; nt++){ frag_cd z = {0.f,0.f,0.f,0.f}; s[nt] = z; }
#pragma unroll
    for (int ks = 0; ks < 2; ks++){
#pragma unroll
      for (int nt = 0; nt < 4; nt++){
        const int bo = (nt*16 + lr)*LP + ks*32 + quad*8;
        frag_ab b_h = *(const frag_ab*)&Kh[bo];
        frag_ab b_l = *(const frag_ab*)&Kl[bo];
        s[nt] = __builtin_amdgcn_mfma_f32_16x16x32_bf16(qa_l[ks], b_h, s[nt], 0, 0, 0);
        s[nt] = __builtin_amdgcn_mfma_f32_16x16x32_bf16(qa_h[ks], b_l, s[nt], 0, 0, 0);
        s[nt] = __builtin_amdgcn_mfma_f32_16x16x32_bf16(qa_h[ks], b_h, s[nt], 0, 0, 0);
      }
    }
    // online softmax (exp2); P into dedicated planes (wave-private rows, no barrier needed)
#pragma unroll
    for (int rg = 0; rg < 4; rg++){
      float mx = fmaxf(fmaxf(s[0][rg], s[1][rg]), fmaxf(s[2][rg], s[3][rg]));
#pragma unroll
      for (int o2 = 8; o2 >= 1; o2 >>= 1) mx = fmaxf(mx, __shfl_xor(mx, o2));
      const float mnew = fmaxf(m_run[rg], mx);
      float e0 = exp2f((s[0][rg] - mnew) * LOG2E), e1 = exp2f((s[1][rg] - mnew) * LOG2E);
      float e2 = exp2f((s[2][rg] - mnew) * LOG2E), e3 = exp2f((s[3][rg] - mnew) * LOG2E);
      float psum = e0 + e1 + e2 + e3;
#pragma unroll
      for (int o2 = 8; o2 >= 1; o2 >>= 1) psum += __shfl_xor(psum, o2);
      const float alpha = exp2f((m_run[rg] - mnew) * LOG2E);
      l_run[rg] = l_run[rg] * alpha + psum;
      m_run[rg] = mnew;
#pragma unroll
      for (int nt = 0; nt < 4; nt++) o[nt][rg] *= alpha;
      const int prow = (wave*16 + quad*4 + rg) * LP;
      float ee[4] = {e0, e1, e2, e3};
#pragma unroll
      for (int nt = 0; nt < 4; nt++){
        const unsigned short hh = f2bs(ee[nt]);
        Ph[prow + nt*16 + lr] = hh;
        Pl[prow + nt*16 + lr] = f2bs(ee[nt] - bs2f(hh));
      }
    }
    // O += P @ W2chunk   (P wave-private rows; W planes synced at stage barrier)
#pragma unroll
    for (int ks = 0; ks < 2; ks++){
      const int ao = (wave*16 + lr)*LP + ks*32 + quad*8;
      frag_ab p_h = *(const frag_ab*)&Ph[ao];
      frag_ab p_l = *(const frag_ab*)&Pl[ao];
#pragma unroll
      for (int nt = 0; nt < 4; nt++){
        const int bo = (nt*16 + lr)*LP + ks*32 + quad*8;
        frag_ab b_h = *(const frag_ab*)&Wth[bo];
        frag_ab b_l = *(const frag_ab*)&Wtl[bo];
        o[nt] = __builtin_amdgcn_mfma_f32_16x16x32_bf16(p_l, b_h, o[nt], 0, 0, 0);
        o[nt] = __builtin_amdgcn_mfma_f32_16x16x32_bf16(p_h, b_l, o[nt], 0, 0, 0);
        o[nt] = __builtin_amdgcn_mfma_f32_16x16x32_bf16(p_h, b_h, o[nt], 0, 0, 0);
      }
    }
  }
  // normalize
#pragma unroll
  for (int rg = 0; rg < 4; rg++){
    const float inv = 1.f / l_run[rg];
#pragma unroll
    for (int nt = 0; nt < 4; nt++) o[nt][rg] *= inv;
  }
  // conv: stage v rows [i0-16, i0+143] (160 rows) into Vs (all LDS planes dead)
  __syncthreads();
#pragma unroll
  for (int u = 0; u < 5; u++){
    const int f = tid + u * 512, row = f >> 4, c4 = (f & 15) << 2;
    const int g = i0 - 16 + row;
    float4 vv = make_float4(0.f, 0.f, 0.f, 0.f);
    if (g >= 0 && g < NTOK) vv = *(const float4*)(vf + ((size_t)bh * NTOK + g) * DH + c4);
    *(float4*)&Vs[row][c4] = vv;
  }
  __syncthreads();
  // sliding-window conv: 36 reads per (nt), reuse across rg.
  // block-local out row R (0..127) uses Vs rows R..R+32
  const int rbase = wave*16 + quad*4;
#pragma unroll
  for (int nt = 0; nt < 4; nt++){
    const int col = nt*16 + lr;
#pragma unroll
    for (int s5 = 0; s5 < 36; s5++){
      const float v = Vs[rbase + s5][col];
#pragma unroll
      for (int rg = 0; rg < 4; rg++){
        const int t = s5 - rg;
        if (t >= 0 && t <= 32) o[nt][rg] += wcs[t] * v;
      }
    }
  }
  // pack (hi|lo) bf16, stage in St, coalesced write over q tile
  __syncthreads();
#pragma unroll
  for (int nt = 0; nt < 4; nt++)
#pragma unroll
    for (int rg = 0; rg < 4; rg++){
      const float val = o[nt][rg];
      const unsigned short hi = f2bs(val);
      const unsigned short lo = f2bs(val - bs2f(hi));
      St[rbase + rg][nt*16 + lr] = __uint_as_float((unsigned int)hi | ((unsigned int)lo << 16));
    }
  __syncthreads();
#pragma unroll
  for (int u = 0; u < 4; u++){
    const int f = tid + u * 512, row = f >> 4, c4 = (f & 15) << 2;
    *(float4*)(qb + (size_t)(i0 + row) * DH + c4) = *(const float4*)&St[row][c4];
  }
}

extern "C" void kernel_launch(void* const* d_in, const int* in_sizes, int n_in,
                              void* d_out, int out_size, void* d_ws, size_t ws_size,
                              hipStream_t stream){
  (void)in_sizes; (void)n_in; (void)out_size; (void)ws_size;
  const float* x     = (const float*)d_in[0];
  const float* wqkv  = (const float*)d_in[1];
  const float* wout  = (const float*)d_in[2];
  const float* bout  = (const float*)d_in[3];
  const float* wconv = (const float*)d_in[4];
  float* outp = (float*)d_out;

  char* base = (char*)d_ws;
  auto alloc = [&](size_t bytes)->char*{
    char* p = base; base += (bytes + 255) & ~(size_t)255; return p;
  };
  const size_t QS = (size_t)BH * NTOK * DH;   // 8388608
  const size_t LS = (size_t)BH * MLM * DH;    // 262144
  const size_t MM = (size_t)BH * MLM * MLM;   // 1048576

  float* qf   = (float*)alloc(QS * 4);   // q; packed oh overwrites in place
  float* vf   = (float*)alloc(QS * 4);
  unsigned short* kSh = (unsigned short*)alloc(QS * 2);
  unsigned short* kSl = (unsigned short*)alloc(QS * 2);
  float* qlf  = (float*)alloc(LS * 4);
  float* klf  = (float*)alloc(LS * 4);
  float* a2   = (float*)alloc(MM * 4);
  float* zb   = (float*)alloc(MM * 4);
  float* z2   = (float*)alloc(MM * 4);
  float* xz   = (float*)alloc(MM * 4);
  float* t2   = (float*)alloc(MM * 4);
  float* t4   = (float*)alloc(MM * 4);
  float* part = (float*)alloc(64 * 4);
  // union region: pinv transpose-split planes (10 x MM ushorts = 21.0 MB) alias pbuf
  // (flash partials, 16 x 16 x 256 x 68 x 4 B = 17.8 MB).  Planes dead before k_flash.
  char* un = alloc(10 * MM * 2);
  unsigned short* pl0 = (unsigned short*)un;
  unsigned short* zbTh = pl0 + 0*MM; unsigned short* zbTl = pl0 + 1*MM;
  unsigned short* z2Th = pl0 + 2*MM; unsigned short* z2Tl = pl0 + 3*MM;
  unsigned short* xzTh = pl0 + 4*MM; unsigned short* xzTl = pl0 + 5*MM;
  unsigned short* t2Th = pl0 + 6*MM; unsigned short* t2Tl = pl0 + 7*MM;
  unsigned short* t4Th = pl0 + 8*MM; unsigned short* t4Tl = pl0 + 9*MM;
  float* pbuf = (float*)un;
  float* av   = (float*)alloc(LS * 4);
  float* w2   = (float*)alloc(LS * 4);
  unsigned short* wqTh = (unsigned short*)alloc((size_t)1536 * 512 * 2);
  unsigned short* wqTl = (unsigned short*)alloc((size_t)1536 * 512 * 2);
  unsigned short* woTh = (unsigned short*)alloc((size_t)512 * 512 * 2);
  unsigned short* woTl = (unsigned short*)alloc((size_t)512 * 512 * 2);
  unsigned short* qlSh = (unsigned short*)alloc(LS * 2);
  unsigned short* qlSl = (unsigned short*)alloc(LS * 2);
  unsigned short* klSh = (unsigned short*)alloc(LS * 2);
  unsigned short* klSl = (unsigned short*)alloc(LS * 2);
  unsigned short* w2Th = (unsigned short*)alloc(LS * 2);
  unsigned short* w2Tl = (unsigned short*)alloc(LS * 2);
  unsigned short* vTh  = (unsigned short*)alloc(QS * 2);
  unsigned short* vTl  = (unsigned short*)alloc(QS * 2);
  // xh/xl alias vTh/vTl: consumed by k_mfma_qkv before k_vtrans overwrites.
  unsigned short* xh = vTh;
  unsigned short* xl = vTl;

  // 0. weight transpose + split (wqkv pre-swizzled for gload_lds; wout NOT); x split+swizzled
  k_splitw<<<1536 * 512 / 256, 256, 0, stream>>>(wqkv, 512, 1536, wqTh, wqTl, 1);
  k_splitw<<<512 * 512 / 256, 256, 0, stream>>>(wout, 512, 512, woTh, woTl, 0);
  k_splitx<<<8192, 256, 0, stream>>>(x, xh, xl);
  // 1. QKV projection (MFMA split-bf16, double-buffered gload_lds, XCD swizzle)
  k_mfma_qkv<<<dim3(1536), 256, 0, stream>>>(xh, xl, wqTh, wqTl, qf, kSh, kSl, vf);
  // 1b. v transpose+split for MFMA PV operand (overwrites xh/xl)
  k_vtrans<<<dim3(NTOK / 64, BH), 256, 0, stream>>>(vf, vTh, vTl);
  // 2. landmarks (+ split copies)
  k_land2<<<dim3(BH * MLM, 2), 64, 0, stream>>>(qf, kSh, kSl, qlf, klf, qlSh, qlSl, klSh, klSl);
  // 3. sim2 + softmax -> attn2
  k_sim2<<<dim3(4, 4, BH), 256, 0, stream>>>(qlf, klf, xz);
  k_softmax256<<<BH * MLM, 256, 0, stream>>>(xz, a2);
  // 4. pinv init (z0 also emits z^T split)
  k_colrow<<<BH, 256, 0, stream>>>(a2, part);
  k_z0<<<BH * MLM, 256, 0, stream>>>(a2, part, zb, zbTh, zbTl);
  // 5. 6 Newton-Schulz iterations (24 dispatches, 512-block prefetch GEMM, 3-term)
  {
    float* zc = zb;  unsigned short* zcTh = zbTh; unsigned short* zcTl = zbTl;
    float* zn = z2;  unsigned short* znTh = z2Th; unsigned short* znTl = z2Tl;
    for (int it = 0; it < 6; ++it){
      k_gemm256m<<<dim3(32, BH), 256, 0, stream>>>(a2, zcTh, zcTl, a2, xz, xzTh, xzTl, 0.f, -1.f, 1);
      k_gemm256m<<<dim3(32, BH), 256, 0, stream>>>(xz, xzTh, xzTl, xz, t2, t2Th, t2Tl, 7.f, 1.f, 0);
      k_gemm256m<<<dim3(32, BH), 256, 0, stream>>>(xz, t2Th, t2Tl, xz, t4, t4Th, t4Tl, 15.f, 1.f, 0);
      k_gemm256m<<<dim3(32, BH), 256, 0, stream>>>(zc, t4Th, t4Tl, zc, zn, znTh, znTl, 13.f, 0.25f, 1);
      float* tf = zc; zc = zn; zn = tf;
      unsigned short* th = zcTh; zcTh = znTh; znTh = th;
      unsigned short* tl = zcTl; zcTl = znTl; znTl = tl;
    }
  }
  const size_t FLASH_LDS = (size_t)4 * 64 * LP * 2;   // 36864 B
  const size_t ATTN1_LDS = (size_t)8 * 64 * LP * 2;   // 73728 B (K/W 4 planes + P 2x128-row)
  // 6. flash attn3@v (MFMA, all pre-split; kc split 16-way) + combine
  k_flash<<<dim3(16, 4, BH), 256, FLASH_LDS, stream>>>(qlSh, qlSl, kSh, kSl, vTh, vTl, pbuf);
  k_comb<<<BH * MLM / 4, 256, 0, stream>>>(pbuf, av);
  // 7. w2 = z_final @ av (final z lands in zb after 6 iters; + transposed split for attn1)
  k_w2<<<dim3(4, BH), 256, 0, stream>>>(zb, av, w2, w2Th, w2Tl);
  // 8. fused flash attn1 + conv (MFMA, 512 threads / 128-row tiles); packed oh overwrites q
  k_attn1<<<dim3(64, BH), 512, ATTN1_LDS, stream>>>(qf, klSh, klSl, vf, w2Th, w2Tl, wconv);
  // 9. output projection + residual (MFMA split-bf16)
  k_mfma_final<<<dim3(512), 256, 0, stream>>>((const unsigned int*)qf, woTh, woTl, x, bout, outp);
}

// Round 13
// 658.058 us; speedup vs baseline: 1.1296x; 1.0281x over previous
//
#include <hip/hip_runtime.h>
#include <hip/hip_bf16.h>

#define BH 16
#define NTOK 8192
#define NHEAD 8
#define DH 64
#define MLM 256
#define QSCALE 0.125f
#define LP 72   // ushort stride for flash LDS tiles; MUST be >= 64 (row holds 64 ushorts of K-dim)
#define LOG2E 1.4426950408889634f

typedef unsigned short ushort_t;
using frag_ab = __attribute__((ext_vector_type(8))) short;   // 8 bf16 (4 VGPRs)
using frag_cd = __attribute__((ext_vector_type(4))) float;   // 4 fp32 acc

__device__ __forceinline__ unsigned short f2bs(float f){
  __hip_bfloat16 h = __float2bfloat16(f);
  return *(unsigned short*)&h;
}
__device__ __forceinline__ float bs2f(unsigned short u){
  union { unsigned int i; float f; } cv; cv.i = ((unsigned int)u) << 16; return cv.f;
}

// async global->LDS, 16B per lane.  LDS dest = wave-uniform base + lane*16 (HW).
__device__ __forceinline__ void gl_lds16(const unsigned short* g, unsigned short* l){
  __builtin_amdgcn_global_load_lds((const __attribute__((address_space(1))) unsigned int*)(const void*)g,
                                   (__attribute__((address_space(3))) unsigned int*)(void*)l, 16, 0, 0);
}

// ---------------- weight transpose + hi/lo bf16 split: in[K][N] -> outh/outl [N][K]
// swz!=0: pre-swizzle 16B slot within each 32-col K-group (slot ^= row&3) for gload_lds consumers
__global__ __launch_bounds__(256) void k_splitw(const float* __restrict__ in, int K, int N,
                                                unsigned short* __restrict__ oh,
                                                unsigned short* __restrict__ ol, int swz){
  const int idx = blockIdx.x * 256 + threadIdx.x;   // over N*K
  const int n = idx / K, k = idx - n * K;
  const float v = in[(size_t)k * N + n];
  const unsigned short hi = f2bs(v);
  int kd = k;
  if (swz){
    const int q = (k >> 3) & 3;
    kd = (k & ~31) | (((q ^ (n & 3)) & 3) << 3) | (k & 7);
  }
  oh[(size_t)n * K + kd] = hi;
  ol[(size_t)n * K + kd] = f2bs(v - bs2f(hi));
}

// ---------------- plain hi/lo split of x, PRE-SWIZZLED for gload_lds (slot ^= row&3)
__global__ __launch_bounds__(256) void k_splitx(const float* __restrict__ in,
                                                unsigned short* __restrict__ oh,
                                                unsigned short* __restrict__ ol){
  const size_t i4 = ((size_t)blockIdx.x * 256 + threadIdx.x) * 4;
  const int row = (int)(i4 >> 9);
  const int col = (int)(i4 & 511);
  const int q = (col >> 3) & 3;
  const int cd = (col & ~31) | (((q ^ (row & 3)) & 3) << 3) | (col & 7);
  const size_t o4 = ((size_t)row << 9) + cd;
  float4 v = *(const float4*)(in + i4);
  const unsigned short h0 = f2bs(v.x), h1 = f2bs(v.y), h2 = f2bs(v.z), h3 = f2bs(v.w);
  *(ushort4*)(oh + o4) = make_ushort4(h0, h1, h2, h3);
  *(ushort4*)(ol + o4) = make_ushort4(f2bs(v.x - bs2f(h0)), f2bs(v.y - bs2f(h1)),
                                      f2bs(v.z - bs2f(h2)), f2bs(v.w - bs2f(h3)));
}

// ---------------- MFMA split-bf16 GEMM: qkv.  A = x pre-split+swizzled [16384][512],
// B = wqkvT pre-split+swizzled [1536][512].  128x128 tile, 4 waves, 64x64 each.
// LDS DOUBLE-BUFFER 2-phase; XCD-aware bijective block swizzle (m-major chunks per XCD).
__global__ __launch_bounds__(256) void k_mfma_qkv(const unsigned short* __restrict__ xh,
                                                  const unsigned short* __restrict__ xl,
                                                  const unsigned short* __restrict__ bth,
                                                  const unsigned short* __restrict__ btl,
                                                  float* __restrict__ q,
                                                  unsigned short* __restrict__ kSh,
                                                  unsigned short* __restrict__ kSl,
                                                  float* __restrict__ v){
  // XCD swizzle: 1536 blocks, 8 XCDs, 192/chunk.
  const int orig = blockIdx.x;
  const int sw = (orig & 7) * 192 + (orig >> 3);
  const int n0 = (sw % 12) * 128;   // over 1536
  const int m0 = (sw / 12) * 128;   // over 16384
  __shared__ unsigned short SB[2][4 * 128 * 32];   // 2 buffers x {Ah,Al,Bh,Bl} planes
  const int tid = threadIdx.x;
  const int wave = tid >> 6, lane = tid & 63;
  const int wm = wave >> 1, wn = wave & 1;
  const int lr = lane & 15, quad = lane >> 4;
  const int cswz = ((quad ^ (lr & 3)) & 3) << 3;   // swizzled 8-ushort slot
  // staging: wave w owns plane w
  const unsigned short* gsrc = (wave == 0) ? xh : (wave == 1) ? xl : (wave == 2) ? bth : btl;
  const int R0 = (wave < 2) ? m0 : n0;
  const int lrow = lane >> 2, lslot = (lane & 3) << 3;
  const int pbase = wave * 4096;
  frag_cd acc[4][4];
#pragma unroll
  for (int mt = 0; mt < 4; mt++)
#pragma unroll
    for (int nt = 0; nt < 4; nt++){
      frag_cd z = {0.f, 0.f, 0.f, 0.f};
      acc[mt][nt] = z;
    }
  // prologue: stage k0=0 into buf 0
#pragma unroll
  for (int u = 0; u < 8; u++)
    gl_lds16(gsrc + (size_t)(R0 + u*16 + lrow) * 512 + lslot, &SB[0][pbase] + u * 512);
  __syncthreads();
  int cur = 0;
  for (int k0 = 0; k0 < 512; k0 += 32){
    // issue next K-step's loads into the other buffer (overlap with MFMA below)
    if (k0 + 32 < 512){
#pragma unroll
      for (int u = 0; u < 8; u++)
        gl_lds16(gsrc + (size_t)(R0 + u*16 + lrow) * 512 + k0 + 32 + lslot,
                 &SB[cur ^ 1][pbase] + u * 512);
    }
    const unsigned short* Ah = &SB[cur][0];
    const unsigned short* Al = &SB[cur][4096];
    const unsigned short* Bh = &SB[cur][8192];
    const unsigned short* Bl = &SB[cur][12288];
    frag_ab a_h[4], a_l[4], b_h[4], b_l[4];
#pragma unroll
    for (int t = 0; t < 4; t++){
      const int ar = (wm*64 + t*16 + lr) << 5;
      const int br = (wn*64 + t*16 + lr) << 5;
      a_h[t] = *(const frag_ab*)&Ah[ar + cswz];
      a_l[t] = *(const frag_ab*)&Al[ar + cswz];
      b_h[t] = *(const frag_ab*)&Bh[br + cswz];
      b_l[t] = *(const frag_ab*)&Bl[br + cswz];
    }
#pragma unroll
    for (int mt = 0; mt < 4; mt++)
#pragma unroll
      for (int nt = 0; nt < 4; nt++){
        acc[mt][nt] = __builtin_amdgcn_mfma_f32_16x16x32_bf16(a_l[mt], b_h[nt], acc[mt][nt], 0, 0, 0);
        acc[mt][nt] = __builtin_amdgcn_mfma_f32_16x16x32_bf16(a_h[mt], b_l[nt], acc[mt][nt], 0, 0, 0);
        acc[mt][nt] = __builtin_amdgcn_mfma_f32_16x16x32_bf16(a_h[mt], b_h[nt], acc[mt][nt], 0, 0, 0);
      }
    __syncthreads();   // drains vmcnt (next buffer landed) + everyone done reading cur
    cur ^= 1;
  }
  // epilogue: D row = quad*4+reg, col = lane&15
#pragma unroll
  for (int mt = 0; mt < 4; mt++)
#pragma unroll
    for (int nt = 0; nt < 4; nt++)
#pragma unroll
      for (int rg = 0; rg < 4; rg++){
        const int row = m0 + wm*64 + mt*16 + quad*4 + rg;
        const int col = n0 + wn*64 + nt*16 + lr;
        const int bb = row >> 13, i = row & 8191;
        const int which = col >> 9;
        const int cc = col & 511;
        const int h = cc >> 6, d = cc & 63;
        const size_t off = (((size_t)(bb * NHEAD + h)) * NTOK + i) * DH + d;
        const float val = acc[mt][nt][rg];
        if (which == 0)      q[off] = val * QSCALE;
        else if (which == 1){
          const unsigned short hi = f2bs(val);
          kSh[off] = hi; kSl[off] = f2bs(val - bs2f(hi));
        }
        else                 v[off] = val;
      }
}

// ---------------- MFMA split-bf16 GEMM: final.  A = oh packed (hi|lo in uint32 slots of qf,
// layout [bh][8192][64]), B = woutT hi/lo [512][512].  out = A@B + bout + x.
// A register-prefetched one K-step ahead; XCD-aware bijective block swizzle.
__global__ __launch_bounds__(256) void k_mfma_final(const unsigned int* __restrict__ qpk,
                                                    const unsigned short* __restrict__ bth,
                                                    const unsigned short* __restrict__ btl,
                                                    const float* __restrict__ xin,
                                                    const float* __restrict__ bout,
                                                    float* __restrict__ outp){
  // XCD swizzle: 512 blocks, 8 XCDs, 64/chunk, m-major within chunk.
  const int orig = blockIdx.x;
  const int sw = (orig & 7) * 64 + (orig >> 3);
  const int n0 = (sw & 3) * 128;    // over 512
  const int m0 = (sw >> 2) * 128;   // over 16384
  __shared__ unsigned short Ah[128][40], Al[128][40], Bh[128][40], Bl[128][40];
  const int tid = threadIdx.x;
  const int wave = tid >> 6, lane = tid & 63;
  const int wm = wave >> 1, wn = wave & 1;
  const int lr = lane & 15, quad = lane >> 4, koff = quad * 8;
  const int bb = m0 >> 13;
  frag_cd acc[4][4];
#pragma unroll
  for (int mt = 0; mt < 4; mt++)
#pragma unroll
    for (int nt = 0; nt < 4; nt++){
      frag_cd z = {0.f, 0.f, 0.f, 0.f};
      acc[mt][nt] = z;
    }
  const int arow = tid >> 3, ac4 = (tid & 7) << 2;     // A: 4 slots of 32 rows
  const int brow = tid >> 2, bch = (tid & 3) << 3;     // B: 2 slots of 64 rows
  uint4 pw[4];
  // prologue: prefetch A regs for k0=0
#pragma unroll
  for (int u = 0; u < 4; u++){
    const int row = arow + u * 32;
    const int i = (m0 + row) & 8191;
    pw[u] = *(const uint4*)(qpk + (((size_t)(bb * NHEAD + 0)) * NTOK + i) * DH + 0 + ac4);
  }
  for (int k0 = 0; k0 < 512; k0 += 32){
    __syncthreads();
    // write LDS from prefetched A regs
#pragma unroll
    for (int u = 0; u < 4; u++){
      const int row = arow + u * 32;
      *(ushort4*)&Ah[row][ac4] = make_ushort4((unsigned short)pw[u].x, (unsigned short)pw[u].y,
                                              (unsigned short)pw[u].z, (unsigned short)pw[u].w);
      *(ushort4*)&Al[row][ac4] = make_ushort4((unsigned short)(pw[u].x >> 16), (unsigned short)(pw[u].y >> 16),
                                              (unsigned short)(pw[u].z >> 16), (unsigned short)(pw[u].w >> 16));
    }
    // stage B (pre-split copies, L2-hot)
#pragma unroll
    for (int u = 0; u < 2; u++){
      const int row = brow + u * 64;
      *(uint4*)&Bh[row][bch] = *(const uint4*)(bth + (size_t)(n0 + row) * 512 + k0 + bch);
      *(uint4*)&Bl[row][bch] = *(const uint4*)(btl + (size_t)(n0 + row) * 512 + k0 + bch);
    }
    __syncthreads();
    // prefetch A regs for k0+32 (loads in flight during MFMA)
    if (k0 + 32 < 512){
      const int hn = (k0 + 32) >> 6, dbn = (k0 + 32) & 63;
#pragma unroll
      for (int u = 0; u < 4; u++){
        const int row = arow + u * 32;
        const int i = (m0 + row) & 8191;
        pw[u] = *(const uint4*)(qpk + (((size_t)(bb * NHEAD + hn)) * NTOK + i) * DH + dbn + ac4);
      }
    }
    frag_ab a_h[4], a_l[4], b_h[4], b_l[4];
#pragma unroll
    for (int t = 0; t < 4; t++){
      a_h[t] = *(const frag_ab*)&Ah[wm*64 + t*16 + lr][koff];
      a_l[t] = *(const frag_ab*)&Al[wm*64 + t*16 + lr][koff];
      b_h[t] = *(const frag_ab*)&Bh[wn*64 + t*16 + lr][koff];
      b_l[t] = *(const frag_ab*)&Bl[wn*64 + t*16 + lr][koff];
    }
#pragma unroll
    for (int mt = 0; mt < 4; mt++)
#pragma unroll
      for (int nt = 0; nt < 4; nt++){
        acc[mt][nt] = __builtin_amdgcn_mfma_f32_16x16x32_bf16(a_l[mt], b_h[nt], acc[mt][nt], 0, 0, 0);
        acc[mt][nt] = __builtin_amdgcn_mfma_f32_16x16x32_bf16(a_h[mt], b_l[nt], acc[mt][nt], 0, 0, 0);
        acc[mt][nt] = __builtin_amdgcn_mfma_f32_16x16x32_bf16(a_h[mt], b_h[nt], acc[mt][nt], 0, 0, 0);
      }
  }
#pragma unroll
  for (int mt = 0; mt < 4; mt++)
#pragma unroll
    for (int nt = 0; nt < 4; nt++)
#pragma unroll
      for (int rg = 0; rg < 4; rg++){
        const int row = m0 + wm*64 + mt*16 + quad*4 + rg;
        const int col = n0 + wn*64 + nt*16 + lr;
        outp[(size_t)row * 512 + col] = acc[mt][nt][rg] + bout[col] + xin[(size_t)row * 512 + col];
      }
}

// ---------------- landmark means for q and k in one launch (grid.y selects)
// k is read from pre-split planes; also emits hi/lo bf16 split copies
__global__ __launch_bounds__(64) void k_land2(const float* __restrict__ qf,
                                              const unsigned short* __restrict__ kSh,
                                              const unsigned short* __restrict__ kSl,
                                              float* __restrict__ qlf, float* __restrict__ klf,
                                              unsigned short* __restrict__ qlSh, unsigned short* __restrict__ qlSl,
                                              unsigned short* __restrict__ klSh, unsigned short* __restrict__ klSl){
  const int isK = blockIdx.y;
  float* dst = isK ? klf : qlf;
  unsigned short* dh = isK ? klSh : qlSh;
  unsigned short* dl = isK ? klSl : qlSl;
  const int bh = blockIdx.x >> 8;
  const int j  = blockIdx.x & 255;
  const int d  = threadIdx.x;
  const size_t base = ((size_t)bh * NTOK + (size_t)j * 32) * DH + d;
  float s = 0.f;
  if (!isK){
    const float* p = qf + base;
#pragma unroll
    for (int t = 0; t < 32; t++) s += p[t * DH];
  } else {
    const unsigned short* ph = kSh + base;
    const unsigned short* pl = kSl + base;
#pragma unroll
    for (int t = 0; t < 32; t++) s += bs2f(ph[t * DH]) + bs2f(pl[t * DH]);
  }
  const float val = s * (1.f / 32.f);
  const size_t oidx = ((size_t)bh * MLM + j) * DH + d;
  dst[oidx] = val;
  const unsigned short hi = f2bs(val);
  dh[oidx] = hi;
  dl[oidx] = f2bs(val - bs2f(hi));
}

// ---------------- transpose + split v: [bh][8192][64] fp32 -> vTh/vTl [bh][64][8192] bf16
__global__ __launch_bounds__(256) void k_vtrans(const float* __restrict__ vf,
                                                unsigned short* __restrict__ vTh,
                                                unsigned short* __restrict__ vTl){
  __shared__ float T[64][68];
  const int j0 = blockIdx.x * 64, bh = blockIdx.y;
  const int tid = threadIdx.x;
#pragma unroll
  for (int u = 0; u < 4; u++){
    const int f = tid + u * 256, row = f >> 4, c4 = (f & 15) << 2;
    *(float4*)&T[row][c4] = *(const float4*)(vf + ((size_t)bh * NTOK + j0 + row) * DH + c4);
  }
  __syncthreads();
#pragma unroll
  for (int u = 0; u < 4; u++){
    const int f = tid + u * 256, d = f >> 4, j4 = (f & 15) << 2;
    const float v0 = T[j4+0][d], v1 = T[j4+1][d], v2 = T[j4+2][d], v3 = T[j4+3][d];
    const unsigned short h0 = f2bs(v0), h1 = f2bs(v1), h2 = f2bs(v2), h3 = f2bs(v3);
    const size_t off = ((size_t)bh * DH + d) * NTOK + j0 + j4;
    *(ushort4*)(vTh + off) = make_ushort4(h0, h1, h2, h3);
    *(ushort4*)(vTl + off) = make_ushort4(f2bs(v0 - bs2f(h0)), f2bs(v1 - bs2f(h1)),
                                          f2bs(v2 - bs2f(h2)), f2bs(v3 - bs2f(h3)));
  }
}

// ---------------- sim2 = ql @ kl^T (fp32, K=64), batched [bh][256][256]
__global__ __launch_bounds__(256) void k_sim2(const float* __restrict__ qlf,
                                              const float* __restrict__ klf,
                                              float* __restrict__ C){
  const int bh = blockIdx.z;
  const float* Ab = qlf + (size_t)bh * MLM * DH;
  const float* Bb = klf + (size_t)bh * MLM * DH;
  float* Cb = C + (size_t)bh * MLM * MLM;
  const int n0 = blockIdx.x * 64;
  const int m0 = blockIdx.y * 64;
  __shared__ float As[16][64];
  __shared__ float Bs[16][64];
  const int tid = threadIdx.x, ty = tid >> 4, tx = tid & 15;
  const int lm = tid >> 2, lk = (tid & 3) << 2;
  float acc[4][4] = {};
  for (int k0 = 0; k0 < 64; k0 += 16){
    float4 a4 = *(const float4*)(Ab + (size_t)(m0 + lm) * DH + k0 + lk);
    As[lk+0][lm] = a4.x; As[lk+1][lm] = a4.y; As[lk+2][lm] = a4.z; As[lk+3][lm] = a4.w;
    float4 b4 = *(const float4*)(Bb + (size_t)(n0 + lm) * DH + k0 + lk);
    Bs[lk+0][lm] = b4.x; Bs[lk+1][lm] = b4.y; Bs[lk+2][lm] = b4.z; Bs[lk+3][lm] = b4.w;
    __syncthreads();
#pragma unroll
    for (int kk = 0; kk < 16; kk++){
      float a[4], bv[4];
#pragma unroll
      for (int r = 0; r < 4; r++) a[r] = As[kk][ty*4 + r];
#pragma unroll
      for (int c = 0; c < 4; c++) bv[c] = Bs[kk][tx*4 + c];
#pragma unroll
      for (int r = 0; r < 4; r++)
#pragma unroll
        for (int c = 0; c < 4; c++) acc[r][c] += a[r] * bv[c];
    }
    __syncthreads();
  }
#pragma unroll
  for (int r = 0; r < 4; r++)
#pragma unroll
    for (int c = 0; c < 4; c++)
      Cb[(size_t)(m0 + ty*4 + r) * MLM + n0 + tx*4 + c] = acc[r][c];
}

// ---------------- row softmax over 256
__global__ __launch_bounds__(256) void k_softmax256(const float* __restrict__ in, float* __restrict__ outp){
  const int row = blockIdx.x;
  const int t = threadIdx.x;
  float v = in[(size_t)row * 256 + t];
  __shared__ float red[256];
  red[t] = v; __syncthreads();
  for (int o = 128; o > 0; o >>= 1){ if (t < o) red[t] = fmaxf(red[t], red[t+o]); __syncthreads(); }
  float mx = red[0]; __syncthreads();
  float e = exp2f((v - mx) * LOG2E);
  red[t] = e; __syncthreads();
  for (int o = 128; o > 0; o >>= 1){ if (t < o) red[t] += red[t+o]; __syncthreads(); }
  outp[(size_t)row * 256 + t] = e / red[0];
}

// ---------------- per-batch COLUMN abs-sum maxima (row-sums of softmax are exactly 1)
__global__ __launch_bounds__(256) void k_colrow(const float* __restrict__ a2, float* __restrict__ part){
  const int bh = blockIdx.x;
  const int t = threadIdx.x;
  const float* p = a2 + (size_t)bh * 65536;
  float cs = 0.f;
  for (int i = 0; i < 256; i++) cs += fabsf(p[(size_t)i * 256 + t]);
  __shared__ float r2[256];
  r2[t] = cs; __syncthreads();
  for (int o = 128; o > 0; o >>= 1){
    if (t < o) r2[t] = fmaxf(r2[t], r2[t+o]);
    __syncthreads();
  }
  if (t == 0) part[bh] = r2[0];
}

// ---------------- z0 = a2^T * (1/(col*row)); col==1 so sc = 1/max_colsum
// also emits z^T pre-split (= a2 scaled, no transpose needed)
__global__ __launch_bounds__(256) void k_z0(const float* __restrict__ a2, const float* __restrict__ part,
                                            float* __restrict__ z,
                                            unsigned short* __restrict__ zTh,
                                            unsigned short* __restrict__ zTl){
  const int bh = blockIdx.x >> 8;
  const int i  = blockIdx.x & 255;
  const int j  = threadIdx.x;
  float m2 = 0.f;
#pragma unroll
  for (int t = 0; t < 16; t++) m2 = fmaxf(m2, part[t]);
  const float sc = 1.f / m2;
  const size_t ridx = ((size_t)bh * 256 + j) * 256 + i;
  const float val = a2[ridx] * sc;
  z[((size_t)bh * 256 + i) * 256 + j] = val;
  const unsigned short hi = f2bs(val);
  zTh[ridx] = hi;
  zTl[ridx] = f2bs(val - bs2f(hi));
}

// ---------------- batched 256^3 MFMA split-bf16 GEMM (NS chain step):
// C = s0*(c0*D - A@B), B pre-transposed+split.  32x64 tile -> 512 blocks (2/CU),
// register prefetch double-buffer, 3-term split, LDS-transposed coalesced C^T epilogue.
__global__ __launch_bounds__(256) void k_gemm256m(const float* __restrict__ A,
                                                  const unsigned short* __restrict__ BTh,
                                                  const unsigned short* __restrict__ BTl,
                                                  const float* __restrict__ D,
                                                  float* __restrict__ C,
                                                  unsigned short* __restrict__ CTh,
                                                  unsigned short* __restrict__ CTl,
                                                  float c0, float s0, int wC){
  __shared__ unsigned short Ah[32][40], Al[32][40], Bh[64][40], Bl[64][40];
  __shared__ float Ct[64][33];
  const int bh = blockIdx.y, tile = blockIdx.x;
  const int m0 = (tile >> 2) * 32, n0 = (tile & 3) * 64;
  const size_t bo = (size_t)bh * 65536;
  const int tid = threadIdx.x;
  const int wave = tid >> 6, lane = tid & 63;
  const int wm = wave >> 1, wn = wave & 1;
  const int lr = lane & 15, quad = lane >> 4, koff = quad * 8;
  const int ar = tid >> 3, ac = (tid & 7) << 2;     // A tile: 32 rows x 32 cols fp32
  const int br = tid >> 2, bc = (tid & 3) << 3;     // B tile: 64 rows x 32 cols ushort
  frag_cd acc[2];
  { frag_cd z = {0.f,0.f,0.f,0.f}; acc[0] = z; acc[1] = z; }
  float4 ra  = *(const float4*)(A + bo + (size_t)(m0 + ar) * 256 + ac);
  uint4  rbh = *(const uint4*)(BTh + bo + (size_t)(n0 + br) * 256 + bc);
  uint4  rbl = *(const uint4*)(BTl + bo + (size_t)(n0 + br) * 256 + bc);
  for (int k0 = 0; k0 < 256; k0 += 32){
    __syncthreads();
    {
      const unsigned short h0=f2bs(ra.x),h1=f2bs(ra.y),h2=f2bs(ra.z),h3=f2bs(ra.w);
      *(ushort4*)&Ah[ar][ac] = make_ushort4(h0,h1,h2,h3);
      *(ushort4*)&Al[ar][ac] = make_ushort4(f2bs(ra.x-bs2f(h0)), f2bs(ra.y-bs2f(h1)),
                                            f2bs(ra.z-bs2f(h2)), f2bs(ra.w-bs2f(h3)));
      *(uint4*)&Bh[br][bc] = rbh;
      *(uint4*)&Bl[br][bc] = rbl;
    }
    __syncthreads();
    if (k0 < 224){
      ra  = *(const float4*)(A + bo + (size_t)(m0 + ar) * 256 + k0 + 32 + ac);
      rbh = *(const uint4*)(BTh + bo + (size_t)(n0 + br) * 256 + k0 + 32 + bc);
      rbl = *(const uint4*)(BTl + bo + (size_t)(n0 + br) * 256 + k0 + 32 + bc);
    }
    frag_ab a_h = *(const frag_ab*)&Ah[wm*16 + lr][koff];
    frag_ab a_l = *(const frag_ab*)&Al[wm*16 + lr][koff];
#pragma unroll
    for (int b = 0; b < 2; b++){
      frag_ab b_h = *(const frag_ab*)&Bh[wn*32 + b*16 + lr][koff];
      frag_ab b_l = *(const frag_ab*)&Bl[wn*32 + b*16 + lr][koff];
      acc[b] = __builtin_amdgcn_mfma_f32_16x16x32_bf16(a_l, b_h, acc[b], 0, 0, 0);
      acc[b] = __builtin_amdgcn_mfma_f32_16x16x32_bf16(a_h, b_l, acc[b], 0, 0, 0);
      acc[b] = __builtin_amdgcn_mfma_f32_16x16x32_bf16(a_h, b_h, acc[b], 0, 0, 0);
    }
  }
  // epilogue: fp32 C direct; C^T via LDS transpose for coalesced split writes
  const bool useD = (c0 != 0.f);
#pragma unroll
  for (int b = 0; b < 2; b++)
#pragma unroll
    for (int rg = 0; rg < 4; rg++){
      const int row = m0 + wm*16 + quad*4 + rg;
      const int col = n0 + wn*32 + b*16 + lr;
      const size_t idx = bo + (size_t)row * 256 + col;
      const float dv = useD ? D[idx] : 0.f;
      const float val = s0 * (c0 * dv - acc[b][rg]);
      if (wC) C[idx] = val;
      Ct[col - n0][row - m0] = val;
    }
  __syncthreads();
  {
    const int cr = tid >> 2, sg = (tid & 3) << 3;
    unsigned int ph[4], pl[4];
#pragma unroll
    for (int j = 0; j < 4; j++){
      const float v0 = Ct[cr][sg + 2*j], v1 = Ct[cr][sg + 2*j + 1];
      const unsigned short h0 = f2bs(v0), h1 = f2bs(v1);
      ph[j] = (unsigned int)h0 | ((unsigned int)h1 << 16);
      pl[j] = (unsigned int)f2bs(v0 - bs2f(h0)) | ((unsigned int)f2bs(v1 - bs2f(h1)) << 16);
    }
    const size_t tb = bo + (size_t)(n0 + cr) * 256 + m0 + sg;
    *(uint4*)(CTh + tb) = make_uint4(ph[0], ph[1], ph[2], ph[3]);
    *(uint4*)(CTl + tb) = make_uint4(pl[0], pl[1], pl[2], pl[3]);
  }
}

// ---------------- flash (MFMA split-bf16): partial online-softmax (attn3 @ v) per (kc, mtile, bh)
// 4 waves, each owns 16 q-rows x full 64-col chunk.  Q lifted to registers; P aliases K planes.
// LDS = 4 planes (36864 B).  kc split 16-way.  exp2 softmax.  setprio around MFMA.
__global__ __launch_bounds__(256) void k_flash(const unsigned short* __restrict__ qlSh,
                                               const unsigned short* __restrict__ qlSl,
                                               const unsigned short* __restrict__ kSh,
                                               const unsigned short* __restrict__ kSl,
                                               const unsigned short* __restrict__ vTh,
                                               const unsigned short* __restrict__ vTl,
                                               float* __restrict__ pbuf){
  extern __shared__ __align__(16) unsigned short sm[];
  unsigned short* Kh  = sm;                 // Q staging, then K, then P (hi)
  unsigned short* Kl  = sm + 1*64*LP;       // Q staging, then K, then P (lo)
  unsigned short* Wth = sm + 2*64*LP;
  unsigned short* Wtl = sm + 3*64*LP;
  const int kc = blockIdx.x, mt = blockIdx.y, bh = blockIdx.z;
  const int m0 = mt * 64, kbeg = kc * 512;
  const int tid = threadIdx.x;
  const int wave = tid >> 6, lane = tid & 63;
  const int lr = lane & 15, quad = lane >> 4;
  const size_t qbase = (size_t)bh * MLM * DH;
  const size_t kb  = (size_t)bh * NTOK * DH;
  const size_t vtb = (size_t)bh * DH * NTOK;
  // prologue: stage Q through K planes, lift own-wave fragments to registers
#pragma unroll
  for (int u = 0; u < 4; u++){
    const int f = tid + u * 256, row = f >> 4, c4 = (f & 15) << 2;
    *(ushort4*)&Kh[row*LP + c4] = *(const ushort4*)(qlSh + qbase + (size_t)(m0 + row) * DH + c4);
    *(ushort4*)&Kl[row*LP + c4] = *(const ushort4*)(qlSl + qbase + (size_t)(m0 + row) * DH + c4);
  }
  __syncthreads();
  frag_ab qa_h[2], qa_l[2];
#pragma unroll
  for (int ks = 0; ks < 2; ks++){
    const int ao = (wave*16 + lr)*LP + ks*32 + quad*8;
    qa_h[ks] = *(const frag_ab*)&Kh[ao];
    qa_l[ks] = *(const frag_ab*)&Kl[ao];
  }
  float m_run[4], l_run[4];
  frag_cd o[4];
#pragma unroll
  for (int r = 0; r < 4; r++){ m_run[r] = -1e30f; l_run[r] = 0.f; }
#pragma unroll
  for (int nt = 0; nt < 4; nt++){ frag_cd z = {0.f,0.f,0.f,0.f}; o[nt] = z; }

  for (int ch = 0; ch < 8; ch++){
    const int kr0 = kbeg + ch * 64;
    __syncthreads();   // prev PV done (and Q frag reads done on first iter)
    // stage K chunk and V^T chunk (all pre-split copies)
#pragma unroll
    for (int u = 0; u < 4; u++){
      const int f = tid + u * 256, row = f >> 4, c4 = (f & 15) << 2;
      *(ushort4*)&Kh[row*LP + c4]  = *(const ushort4*)(kSh + kb + (size_t)(kr0 + row) * DH + c4);
      *(ushort4*)&Kl[row*LP + c4]  = *(const ushort4*)(kSl + kb + (size_t)(kr0 + row) * DH + c4);
      *(ushort4*)&Wth[row*LP + c4] = *(const ushort4*)(vTh + vtb + (size_t)row * NTOK + kr0 + c4);
      *(ushort4*)&Wtl[row*LP + c4] = *(const ushort4*)(vTl + vtb + (size_t)row * NTOK + kr0 + c4);
    }
    __syncthreads();
    // S = Q @ K^T  (3-term split, Q from registers)
    frag_cd s[4];
#pragma unroll
    for (int nt = 0; nt < 4; nt++){ frag_cd z = {0.f,0.f,0.f,0.f}; s[nt] = z; }
    __builtin_amdgcn_s_setprio(1);
#pragma unroll
    for (int ks = 0; ks < 2; ks++){
#pragma unroll
      for (int nt = 0; nt < 4; nt++){
        const int bo = (nt*16 + lr)*LP + ks*32 + quad*8;
        frag_ab b_h = *(const frag_ab*)&Kh[bo];
        frag_ab b_l = *(const frag_ab*)&Kl[bo];
        s[nt] = __builtin_amdgcn_mfma_f32_16x16x32_bf16(qa_l[ks], b_h, s[nt], 0, 0, 0);
        s[nt] = __builtin_amdgcn_mfma_f32_16x16x32_bf16(qa_h[ks], b_l, s[nt], 0, 0, 0);
        s[nt] = __builtin_amdgcn_mfma_f32_16x16x32_bf16(qa_h[ks], b_h, s[nt], 0, 0, 0);
      }
    }
    __builtin_amdgcn_s_setprio(0);
    __syncthreads();   // all cross-wave K reads complete before P overwrites K planes
    // online softmax (exp2); P written into K planes (own-wave rows only)
#pragma unroll
    for (int rg = 0; rg < 4; rg++){
      float mx = fmaxf(fmaxf(s[0][rg], s[1][rg]), fmaxf(s[2][rg], s[3][rg]));
#pragma unroll
      for (int o2 = 8; o2 >= 1; o2 >>= 1) mx = fmaxf(mx, __shfl_xor(mx, o2));
      const float mnew = fmaxf(m_run[rg], mx);
      float e0 = exp2f((s[0][rg] - mnew) * LOG2E), e1 = exp2f((s[1][rg] - mnew) * LOG2E);
      float e2 = exp2f((s[2][rg] - mnew) * LOG2E), e3 = exp2f((s[3][rg] - mnew) * LOG2E);
      float psum = e0 + e1 + e2 + e3;
#pragma unroll
      for (int o2 = 8; o2 >= 1; o2 >>= 1) psum += __shfl_xor(psum, o2);
      const float alpha = exp2f((m_run[rg] - mnew) * LOG2E);
      l_run[rg] = l_run[rg] * alpha + psum;
      m_run[rg] = mnew;
#pragma unroll
      for (int nt = 0; nt < 4; nt++) o[nt][rg] *= alpha;
      const int prow = (wave*16 + quad*4 + rg) * LP;
      float ee[4] = {e0, e1, e2, e3};
#pragma unroll
      for (int nt = 0; nt < 4; nt++){
        const unsigned short hh = f2bs(ee[nt]);
        Kh[prow + nt*16 + lr] = hh;
        Kl[prow + nt*16 + lr] = f2bs(ee[nt] - bs2f(hh));
      }
    }
    // O += P @ V   (P own-wave rows from K planes; V^T cross-wave from W planes)
    __builtin_amdgcn_s_setprio(1);
#pragma unroll
    for (int ks = 0; ks < 2; ks++){
      const int ao = (wave*16 + lr)*LP + ks*32 + quad*8;
      frag_ab p_h = *(const frag_ab*)&Kh[ao];
      frag_ab p_l = *(const frag_ab*)&Kl[ao];
#pragma unroll
      for (int nt = 0; nt < 4; nt++){
        const int bo = (nt*16 + lr)*LP + ks*32 + quad*8;
        frag_ab b_h = *(const frag_ab*)&Wth[bo];
        frag_ab b_l = *(const frag_ab*)&Wtl[bo];
        o[nt] = __builtin_amdgcn_mfma_f32_16x16x32_bf16(p_l, b_h, o[nt], 0, 0, 0);
        o[nt] = __builtin_amdgcn_mfma_f32_16x16x32_bf16(p_h, b_l, o[nt], 0, 0, 0);
        o[nt] = __builtin_amdgcn_mfma_f32_16x16x32_bf16(p_h, b_h, o[nt], 0, 0, 0);
      }
    }
    __builtin_amdgcn_s_setprio(0);
  }
  // epilogue: unnormalized o + (m,l) partials, layout compatible with k_comb
  float* pb = pbuf + (((size_t)bh * 16 + kc) * 256 + m0) * 68;
#pragma unroll
  for (int rg = 0; rg < 4; rg++){
    const int row = wave*16 + quad*4 + rg;
#pragma unroll
    for (int nt = 0; nt < 4; nt++)
      pb[(size_t)row * 68 + nt*16 + lr] = o[nt][rg];
    if (lr == 0){
      pb[(size_t)row * 68 + 64] = m_run[rg];
      pb[(size_t)row * 68 + 65] = l_run[rg];
    }
  }
}

// ---------------- combine flash partials (16) -> av fp32 [bh][256][64]
__global__ __launch_bounds__(256) void k_comb(const float* __restrict__ pbuf, float* __restrict__ av){
  const int wv = threadIdx.x >> 6, lane = threadIdx.x & 63;
  const int id = blockIdx.x * 4 + wv;
  const int bh = id >> 8, row = id & 255;
  const float* base = pbuf + ((size_t)bh * 16 * 256 + row) * 68;
  float M = -1e30f;
#pragma unroll
  for (int k = 0; k < 16; k++) M = fmaxf(M, base[(size_t)k * 256 * 68 + 64]);
  float L = 0.f, o = 0.f;
#pragma unroll
  for (int k = 0; k < 16; k++){
    const float* p = base + (size_t)k * 256 * 68;
    float w = exp2f((p[64] - M) * LOG2E);
    L += p[65] * w;
    o += p[lane] * w;
  }
  av[((size_t)bh * MLM + row) * DH + lane] = o / L;
}

// ---------------- w2 = z_final @ av (fp32, M=256,N=64,K=256), batched
// also emits transposed hi/lo split w2T [bh][64][256] for the MFMA attn1 PV operand
__global__ __launch_bounds__(256) void k_w2(const float* __restrict__ Z, const float* __restrict__ AV,
                                            float* __restrict__ W2,
                                            unsigned short* __restrict__ w2Th,
                                            unsigned short* __restrict__ w2Tl){
  const int bh = blockIdx.y, mt = blockIdx.x;
  const float* Zb = Z + (size_t)bh * 65536;
  const float* Vb = AV + (size_t)bh * MLM * DH;
  float* Wb = W2 + (size_t)bh * MLM * DH;
  const int m0 = mt * 64;
  __shared__ float As[16][64];
  __shared__ float Bs[16][64];
  const int tid = threadIdx.x, ty = tid >> 4, tx = tid & 15;
  const int lm = tid >> 2, lk = (tid & 3) << 2;
  const int lk2 = tid >> 4, ln = (tid & 15) << 2;
  float acc[4][4] = {};
  for (int k0 = 0; k0 < 256; k0 += 16){
    float4 a4 = *(const float4*)(Zb + (size_t)(m0 + lm) * 256 + k0 + lk);
    As[lk+0][lm] = a4.x; As[lk+1][lm] = a4.y; As[lk+2][lm] = a4.z; As[lk+3][lm] = a4.w;
    float4 b4 = *(const float4*)(Vb + (size_t)(k0 + lk2) * DH + ln);
    *(float4*)&Bs[lk2][ln] = b4;
    __syncthreads();
#pragma unroll
    for (int kk = 0; kk < 16; kk++){
      float a[4], bv[4];
#pragma unroll
      for (int r = 0; r < 4; r++) a[r] = As[kk][ty*4 + r];
#pragma unroll
      for (int c = 0; c < 4; c++) bv[c] = Bs[kk][tx*4 + c];
#pragma unroll
      for (int r = 0; r < 4; r++)
#pragma unroll
        for (int c = 0; c < 4; c++) acc[r][c] += a[r] * bv[c];
    }
    __syncthreads();
  }
#pragma unroll
  for (int r = 0; r < 4; r++)
#pragma unroll
    for (int c = 0; c < 4; c++){
      const float val = acc[r][c];
      Wb[(size_t)(m0 + ty*4 + r) * DH + tx*4 + c] = val;
      const unsigned short hi = f2bs(val);
      const size_t tidx = ((size_t)bh * DH + tx*4 + c) * MLM + m0 + ty*4 + r;
      w2Th[tidx] = hi;
      w2Tl[tidx] = f2bs(val - bs2f(hi));
    }
}

// ---------------- fused attn1 (MFMA split-bf16): 512 threads / 8 waves, 128-row q tiles.
// Q fragments direct from global; K/W2 staged via REGISTER PREFETCH (next jc issued during
// current MFMA/softmax); P dedicated 2 planes.  exp2 softmax, setprio around MFMA.
// Output packed (hi|lo) bf16 IN PLACE over q.
__global__ __launch_bounds__(512) void k_attn1(float* __restrict__ qoh,
                                               const unsigned short* __restrict__ klSh,
                                               const unsigned short* __restrict__ klSl,
                                               const float* __restrict__ vf,
                                               const unsigned short* __restrict__ w2Th,
                                               const unsigned short* __restrict__ w2Tl,
                                               const float* __restrict__ wconv){
  extern __shared__ __align__(16) unsigned short sm[];
  unsigned short* Kh  = sm;                 // [64][LP]
  unsigned short* Kl  = sm + 1*64*LP;
  unsigned short* Wth = sm + 2*64*LP;
  unsigned short* Wtl = sm + 3*64*LP;
  unsigned short* Ph  = sm + 4*64*LP;       // [128][LP]
  unsigned short* Pl  = sm + 6*64*LP;       // [128][LP]
  float (*Vs)[68] = (float (*)[68])sm;      // conv phase: [160][68] = 43520 B
  float (*St)[68] = (float (*)[68])sm;      // pack phase: [128][68] = 34816 B
  __shared__ float wcs[33];
  const int it = blockIdx.x, bh = blockIdx.y, h = bh & 7;
  const int i0 = it * 128;
  float* qb = qoh + (size_t)bh * NTOK * DH;
  const int tid = threadIdx.x;
  const int wave = tid >> 6, lane = tid & 63;
  const int lr = lane & 15, quad = lane >> 4;
  if (tid < 33) wcs[tid] = wconv[h*33 + tid];
  // prologue: Q fragments direct from global (fp32 -> split in registers)
  frag_ab qa_h[2], qa_l[2];
#pragma unroll
  for (int ks = 0; ks < 2; ks++){
    const float* qsrc = qb + (size_t)(i0 + wave*16 + lr) * DH + ks*32 + quad*8;
    float4 a0 = *(const float4*)qsrc;
    float4 a1 = *(const float4*)(qsrc + 4);
    float vv[8] = {a0.x, a0.y, a0.z, a0.w, a1.x, a1.y, a1.z, a1.w};
    frag_ab fh, fl;
#pragma unroll
    for (int j = 0; j < 8; j++){
      const unsigned short hb = f2bs(vv[j]);
      fh[j] = (short)hb;
      fl[j] = (short)f2bs(vv[j] - bs2f(hb));
    }
    qa_h[ks] = fh; qa_l[ks] = fl;
  }
  float m_run[4], l_run[4];
  frag_cd o[4];
#pragma unroll
  for (int r = 0; r < 4; r++){ m_run[r] = -1e30f; l_run[r] = 0.f; }
#pragma unroll
  for (int nt = 0; nt < 4; nt++){ frag_cd z = {0.f,0.f,0.f,0.f}; o[nt] = z; }
  const size_t klbase = (size_t)bh * MLM * DH;
  const size_t wtbase = (size_t)bh * DH * MLM;
  // staging geometry (each thread owns 2 rows-slots of each plane)
  const int sr0 = tid >> 4, sc4 = (tid & 15) << 2;        // slot u=0: row sr0
  const int sr1 = (tid + 512) >> 4;                       // slot u=1: row sr1
  // prefetch jc=0 staging into registers
  ushort4 rKh[2], rKl[2], rWh[2], rWl[2];
  {
    const int j0 = 0;
    rKh[0] = *(const ushort4*)(klSh + klbase + (size_t)(j0 + sr0) * DH + sc4);
    rKl[0] = *(const ushort4*)(klSl + klbase + (size_t)(j0 + sr0) * DH + sc4);
    rWh[0] = *(const ushort4*)(w2Th + wtbase + (size_t)sr0 * MLM + j0 + sc4);
    rWl[0] = *(const ushort4*)(w2Tl + wtbase + (size_t)sr0 * MLM + j0 + sc4);
    rKh[1] = *(const ushort4*)(klSh + klbase + (size_t)(j0 + sr1) * DH + sc4);
    rKl[1] = *(const ushort4*)(klSl + klbase + (size_t)(j0 + sr1) * DH + sc4);
    rWh[1] = *(const ushort4*)(w2Th + wtbase + (size_t)sr1 * MLM + j0 + sc4);
    rWl[1] = *(const ushort4*)(w2Tl + wtbase + (size_t)sr1 * MLM + j0 + sc4);
  }

  for (int jc = 0; jc < 4; jc++){
    __syncthreads();   // prev iter's K/W reads done before restage
    // write prefetched registers into K/W planes (pure ds_write, no load latency)
    *(ushort4*)&Kh[sr0*LP + sc4]  = rKh[0];
    *(ushort4*)&Kl[sr0*LP + sc4]  = rKl[0];
    *(ushort4*)&Wth[sr0*LP + sc4] = rWh[0];
    *(ushort4*)&Wtl[sr0*LP + sc4] = rWl[0];
    *(ushort4*)&Kh[sr1*LP + sc4]  = rKh[1];
    *(ushort4*)&Kl[sr1*LP + sc4]  = rKl[1];
    *(ushort4*)&Wth[sr1*LP + sc4] = rWh[1];
    *(ushort4*)&Wtl[sr1*LP + sc4] = rWl[1];
    __syncthreads();
    // issue next jc's staging loads (latency hides under MFMA + softmax below)
    if (jc < 3){
      const int j0n = (jc + 1) * 64;
      rKh[0] = *(const ushort4*)(klSh + klbase + (size_t)(j0n + sr0) * DH + sc4);
      rKl[0] = *(const ushort4*)(klSl + klbase + (size_t)(j0n + sr0) * DH + sc4);
      rWh[0] = *(const ushort4*)(w2Th + wtbase + (size_t)sr0 * MLM + j0n + sc4);
      rWl[0] = *(const ushort4*)(w2Tl + wtbase + (size_t)sr0 * MLM + j0n + sc4);
      rKh[1] = *(const ushort4*)(klSh + klbase + (size_t)(j0n + sr1) * DH + sc4);
      rKl[1] = *(const ushort4*)(klSl + klbase + (size_t)(j0n + sr1) * DH + sc4);
      rWh[1] = *(const ushort4*)(w2Th + wtbase + (size_t)sr1 * MLM + j0n + sc4);
      rWl[1] = *(const ushort4*)(w2Tl + wtbase + (size_t)sr1 * MLM + j0n + sc4);
    }
    // S = Q @ K_l^T  (Q from registers)
    frag_cd s[4];
#pragma unroll
    for (int nt = 0; nt < 4; nt++){ frag_cd z = {0.f,0.f,0.f,0.f}; s[nt] = z; }
    __builtin_amdgcn_s_setprio(1);
#pragma unroll
    for (int ks = 0; ks < 2; ks++){
#pragma unroll
      for (int nt = 0; nt < 4; nt++){
        const int bo = (nt*16 + lr)*LP + ks*32 + quad*8;
        frag_ab b_h = *(const frag_ab*)&Kh[bo];
        frag_ab b_l = *(const frag_ab*)&Kl[bo];
        s[nt] = __builtin_amdgcn_mfma_f32_16x16x32_bf16(qa_l[ks], b_h, s[nt], 0, 0, 0);
        s[nt] = __builtin_amdgcn_mfma_f32_16x16x32_bf16(qa_h[ks], b_l, s[nt], 0, 0, 0);
        s[nt] = __builtin_amdgcn_mfma_f32_16x16x32_bf16(qa_h[ks], b_h, s[nt], 0, 0, 0);
      }
    }
    __builtin_amdgcn_s_setprio(0);
    // online softmax (exp2); P into dedicated planes (wave-private rows, no barrier needed)
#pragma unroll
    for (int rg = 0; rg < 4; rg++){
      float mx = fmaxf(fmaxf(s[0][rg], s[1][rg]), fmaxf(s[2][rg], s[3][rg]));
#pragma unroll
      for (int o2 = 8; o2 >= 1; o2 >>= 1) mx = fmaxf(mx, __shfl_xor(mx, o2));
      const float mnew = fmaxf(m_run[rg], mx);
      float e0 = exp2f((s[0][rg] - mnew) * LOG2E), e1 = exp2f((s[1][rg] - mnew) * LOG2E);
      float e2 = exp2f((s[2][rg] - mnew) * LOG2E), e3 = exp2f((s[3][rg] - mnew) * LOG2E);
      float psum = e0 + e1 + e2 + e3;
#pragma unroll
      for (int o2 = 8; o2 >= 1; o2 >>= 1) psum += __shfl_xor(psum, o2);
      const float alpha = exp2f((m_run[rg] - mnew) * LOG2E);
      l_run[rg] = l_run[rg] * alpha + psum;
      m_run[rg] = mnew;
#pragma unroll
      for (int nt = 0; nt < 4; nt++) o[nt][rg] *= alpha;
      const int prow = (wave*16 + quad*4 + rg) * LP;
      float ee[4] = {e0, e1, e2, e3};
#pragma unroll
      for (int nt = 0; nt < 4; nt++){
        const unsigned short hh = f2bs(ee[nt]);
        Ph[prow + nt*16 + lr] = hh;
        Pl[prow + nt*16 + lr] = f2bs(ee[nt] - bs2f(hh));
      }
    }
    // O += P @ W2chunk   (P wave-private rows; W planes synced at stage barrier)
    __builtin_amdgcn_s_setprio(1);
#pragma unroll
    for (int ks = 0; ks < 2; ks++){
      const int ao = (wave*16 + lr)*LP + ks*32 + quad*8;
      frag_ab p_h = *(const frag_ab*)&Ph[ao];
      frag_ab p_l = *(const frag_ab*)&Pl[ao];
#pragma unroll
      for (int nt = 0; nt < 4; nt++){
        const int bo = (nt*16 + lr)*LP + ks*32 + quad*8;
        frag_ab b_h = *(const frag_ab*)&Wth[bo];
        frag_ab b_l = *(const frag_ab*)&Wtl[bo];
        o[nt] = __builtin_amdgcn_mfma_f32_16x16x32_bf16(p_l, b_h, o[nt], 0, 0, 0);
        o[nt] = __builtin_amdgcn_mfma_f32_16x16x32_bf16(p_h, b_l, o[nt], 0, 0, 0);
        o[nt] = __builtin_amdgcn_mfma_f32_16x16x32_bf16(p_h, b_h, o[nt], 0, 0, 0);
      }
    }
    __builtin_amdgcn_s_setprio(0);
  }
  // normalize
#pragma unroll
  for (int rg = 0; rg < 4; rg++){
    const float inv = 1.f / l_run[rg];
#pragma unroll
    for (int nt = 0; nt < 4; nt++) o[nt][rg] *= inv;
  }
  // conv: stage v rows [i0-16, i0+143] (160 rows) into Vs (all LDS planes dead)
  __syncthreads();
#pragma unroll
  for (int u = 0; u < 5; u++){
    const int f = tid + u * 512, row = f >> 4, c4 = (f & 15) << 2;
    const int g = i0 - 16 + row;
    float4 vv = make_float4(0.f, 0.f, 0.f, 0.f);
    if (g >= 0 && g < NTOK) vv = *(const float4*)(vf + ((size_t)bh * NTOK + g) * DH + c4);
    *(float4*)&Vs[row][c4] = vv;
  }
  __syncthreads();
  // sliding-window conv: 36 reads per (nt), reuse across rg.
  // block-local out row R (0..127) uses Vs rows R..R+32
  const int rbase = wave*16 + quad*4;
#pragma unroll
  for (int nt = 0; nt < 4; nt++){
    const int col = nt*16 + lr;
#pragma unroll
    for (int s5 = 0; s5 < 36; s5++){
      const float v = Vs[rbase + s5][col];
#pragma unroll
      for (int rg = 0; rg < 4; rg++){
        const int t = s5 - rg;
        if (t >= 0 && t <= 32) o[nt][rg] += wcs[t] * v;
      }
    }
  }
  // pack (hi|lo) bf16, stage in St, coalesced write over q tile
  __syncthreads();
#pragma unroll
  for (int nt = 0; nt < 4; nt++)
#pragma unroll
    for (int rg = 0; rg < 4; rg++){
      const float val = o[nt][rg];
      const unsigned short hi = f2bs(val);
      const unsigned short lo = f2bs(val - bs2f(hi));
      St[rbase + rg][nt*16 + lr] = __uint_as_float((unsigned int)hi | ((unsigned int)lo << 16));
    }
  __syncthreads();
#pragma unroll
  for (int u = 0; u < 4; u++){
    const int f = tid + u * 512, row = f >> 4, c4 = (f & 15) << 2;
    *(float4*)(qb + (size_t)(i0 + row) * DH + c4) = *(const float4*)&St[row][c4];
  }
}

extern "C" void kernel_launch(void* const* d_in, const int* in_sizes, int n_in,
                              void* d_out, int out_size, void* d_ws, size_t ws_size,
                              hipStream_t stream){
  (void)in_sizes; (void)n_in; (void)out_size; (void)ws_size;
  const float* x     = (const float*)d_in[0];
  const float* wqkv  = (const float*)d_in[1];
  const float* wout  = (const float*)d_in[2];
  const float* bout  = (const float*)d_in[3];
  const float* wconv = (const float*)d_in[4];
  float* outp = (float*)d_out;

  char* base = (char*)d_ws;
  auto alloc = [&](size_t bytes)->char*{
    char* p = base; base += (bytes + 255) & ~(size_t)255; return p;
  };
  const size_t QS = (size_t)BH * NTOK * DH;   // 8388608
  const size_t LS = (size_t)BH * MLM * DH;    // 262144
  const size_t MM = (size_t)BH * MLM * MLM;   // 1048576

  float* qf   = (float*)alloc(QS * 4);   // q; packed oh overwrites in place
  float* vf   = (float*)alloc(QS * 4);
  unsigned short* kSh = (unsigned short*)alloc(QS * 2);
  unsigned short* kSl = (unsigned short*)alloc(QS * 2);
  float* qlf  = (float*)alloc(LS * 4);
  float* klf  = (float*)alloc(LS * 4);
  float* a2   = (float*)alloc(MM * 4);
  float* zb   = (float*)alloc(MM * 4);
  float* z2   = (float*)alloc(MM * 4);
  float* xz   = (float*)alloc(MM * 4);
  float* t2   = (float*)alloc(MM * 4);
  float* t4   = (float*)alloc(MM * 4);
  float* part = (float*)alloc(64 * 4);
  // union region: pinv transpose-split planes (10 x MM ushorts = 21.0 MB) alias pbuf
  // (flash partials, 16 x 16 x 256 x 68 x 4 B = 17.8 MB).  Planes dead before k_flash.
  char* un = alloc(10 * MM * 2);
  unsigned short* pl0 = (unsigned short*)un;
  unsigned short* zbTh = pl0 + 0*MM; unsigned short* zbTl = pl0 + 1*MM;
  unsigned short* z2Th = pl0 + 2*MM; unsigned short* z2Tl = pl0 + 3*MM;
  unsigned short* xzTh = pl0 + 4*MM; unsigned short* xzTl = pl0 + 5*MM;
  unsigned short* t2Th = pl0 + 6*MM; unsigned short* t2Tl = pl0 + 7*MM;
  unsigned short* t4Th = pl0 + 8*MM; unsigned short* t4Tl = pl0 + 9*MM;
  float* pbuf = (float*)un;
  float* av   = (float*)alloc(LS * 4);
  float* w2   = (float*)alloc(LS * 4);
  unsigned short* wqTh = (unsigned short*)alloc((size_t)1536 * 512 * 2);
  unsigned short* wqTl = (unsigned short*)alloc((size_t)1536 * 512 * 2);
  unsigned short* woTh = (unsigned short*)alloc((size_t)512 * 512 * 2);
  unsigned short* woTl = (unsigned short*)alloc((size_t)512 * 512 * 2);
  unsigned short* qlSh = (unsigned short*)alloc(LS * 2);
  unsigned short* qlSl = (unsigned short*)alloc(LS * 2);
  unsigned short* klSh = (unsigned short*)alloc(LS * 2);
  unsigned short* klSl = (unsigned short*)alloc(LS * 2);
  unsigned short* w2Th = (unsigned short*)alloc(LS * 2);
  unsigned short* w2Tl = (unsigned short*)alloc(LS * 2);
  unsigned short* vTh  = (unsigned short*)alloc(QS * 2);
  unsigned short* vTl  = (unsigned short*)alloc(QS * 2);
  // xh/xl alias vTh/vTl: consumed by k_mfma_qkv before k_vtrans overwrites.
  unsigned short* xh = vTh;
  unsigned short* xl = vTl;

  // 0. weight transpose + split (wqkv pre-swizzled for gload_lds; wout NOT); x split+swizzled
  k_splitw<<<1536 * 512 / 256, 256, 0, stream>>>(wqkv, 512, 1536, wqTh, wqTl, 1);
  k_splitw<<<512 * 512 / 256, 256, 0, stream>>>(wout, 512, 512, woTh, woTl, 0);
  k_splitx<<<8192, 256, 0, stream>>>(x, xh, xl);
  // 1. QKV projection (MFMA split-bf16, double-buffered gload_lds, XCD swizzle)
  k_mfma_qkv<<<dim3(1536), 256, 0, stream>>>(xh, xl, wqTh, wqTl, qf, kSh, kSl, vf);
  // 1b. v transpose+split for MFMA PV operand (overwrites xh/xl)
  k_vtrans<<<dim3(NTOK / 64, BH), 256, 0, stream>>>(vf, vTh, vTl);
  // 2. landmarks (+ split copies)
  k_land2<<<dim3(BH * MLM, 2), 64, 0, stream>>>(qf, kSh, kSl, qlf, klf, qlSh, qlSl, klSh, klSl);
  // 3. sim2 + softmax -> attn2
  k_sim2<<<dim3(4, 4, BH), 256, 0, stream>>>(qlf, klf, xz);
  k_softmax256<<<BH * MLM, 256, 0, stream>>>(xz, a2);
  // 4. pinv init (z0 also emits z^T split)
  k_colrow<<<BH, 256, 0, stream>>>(a2, part);
  k_z0<<<BH * MLM, 256, 0, stream>>>(a2, part, zb, zbTh, zbTl);
  // 5. 6 Newton-Schulz iterations (24 dispatches, 512-block prefetch GEMM, 3-term)
  {
    float* zc = zb;  unsigned short* zcTh = zbTh; unsigned short* zcTl = zbTl;
    float* zn = z2;  unsigned short* znTh = z2Th; unsigned short* znTl = z2Tl;
    for (int it = 0; it < 6; ++it){
      k_gemm256m<<<dim3(32, BH), 256, 0, stream>>>(a2, zcTh, zcTl, a2, xz, xzTh, xzTl, 0.f, -1.f, 1);
      k_gemm256m<<<dim3(32, BH), 256, 0, stream>>>(xz, xzTh, xzTl, xz, t2, t2Th, t2Tl, 7.f, 1.f, 0);
      k_gemm256m<<<dim3(32, BH), 256, 0, stream>>>(xz, t2Th, t2Tl, xz, t4, t4Th, t4Tl, 15.f, 1.f, 0);
      k_gemm256m<<<dim3(32, BH), 256, 0, stream>>>(zc, t4Th, t4Tl, zc, zn, znTh, znTl, 13.f, 0.25f, 1);
      float* tf = zc; zc = zn; zn = tf;
      unsigned short* th = zcTh; zcTh = znTh; znTh = th;
      unsigned short* tl = zcTl; zcTl = znTl; znTl = tl;
    }
  }
  const size_t FLASH_LDS = (size_t)4 * 64 * LP * 2;   // 36864 B
  const size_t ATTN1_LDS = (size_t)8 * 64 * LP * 2;   // 73728 B (K/W 4 planes + P 2x128-row)
  // 6. flash attn3@v (MFMA, all pre-split; kc split 16-way) + combine
  k_flash<<<dim3(16, 4, BH), 256, FLASH_LDS, stream>>>(qlSh, qlSl, kSh, kSl, vTh, vTl, pbuf);
  k_comb<<<BH * MLM / 4, 256, 0, stream>>>(pbuf, av);
  // 7. w2 = z_final @ av (final z lands in zb after 6 iters; + transposed split for attn1)
  k_w2<<<dim3(4, BH), 256, 0, stream>>>(zb, av, w2, w2Th, w2Tl);
  // 8. fused flash attn1 + conv (MFMA, 512 threads, reg-prefetch staging, setprio)
  k_attn1<<<dim3(64, BH), 512, ATTN1_LDS, stream>>>(qf, klSh, klSl, vf, w2Th, w2Tl, wconv);
  // 9. output projection + residual (MFMA split-bf16)
  k_mfma_final<<<dim3(512), 256, 0, stream>>>((const unsigned int*)qf, woTh, woTl, x, bout, outp);
}